// Round 1
// baseline (675.915 us; speedup 1.0000x reference)
//
#include <hip/hip_runtime.h>
#include <hip/hip_bf16.h>
#include <math.h>

#define N_NODES 8192
#define FEAT 512
#define NEGV -9e15f
#define VHPT_W 8704

typedef __attribute__((ext_vector_type(8))) short short8;
typedef __attribute__((ext_vector_type(4))) float floatx4;

// ---- workspace layout (bytes) ----
#define OFF_KH    0UL          // (dead in fast path; kept for layout stability)
#define OFF_VH    16777216UL   // f32 vh [8192][512]
#define OFF_KHP   33554432UL   // bf16 [8320][512]
#define OFF_VHPT  42074112UL   // bf16 [512][8704]  (padded-position columns)
#define OFF_MASK  50987008UL   // u64 [8192][128]; head reused early for cw (f64[1024])
#define OFF_S     59375616UL   // bf16 S, cap 25165824 elems; head reused early for Ahi/Alo/W*T
#define OFF_PERM  109707264UL
#define OFF_FLAGS 109740032UL
#define OFF_BUCK  109772800UL
#define OFF_META  109805568UL  // ints: [0..4]=boff [5..8]=padded [9..13]=soff(+tot) [14..18]=poff
#define OFF_CMEAN 109806592UL
#define OFF_ROWM  109808640UL  // f32 [8192] row max
#define OFF_ROWI  109841408UL  // f32 [8192] row 1/sum
#define OFF_IPERM 109874176UL  // int [8192] inverse permutation
#define WS_NEEDED 109906944UL
#define CAP_S     25165824L

// aliased (early-lifetime) buffers inside the S region:
#define OFF_AHI   (OFF_S)                 // bf16 [8192][512]
#define OFF_ALO   (OFF_S + 8388608UL)
#define OFF_WKHI  (OFF_S + 16777216UL)    // bf16 [512][512] transposed
#define OFF_WKLO  (OFF_S + 17301504UL)
#define OFF_WVHI  (OFF_S + 17825792UL)
#define OFF_WVLO  (OFF_S + 18350080UL)
#define OFF_CW    (OFF_MASK)              // f64 [512][2] (dead before maskpack)

static __device__ __forceinline__ unsigned short f2bf_bits(float x) {
  __hip_bfloat16 h = __float2bfloat16(x);
  unsigned short u;
  __builtin_memcpy(&u, &h, 2);
  return u;
}
static __device__ __forceinline__ float bf_bits2f(unsigned short u) {
  __hip_bfloat16 h;
  __builtin_memcpy(&h, &u, 2);
  return __bfloat162float(h);
}

// Async 16B/lane global->LDS copy (global_load_lds_dwordx4). LDS side must be
// wave-uniform base + lane*16 — all call sites below satisfy this.
static __device__ __forceinline__ void async_copy16(const void* gptr,
                                                    void* lptr) {
  __builtin_amdgcn_global_load_lds(
      (const __attribute__((address_space(1))) unsigned int*)gptr,
      (__attribute__((address_space(3))) unsigned int*)lptr, 16, 0, 0);
}

// ---------------------------------------------------------------------------
// input f32 -> bf16 hi/lo split (hi = bf16(x), lo = bf16(x - hi))
// ---------------------------------------------------------------------------
__global__ __launch_bounds__(256) void convert_input(
    const float* __restrict__ A, __hip_bfloat16* __restrict__ Ahi,
    __hip_bfloat16* __restrict__ Alo) {
  const long idx = ((long)blockIdx.x * 256 + threadIdx.x) * 4;
  const float4 v = *(const float4*)&A[idx];
  const float vv[4] = {v.x, v.y, v.z, v.w};
  ushort4 hi, lo;
  unsigned short* hp = (unsigned short*)&hi;
  unsigned short* lp = (unsigned short*)&lo;
#pragma unroll
  for (int e = 0; e < 4; e++) {
    unsigned short h = f2bf_bits(vv[e]);
    hp[e] = h;
    lp[e] = f2bf_bits(vv[e] - bf_bits2f(h));
  }
  *(ushort4*)&Ahi[idx] = hi;
  *(ushort4*)&Alo[idx] = lo;
}

// ---------------------------------------------------------------------------
// W[k][n] f32 -> transposed bf16 hi/lo: WT[n][k]. z=0: kW, z=1: vW.
// ---------------------------------------------------------------------------
__global__ __launch_bounds__(256) void convert_w(
    const float* __restrict__ kW, const float* __restrict__ vW,
    __hip_bfloat16* __restrict__ WkhiT, __hip_bfloat16* __restrict__ WkloT,
    __hip_bfloat16* __restrict__ WvhiT, __hip_bfloat16* __restrict__ WvloT) {
  __shared__ float tile[64][65];
  const int z = blockIdx.z;
  const float* __restrict__ W = z ? vW : kW;
  __hip_bfloat16* __restrict__ HiT = z ? WvhiT : WkhiT;
  __hip_bfloat16* __restrict__ LoT = z ? WvloT : WkloT;
  const int k0 = blockIdx.x * 64, n0 = blockIdx.y * 64;
  const int t = threadIdx.x;
#pragma unroll
  for (int s = 0; s < 16; s++) {
    int idx = t + s * 256;
    int r = idx >> 6, c = idx & 63;
    tile[r][c] = W[(long)(k0 + r) * FEAT + n0 + c];
  }
  __syncthreads();
#pragma unroll
  for (int s = 0; s < 16; s++) {
    int idx = t + s * 256;
    int a = idx >> 6, b = idx & 63;
    float w = tile[b][a];
    unsigned short h = f2bf_bits(w);
    unsigned short l = f2bf_bits(w - bf_bits2f(h));
    __builtin_memcpy(&HiT[(long)(n0 + a) * FEAT + k0 + b], &h, 2);
    __builtin_memcpy(&LoT[(long)(n0 + a) * FEAT + k0 + b], &l, 2);
  }
}

// ---------------------------------------------------------------------------
// kh/vh = A@W via split-bf16 MFMA: Ahi*Whi + Ahi*Wlo + Alo*Whi (~f32 accurate)
// z=0: scatter bf16 rows directly to khp[iperm[r]] (gather_khp fused away).
// z=1: write vh f32 (needed for transpose+cmean).
// ---------------------------------------------------------------------------
__global__ __launch_bounds__(256) void mfma_dual(
    const __hip_bfloat16* __restrict__ Ahi, const __hip_bfloat16* __restrict__ Alo,
    const __hip_bfloat16* __restrict__ WkhiT, const __hip_bfloat16* __restrict__ WkloT,
    const __hip_bfloat16* __restrict__ WvhiT, const __hip_bfloat16* __restrict__ WvloT,
    const int* __restrict__ iperm, __hip_bfloat16* __restrict__ khp,
    float* __restrict__ vh) {
  const int z = blockIdx.z;
  const __hip_bfloat16* __restrict__ WhiT = z ? WvhiT : WkhiT;
  const __hip_bfloat16* __restrict__ WloT = z ? WvloT : WkloT;
  const int ti = blockIdx.x, tj = blockIdx.y;
  __shared__ __align__(16) __hip_bfloat16 Ah[128 * 32];
  __shared__ __align__(16) __hip_bfloat16 Al[128 * 32];
  __shared__ __align__(16) __hip_bfloat16 Wh[128 * 32];
  __shared__ __align__(16) __hip_bfloat16 Wl[128 * 32];
  const int t = threadIdx.x;
  const int lane = t & 63, w = t >> 6;
  const int wm = (w >> 1) * 64, wn = (w & 1) * 64;
  const int quad = lane >> 4, ln = lane & 15;
  const int qr = quad * 8;
  floatx4 acc[4][4];
#pragma unroll
  for (int mi = 0; mi < 4; mi++)
#pragma unroll
    for (int ni = 0; ni < 4; ni++) acc[mi][ni] = (floatx4)0.f;
  for (int k0 = 0; k0 < FEAT; k0 += 32) {
    __syncthreads();
#pragma unroll
    for (int s = 0; s < 2; s++) {
      int c = t + s * 256;
      int row = c >> 2, off8 = (c & 3) * 8;
      int lo = row * 32 + off8;  // LDS elem offset == 8c -> byte 16c
      async_copy16(&Ahi[(long)(ti * 128 + row) * FEAT + k0 + off8], &Ah[lo]);
      async_copy16(&Alo[(long)(ti * 128 + row) * FEAT + k0 + off8], &Al[lo]);
      async_copy16(&WhiT[(long)(tj * 128 + row) * FEAT + k0 + off8], &Wh[lo]);
      async_copy16(&WloT[(long)(tj * 128 + row) * FEAT + k0 + off8], &Wl[lo]);
    }
    __syncthreads();
    short8 ah[4], al[4], bh[4], bl[4];
#pragma unroll
    for (int mi = 0; mi < 4; mi++) {
      ah[mi] = *(const short8*)&Ah[(wm + mi * 16 + ln) * 32 + qr];
      al[mi] = *(const short8*)&Al[(wm + mi * 16 + ln) * 32 + qr];
    }
#pragma unroll
    for (int ni = 0; ni < 4; ni++) {
      bh[ni] = *(const short8*)&Wh[(wn + ni * 16 + ln) * 32 + qr];
      bl[ni] = *(const short8*)&Wl[(wn + ni * 16 + ln) * 32 + qr];
    }
#pragma unroll
    for (int mi = 0; mi < 4; mi++)
#pragma unroll
      for (int ni = 0; ni < 4; ni++) {
        acc[mi][ni] = __builtin_amdgcn_mfma_f32_16x16x32_bf16(
            ah[mi], bh[ni], acc[mi][ni], 0, 0, 0);
        acc[mi][ni] = __builtin_amdgcn_mfma_f32_16x16x32_bf16(
            ah[mi], bl[ni], acc[mi][ni], 0, 0, 0);
        acc[mi][ni] = __builtin_amdgcn_mfma_f32_16x16x32_bf16(
            al[mi], bh[ni], acc[mi][ni], 0, 0, 0);
      }
  }
  if (z == 0) {
#pragma unroll
    for (int mi = 0; mi < 4; mi++)
#pragma unroll
      for (int reg = 0; reg < 4; reg++) {
        int r = ti * 128 + wm + mi * 16 + quad * 4 + reg;
        long kr = (long)iperm[r] * FEAT;
#pragma unroll
        for (int ni = 0; ni < 4; ni++) {
          int cc = tj * 128 + wn + ni * 16 + ln;
          khp[kr + cc] = __float2bfloat16(acc[mi][ni][reg]);
        }
      }
  } else {
#pragma unroll
    for (int mi = 0; mi < 4; mi++)
#pragma unroll
      for (int ni = 0; ni < 4; ni++) {
        int cc = tj * 128 + wn + ni * 16 + ln;
#pragma unroll
        for (int reg = 0; reg < 4; reg++) {
          int r = ti * 128 + wm + mi * 16 + quad * 4 + reg;
          vh[(long)r * FEAT + cc] = acc[mi][ni][reg];
        }
      }
  }
}

// ---------------------------------------------------------------------------
// cw[f][b] = sum_h kW[f][h] * rot[h][b]  (fp64)
// ---------------------------------------------------------------------------
__global__ __launch_bounds__(64) void cw_kernel(
    const float* __restrict__ kW, const float* __restrict__ rot,
    double* __restrict__ cw) {
  const int f = blockIdx.x;
  const int lane = threadIdx.x;
  double r0 = 0.0, r1 = 0.0;
  for (int h = lane; h < FEAT; h += 64) {
    double a = (double)kW[(long)f * FEAT + h];
    r0 += a * (double)rot[2 * h];
    r1 += a * (double)rot[2 * h + 1];
  }
#pragma unroll
  for (int off = 32; off > 0; off >>= 1) {
    r0 += __shfl_down(r0, off);
    r1 += __shfl_down(r1, off);
  }
  if (lane == 0) {
    cw[2 * f] = r0;
    cw[2 * f + 1] = r1;
  }
}

// ---------------------------------------------------------------------------
// buckets from EXACT inputs: rv = input @ cw in fp64; argmax([r0,r1,-r0,-r1])
// ---------------------------------------------------------------------------
__global__ __launch_bounds__(64) void rv_bucket_kernel(
    const float* __restrict__ input, const double* __restrict__ cw,
    int* __restrict__ buckets) {
  const int i = blockIdx.x;
  const int lane = threadIdx.x;
  double r0 = 0.0, r1 = 0.0;
  for (int f = lane; f < FEAT; f += 64) {
    double a = (double)input[(long)i * FEAT + f];
    r0 += a * cw[2 * f];
    r1 += a * cw[2 * f + 1];
  }
#pragma unroll
  for (int off = 32; off > 0; off >>= 1) {
    r0 += __shfl_down(r0, off);
    r1 += __shfl_down(r1, off);
  }
  if (lane == 0) {
    int b = 0;
    double best = r0;
    if (r1 > best)  { best = r1;  b = 1; }
    if (-r0 > best) { best = -r0; b = 2; }
    if (-r1 > best) { best = -r1; b = 3; }
    buckets[i] = b;
  }
}

// ---------------------------------------------------------------------------
// Stable counting sort by bucket (1 block, parallel Hillis-Steele scan).
// Emits perm AND inverse perm. Also zeroes cmean.
// ---------------------------------------------------------------------------
__global__ __launch_bounds__(256) void sort_kernel(
    const int* __restrict__ buckets, int* __restrict__ perm,
    int* __restrict__ iperm, int* __restrict__ meta,
    float* __restrict__ cmean) {
  __shared__ int lc[4][256];
  __shared__ int sc[4][256];
  __shared__ int boff_sh[5];
  const int t = threadIdx.x;
  cmean[t] = 0.f;
  cmean[t + 256] = 0.f;
  const int base = t * 32;
  int c0 = 0, c1 = 0, c2 = 0, c3 = 0;
  for (int k = 0; k < 32; k++) {
    int b = buckets[base + k];
    c0 += (b == 0); c1 += (b == 1); c2 += (b == 2); c3 += (b == 3);
  }
  lc[0][t] = c0; lc[1][t] = c1; lc[2][t] = c2; lc[3][t] = c3;
  sc[0][t] = c0; sc[1][t] = c1; sc[2][t] = c2; sc[3][t] = c3;
  __syncthreads();
  for (int off = 1; off < 256; off <<= 1) {
    int a0 = (t >= off) ? sc[0][t - off] : 0;
    int a1 = (t >= off) ? sc[1][t - off] : 0;
    int a2 = (t >= off) ? sc[2][t - off] : 0;
    int a3 = (t >= off) ? sc[3][t - off] : 0;
    __syncthreads();
    sc[0][t] += a0; sc[1][t] += a1; sc[2][t] += a2; sc[3][t] += a3;
    __syncthreads();
  }
  if (t == 0) {
    int boff[5];
    boff[0] = 0;
    for (int b = 0; b < 4; b++) boff[b + 1] = boff[b] + sc[b][255];
    for (int b = 0; b < 5; b++) { meta[b] = boff[b]; boff_sh[b] = boff[b]; }
    long so = 0;
    int po = 0;
    for (int b = 0; b < 4; b++) {
      int tot = boff[b + 1] - boff[b];
      int pad = ((tot + 127) >> 7) << 7;
      meta[5 + b] = pad;
      meta[9 + b] = (int)so;
      meta[14 + b] = po;
      so += (long)pad * pad;
      po += pad;
    }
    meta[13] = (int)so;
    meta[18] = po;
    if (so > CAP_S)
      for (int b = 0; b < 4; b++) meta[5 + b] = 0;
  }
  __syncthreads();
  int s0 = boff_sh[0] + sc[0][t] - lc[0][t];
  int s1 = boff_sh[1] + sc[1][t] - lc[1][t];
  int s2 = boff_sh[2] + sc[2][t] - lc[2][t];
  int s3 = boff_sh[3] + sc[3][t] - lc[3][t];
  for (int k = 0; k < 32; k++) {
    int i = base + k;
    int b = buckets[i];
    int pos = (b == 0) ? s0++ : ((b == 1) ? s1++ : ((b == 2) ? s2++ : s3++));
    perm[pos] = i;
    iperm[i] = pos;
  }
}

// ---------------------------------------------------------------------------
// vhpT[f][poff_b + local] = bf16(vh[perm[boff_b + local]][f]); pads zeroed.
// Fused cmean column-sum accumulation (cmean pre-zeroed by sort_kernel).
// ---------------------------------------------------------------------------
__global__ __launch_bounds__(256) void transpose_vhpT_kernel(
    const float* __restrict__ vh, const int* __restrict__ perm,
    const int* __restrict__ meta, __hip_bfloat16* __restrict__ vhpT,
    float* __restrict__ cmean) {
  __shared__ float tile[64][65];
  __shared__ float cred[4][64];
  const int g0 = blockIdx.x * 64;
  const int f0 = blockIdx.y * 64;
  const int t = threadIdx.x;
#pragma unroll
  for (int s = 0; s < 16; s++) {
    int idx = t + s * 256;
    int r = idx >> 6, c = idx & 63;
    int pos = g0 + r;
    int b = (pos >= meta[15]) + (pos >= meta[16]) + (pos >= meta[17]);
    int local = pos - meta[14 + b];
    int n_b = meta[b + 1] - meta[b];
    float v = 0.f;
    if (local < n_b) v = vh[(long)perm[meta[b] + local] * FEAT + f0 + c];
    tile[r][c] = v;
  }
  __syncthreads();
  {
    const int c = t & 63, seg = t >> 6;
    float ps = 0.f;
#pragma unroll
    for (int rr = 0; rr < 16; rr++) ps += tile[seg * 16 + rr][c];
    cred[seg][c] = ps;
  }
  __syncthreads();
  if (t < 64)
    atomicAdd(&cmean[f0 + t],
              cred[0][t] + cred[1][t] + cred[2][t] + cred[3][t]);
#pragma unroll
  for (int s = 0; s < 16; s++) {
    int idx = t + s * 256;
    int fr = idx >> 6, gc = idx & 63;
    vhpT[(long)(f0 + fr) * VHPT_W + g0 + gc] = __float2bfloat16(tile[gc][fr]);
  }
}

// ---------------------------------------------------------------------------
// maskbits[g][jj] = (adj[perm[g]][perm[boff_b+jj]] > 0), bit-packed per 64.
// ---------------------------------------------------------------------------
__global__ __launch_bounds__(256) void maskpack_kernel(
    const int* __restrict__ adj, const int* __restrict__ perm,
    const int* __restrict__ meta, unsigned long long* __restrict__ maskbits) {
  __shared__ int adj_lds[N_NODES];
  const int g = blockIdx.x;
  const int t = threadIdx.x;
  const int b = (g >= meta[1]) + (g >= meta[2]) + (g >= meta[3]);
  const int boff = meta[b];
  const int n_b = meta[b + 1] - boff;
  const int padded = meta[5 + b];
  const int i = perm[g];
  const int* arow = adj + (long)i * N_NODES;
#pragma unroll
  for (int s = 0; s < 8; s++) {
    int idx = (t + s * 256) * 4;
    *(int4*)&adj_lds[idx] = *(const int4*)&arow[idx];
  }
  __syncthreads();
  const int lane = t & 63, w = t >> 6;
  for (int jj0 = w * 64; jj0 < padded; jj0 += 256) {
    int jj = jj0 + lane;
    int pred = 0;
    if (jj < n_b) pred = adj_lds[perm[boff + jj]] > 0;
    unsigned long long mword = __ballot(pred);
    if (lane == 0) maskbits[(long)g * 128 + (jj0 >> 6)] = mword;
  }
}

// ---------------------------------------------------------------------------
// S tile = khp_b . khp_b^T (bf16 MFMA, async staging, BK=64 dual-panel).
// SYMMETRY: triangular-linearized grid covers ti <= tj only; epilogue routes
// acc through an LDS tile and writes BOTH orientations with coalesced 16B
// stores, applying the orientation-specific mask via u16 bit-selects.
// ---------------------------------------------------------------------------
__global__ __launch_bounds__(256) void s_gemm(
    const __hip_bfloat16* __restrict__ khp, const int* __restrict__ meta,
    const unsigned long long* __restrict__ maskbits,
    __hip_bfloat16* __restrict__ S) {
  const int b = blockIdx.z;
  const int padded = meta[5 + b];
  const int T = padded >> 7;
  const int pairs = (T * (T + 1)) >> 1;
  int L = blockIdx.x;
  if (L >= pairs) return;
  int ti = 0;
  while (L >= T - ti) { L -= T - ti; ti++; }
  const int tj = ti + L;
  const int boff = meta[b];
  const long soff = meta[9 + b];
  // 34,816 B: As/Bs (2 panels x 8 KB each) during main loop; Ct[128][136].
  __shared__ __align__(16) __hip_bfloat16 smem[128 * 136];
  __hip_bfloat16* As = smem;                  // [2][128*32]
  __hip_bfloat16* Bs = smem + 2 * 128 * 32;   // [2][128*32]
  const int t = threadIdx.x;
  const int lane = t & 63, w = t >> 6;
  const int wm = (w >> 1) * 64, wn = (w & 1) * 64;
  const int quad = lane >> 4, ln = lane & 15;
  const int qr = quad * 8;
  floatx4 acc[4][4];
#pragma unroll
  for (int mi = 0; mi < 4; mi++)
#pragma unroll
    for (int ni = 0; ni < 4; ni++) acc[mi][ni] = (floatx4)0.f;
  const long a_g0 = boff + ti * 128;
  const long b_g0 = boff + tj * 128;
  for (int k0 = 0; k0 < FEAT; k0 += 64) {
    __syncthreads();
#pragma unroll
    for (int p = 0; p < 2; p++)
#pragma unroll
      for (int s = 0; s < 2; s++) {
        int c = t + s * 256;
        int row = c >> 2, off8 = (c & 3) * 8;
        int lo = p * 4096 + row * 32 + off8;  // wave-uniform + lane*16
        async_copy16(&khp[(a_g0 + row) * FEAT + k0 + p * 32 + off8], &As[lo]);
        async_copy16(&khp[(b_g0 + row) * FEAT + k0 + p * 32 + off8], &Bs[lo]);
      }
    __syncthreads();
#pragma unroll
    for (int p = 0; p < 2; p++) {
      short8 af[4], bfr[4];
#pragma unroll
      for (int mi = 0; mi < 4; mi++)
        af[mi] =
            *(const short8*)&As[p * 4096 + (wm + mi * 16 + ln) * 32 + qr];
#pragma unroll
      for (int ni = 0; ni < 4; ni++)
        bfr[ni] =
            *(const short8*)&Bs[p * 4096 + (wn + ni * 16 + ln) * 32 + qr];
#pragma unroll
      for (int mi = 0; mi < 4; mi++)
#pragma unroll
        for (int ni = 0; ni < 4; ni++)
          acc[mi][ni] = __builtin_amdgcn_mfma_f32_16x16x32_bf16(
              af[mi], bfr[ni], acc[mi][ni], 0, 0, 0);
    }
  }
  // ---- epilogue: acc -> LDS tile (scaled bf16, unmasked) ----
  const float scale = 0.04419417382415922f;  // 1/sqrt(512)
  __syncthreads();  // As/Bs dead; reuse as Ct
  __hip_bfloat16* Ct = smem;  // [128][136]
#pragma unroll
  for (int mi = 0; mi < 4; mi++)
#pragma unroll
    for (int ni = 0; ni < 4; ni++) {
      int col = wn + ni * 16 + ln;
#pragma unroll
      for (int reg = 0; reg < 4; reg++) {
        int row = wm + mi * 16 + quad * 4 + reg;
        Ct[row * 136 + col] = __float2bfloat16(acc[mi][ni][reg] * scale);
      }
    }
  __syncthreads();
  const unsigned short negb = f2bf_bits(NEGV);
  // normal orientation: coalesced 16B stores of rows of the ti-block
#pragma unroll
  for (int i = 0; i < 8; i++) {
    int idx = t + i * 256;
    int rl = idx >> 4, c8 = (idx & 15) * 8;
    int rg = ti * 128 + rl;
    int cg = tj * 128 + c8;
    union { short8 v; unsigned short u[8]; } pk;
    pk.v = *(const short8*)&Ct[rl * 136 + c8];
    unsigned long long wbits = maskbits[(long)(boff + rg) * 128 + (cg >> 6)];
#pragma unroll
    for (int e = 0; e < 8; e++)
      if (!((wbits >> ((cg & 63) + e)) & 1ULL)) pk.u[e] = negb;
    *(short8*)&S[soff + (long)rg * padded + cg] = pk.v;
  }
  // mirrored orientation (tj-block rows), skipped on diagonal
  if (ti != tj) {
#pragma unroll
    for (int i = 0; i < 8; i++) {
      int idx = t + i * 256;
      int cl = idx >> 4, r8 = (idx & 15) * 8;
      int rg = tj * 128 + cl;   // output row (column of the computed tile)
      int cg = ti * 128 + r8;   // output col base
      union { short8 v; unsigned short u[8]; } pk;
#pragma unroll
      for (int e = 0; e < 8; e++) {
        __hip_bfloat16 hv = Ct[(r8 + e) * 136 + cl];
        __builtin_memcpy(&pk.u[e], &hv, 2);
      }
      unsigned long long wbits = maskbits[(long)(boff + rg) * 128 + (cg >> 6)];
#pragma unroll
      for (int e = 0; e < 8; e++)
        if (!((wbits >> ((cg & 63) + e)) & 1ULL)) pk.u[e] = negb;
      *(short8*)&S[soff + (long)rg * padded + cg] = pk.v;
    }
  }
}

// ---------------------------------------------------------------------------
// Row stats — ONE WAVE PER ROW (4 rows/block): m = max, inv = 1/sum(exp),
// flags for empty rows. Exactly the old softmax passes 1-2; the normalize
// pass is fused into pv_gemm.
// ---------------------------------------------------------------------------
__global__ __launch_bounds__(256) void rowstats_kernel(
    const __hip_bfloat16* __restrict__ S, const int* __restrict__ meta,
    int* __restrict__ flags, float* __restrict__ rowm,
    float* __restrict__ rowinv) {
  const int g = blockIdx.x * 4 + (threadIdx.x >> 6);
  const int lane = threadIdx.x & 63;
  const int b = (g >= meta[1]) + (g >= meta[2]) + (g >= meta[3]);
  const int boff = meta[b];
  const int padded = meta[5 + b];
  const long soff = meta[9 + b];
  const __hip_bfloat16* row = S + soff + (long)(g - boff) * padded;
  // pass 1: row max
  float m = -INFINITY;
  for (int j0 = lane * 8; j0 < padded; j0 += 512) {
    union { short8 v; unsigned short u[8]; } pk;
    pk.v = *(const short8*)&row[j0];
#pragma unroll
    for (int e = 0; e < 8; e++) m = fmaxf(m, bf_bits2f(pk.u[e]));
  }
#pragma unroll
  for (int off = 32; off > 0; off >>= 1) m = fmaxf(m, __shfl_xor(m, off));
  if (m < -8e15f) {  // empty (or degenerate) row -> P == 0 via inv = 0
    if (lane == 0) { flags[g] = 1; rowm[g] = m; rowinv[g] = 0.f; }
    return;
  }
  // pass 2: sum of exp (row is L1/L2-hot from pass 1)
  float sum = 0.f;
  for (int j0 = lane * 8; j0 < padded; j0 += 512) {
    union { short8 v; unsigned short u[8]; } pk;
    pk.v = *(const short8*)&row[j0];
#pragma unroll
    for (int e = 0; e < 8; e++) sum += expf(bf_bits2f(pk.u[e]) - m);
  }
#pragma unroll
  for (int off = 32; off > 0; off >>= 1) sum += __shfl_xor(sum, off);
  if (lane == 0) { flags[g] = 0; rowm[g] = m; rowinv[g] = 1.f / sum; }
}

// ---------------------------------------------------------------------------
// O tile = softmax(S) . vhp, fused: 64 rows x 128 features per block.
// A-fragments converted bf16(expf(S - m) * inv) between LDS load and MFMA
// (bit-identical to the old materialized-P path). BK=64 dual-panel staging.
// Epilogue: ELU + empty-row fallback + scatter to out[perm[g]].
// ---------------------------------------------------------------------------
__global__ __launch_bounds__(256) void pv_fused(
    const __hip_bfloat16* __restrict__ S, const __hip_bfloat16* __restrict__ vhpT,
    const int* __restrict__ meta, const int* __restrict__ perm,
    const int* __restrict__ flags, const float* __restrict__ cmean,
    const float* __restrict__ rowm, const float* __restrict__ rowinv,
    float* __restrict__ out) {
  const int b = blockIdx.z;
  const int padded = meta[5 + b];
  const int ti = blockIdx.x;
  if (ti * 64 >= padded) return;
  const int boff = meta[b];
  const int n_b = meta[b + 1] - boff;
  const long soff = meta[9 + b];
  const int poff = meta[14 + b];
  const int f0 = blockIdx.y * 128;
  __shared__ __align__(16) __hip_bfloat16 As[2 * 64 * 32];
  __shared__ __align__(16) __hip_bfloat16 Bs[2 * 128 * 32];
  const int t = threadIdx.x;
  const int lane = t & 63, w = t >> 6;
  const int wm = (w >> 1) * 32, wn = (w & 1) * 64;
  const int quad = lane >> 4, ln = lane & 15;
  const int qr = quad * 8;
  // per-thread softmax stats for the 2 A-rows this lane feeds
  float mrow[2], invl[2];
#pragma unroll
  for (int mi = 0; mi < 2; mi++) {
    int g = boff + ti * 64 + wm + mi * 16 + ln;
    if (g > N_NODES - 1) g = N_NODES - 1;  // pad rows: garbage, discarded
    mrow[mi] = rowm[g];
    invl[mi] = rowinv[g];
  }
  floatx4 acc[2][4];
#pragma unroll
  for (int mi = 0; mi < 2; mi++)
#pragma unroll
    for (int ni = 0; ni < 4; ni++) acc[mi][ni] = (floatx4)0.f;
  const long r0 = (long)ti * 64;
  for (int k0 = 0; k0 < padded; k0 += 64) {
    __syncthreads();
#pragma unroll
    for (int p = 0; p < 2; p++) {
      {
        int row = t >> 2, off8 = (t & 3) * 8;
        async_copy16(&S[soff + (r0 + row) * padded + k0 + p * 32 + off8],
                     &As[p * 2048 + row * 32 + off8]);
      }
#pragma unroll
      for (int s = 0; s < 2; s++) {
        int c = t + s * 256;
        int row = c >> 2, off8 = (c & 3) * 8;
        async_copy16(
            &vhpT[(long)(f0 + row) * VHPT_W + poff + k0 + p * 32 + off8],
            &Bs[p * 4096 + row * 32 + off8]);
      }
    }
    __syncthreads();
#pragma unroll
    for (int p = 0; p < 2; p++) {
      short8 pa[2], bfr[4];
#pragma unroll
      for (int mi = 0; mi < 2; mi++) {
        union { short8 v; unsigned short u[8]; } in, pw;
        in.v = *(const short8*)&As[p * 2048 + (wm + mi * 16 + ln) * 32 + qr];
#pragma unroll
        for (int e = 0; e < 8; e++) {
          float x = bf_bits2f(in.u[e]);
          pw.u[e] = f2bf_bits(expf(x - mrow[mi]) * invl[mi]);
        }
        pa[mi] = pw.v;
      }
#pragma unroll
      for (int ni = 0; ni < 4; ni++)
        bfr[ni] = *(const short8*)&Bs[p * 4096 + (wn + ni * 16 + ln) * 32 + qr];
#pragma unroll
      for (int mi = 0; mi < 2; mi++)
#pragma unroll
        for (int ni = 0; ni < 4; ni++)
          acc[mi][ni] = __builtin_amdgcn_mfma_f32_16x16x32_bf16(
              pa[mi], bfr[ni], acc[mi][ni], 0, 0, 0);
    }
  }
#pragma unroll
  for (int mi = 0; mi < 2; mi++) {
#pragma unroll
    for (int reg = 0; reg < 4; reg++) {
      int r = ti * 64 + wm + mi * 16 + quad * 4 + reg;
      if (r < n_b) {
        int g = boff + r;
        int node = perm[g];
        int fl = flags[g];
#pragma unroll
        for (int ni = 0; ni < 4; ni++) {
          int fc = f0 + wn + ni * 16 + ln;
          float v = fl ? cmean[fc] * (1.f / (float)N_NODES)
                       : acc[mi][ni][reg];
          v = v > 0.f ? v : expm1f(v);
          out[(long)node * FEAT + fc] = v;
        }
      }
    }
  }
}

// ===========================================================================
// Slow-path fallback (only if ws_size < WS_NEEDED): round-1 implementation.
// ===========================================================================
__global__ __launch_bounds__(256) void gemm_dual(
    const float* __restrict__ A, const float* __restrict__ Wk,
    const float* __restrict__ Wv, float* __restrict__ kh,
    float* __restrict__ vh) {
  __shared__ float As[32][33];
  __shared__ float Bk[32][33];
  __shared__ float Bv[32][33];
  const int tid = threadIdx.x;
  const int row0 = blockIdx.x * 32;
  const int col0 = blockIdx.y * 32;
  const int tx = tid & 15, ty = tid >> 4;
  float ck00 = 0.f, ck01 = 0.f, ck10 = 0.f, ck11 = 0.f;
  float cv00 = 0.f, cv01 = 0.f, cv10 = 0.f, cv11 = 0.f;
  for (int kt = 0; kt < FEAT; kt += 32) {
#pragma unroll
    for (int t = 0; t < 4; t++) {
      int e = tid + t * 256;
      int r = e >> 5, c = e & 31;
      As[r][c] = A[(long)(row0 + r) * FEAT + kt + c];
      Bk[r][c] = Wk[(long)(kt + r) * FEAT + col0 + c];
      Bv[r][c] = Wv[(long)(kt + r) * FEAT + col0 + c];
    }
    __syncthreads();
#pragma unroll
    for (int kk = 0; kk < 32; kk++) {
      float a0 = As[ty * 2][kk], a1 = As[ty * 2 + 1][kk];
      float bk0 = Bk[kk][tx * 2], bk1 = Bk[kk][tx * 2 + 1];
      float bv0 = Bv[kk][tx * 2], bv1 = Bv[kk][tx * 2 + 1];
      ck00 += a0 * bk0; ck01 += a0 * bk1;
      ck10 += a1 * bk0; ck11 += a1 * bk1;
      cv00 += a0 * bv0; cv01 += a0 * bv1;
      cv10 += a1 * bv0; cv11 += a1 * bv1;
    }
    __syncthreads();
  }
  const int r0 = row0 + ty * 2, c0 = col0 + tx * 2;
  kh[(long)r0 * FEAT + c0] = ck00;       kh[(long)r0 * FEAT + c0 + 1] = ck01;
  kh[(long)(r0 + 1) * FEAT + c0] = ck10; kh[(long)(r0 + 1) * FEAT + c0 + 1] = ck11;
  vh[(long)r0 * FEAT + c0] = cv00;       vh[(long)r0 * FEAT + c0 + 1] = cv01;
  vh[(long)(r0 + 1) * FEAT + c0] = cv10; vh[(long)(r0 + 1) * FEAT + c0 + 1] = cv11;
}

__global__ __launch_bounds__(64) void bucket_kernel(
    const float* __restrict__ kh, const float* __restrict__ rot,
    int* __restrict__ buckets) {
  const int i = blockIdx.x;
  const int lane = threadIdx.x;
  double r0 = 0.0, r1 = 0.0;
  for (int h = lane; h < FEAT; h += 64) {
    double a = (double)kh[(long)i * FEAT + h];
    r0 += a * (double)rot[2 * h];
    r1 += a * (double)rot[2 * h + 1];
  }
#pragma unroll
  for (int off = 32; off > 0; off >>= 1) {
    r0 += __shfl_down(r0, off);
    r1 += __shfl_down(r1, off);
  }
  if (lane == 0) {
    int b = 0;
    double best = r0;
    if (r1 > best)  { best = r1;  b = 1; }
    if (-r0 > best) { best = -r0; b = 2; }
    if (-r1 > best) { best = -r1; b = 3; }
    buckets[i] = b;
  }
}

__global__ __launch_bounds__(256) void attn_kernel(
    const float* __restrict__ kh, const float* __restrict__ vh,
    const int* __restrict__ adj, const int* __restrict__ buckets,
    float* __restrict__ out) {
  __shared__ float khi[FEAT];
  __shared__ float pbuf[N_NODES];
  __shared__ unsigned short jlist[N_NODES];
  __shared__ int cnt_sh;
  __shared__ float red[256];
  const int i = blockIdx.x;
  const int tid = threadIdx.x;
  if (tid == 0) cnt_sh = 0;
  for (int k = tid; k < FEAT; k += 256) khi[k] = kh[(long)i * FEAT + k];
  const int mybucket = buckets[i];
  __syncthreads();
  const int* adjrow = adj + (long)i * N_NODES;
  for (int j = tid; j < N_NODES; j += 256) {
    if (adjrow[j] > 0 && buckets[j] == mybucket) {
      int idx = atomicAdd(&cnt_sh, 1);
      jlist[idx] = (unsigned short)j;
    }
  }
  __syncthreads();
  const int cnt = cnt_sh;
  float mloc = -INFINITY;
  for (int idx = tid; idx < cnt; idx += 256) {
    int j = jlist[idx];
    const float4* kj = (const float4*)(kh + (long)j * FEAT);
    const float4* ki = (const float4*)khi;
    float acc = 0.f;
#pragma unroll 8
    for (int k = 0; k < FEAT / 4; k++) {
      float4 a = ki[k];
      float4 b = kj[k];
      acc += a.x * b.x + a.y * b.y + a.z * b.z + a.w * b.w;
    }
    float s = acc * 0.04419417382415922f;
    pbuf[idx] = s;
    mloc = fmaxf(mloc, s);
  }
  red[tid] = mloc;
  __syncthreads();
#pragma unroll
  for (int off = 128; off > 0; off >>= 1) {
    if (tid < off) red[tid] = fmaxf(red[tid], red[tid + off]);
    __syncthreads();
  }
  const float m = red[0];
  __syncthreads();
  float lloc = 0.f;
  for (int idx = tid; idx < cnt; idx += 256) {
    float p = expf(pbuf[idx] - m);
    pbuf[idx] = p;
    lloc += p;
  }
  red[tid] = lloc;
  __syncthreads();
#pragma unroll
  for (int off = 128; off > 0; off >>= 1) {
    if (tid < off) red[tid] += red[tid + off];
    __syncthreads();
  }
  const float l = red[0];
  __syncthreads();
  const int f = 2 * tid;
  float acc0 = 0.f, acc1 = 0.f;
  if (cnt > 0) {
#pragma unroll 4
    for (int idx = 0; idx < cnt; idx++) {
      int j = jlist[idx];
      float p = pbuf[idx];
      float2 v = *(const float2*)(vh + (long)j * FEAT + f);
      acc0 += p * v.x;
      acc1 += p * v.y;
    }
    float invl = 1.f / l;
    acc0 *= invl;
    acc1 *= invl;
  } else {
    for (int j = 0; j < N_NODES; j++) {
      float2 v = *(const float2*)(vh + (long)j * FEAT + f);
      acc0 += v.x;
      acc1 += v.y;
    }
    acc0 *= (1.f / (float)N_NODES);
    acc1 *= (1.f / (float)N_NODES);
  }
  acc0 = acc0 > 0.f ? acc0 : expm1f(acc0);
  acc1 = acc1 > 0.f ? acc1 : expm1f(acc1);
  *(float2*)(out + (long)i * FEAT + f) = make_float2(acc0, acc1);
}

extern "C" void kernel_launch(void* const* d_in, const int* in_sizes, int n_in,
                              void* d_out, int out_size, void* d_ws,
                              size_t ws_size, hipStream_t stream) {
  const float* input = (const float*)d_in[0];
  const int* adj = (const int*)d_in[1];
  const float* rot = (const float*)d_in[2];
  const float* kW = (const float*)d_in[3];
  const float* vW = (const float*)d_in[4];
  float* out = (float*)d_out;

  char* ws = (char*)d_ws;

  if (ws_size >= WS_NEEDED) {
    float* vh = (float*)(ws + OFF_VH);
    __hip_bfloat16* khp = (__hip_bfloat16*)(ws + OFF_KHP);
    __hip_bfloat16* vhpT = (__hip_bfloat16*)(ws + OFF_VHPT);
    unsigned long long* maskbits = (unsigned long long*)(ws + OFF_MASK);
    __hip_bfloat16* S = (__hip_bfloat16*)(ws + OFF_S);
    int* perm = (int*)(ws + OFF_PERM);
    int* iperm = (int*)(ws + OFF_IPERM);
    int* flags = (int*)(ws + OFF_FLAGS);
    int* buckets = (int*)(ws + OFF_BUCK);
    int* meta = (int*)(ws + OFF_META);
    float* cmean = (float*)(ws + OFF_CMEAN);
    float* rowm = (float*)(ws + OFF_ROWM);
    float* rowinv = (float*)(ws + OFF_ROWI);
    __hip_bfloat16* Ahi = (__hip_bfloat16*)(ws + OFF_AHI);
    __hip_bfloat16* Alo = (__hip_bfloat16*)(ws + OFF_ALO);
    __hip_bfloat16* WkhiT = (__hip_bfloat16*)(ws + OFF_WKHI);
    __hip_bfloat16* WkloT = (__hip_bfloat16*)(ws + OFF_WKLO);
    __hip_bfloat16* WvhiT = (__hip_bfloat16*)(ws + OFF_WVHI);
    __hip_bfloat16* WvloT = (__hip_bfloat16*)(ws + OFF_WVLO);
    double* cw = (double*)(ws + OFF_CW);

    // zero khp tail rows [8192, 8320) — read (masked) by s_gemm/pv when the
    // last bucket's padding spills past N.
    hipMemsetAsync(ws + OFF_KHP + (size_t)N_NODES * FEAT * 2, 0,
                   128 * FEAT * 2, stream);
    convert_input<<<4096, 256, 0, stream>>>(input, Ahi, Alo);
    convert_w<<<dim3(8, 8, 2), 256, 0, stream>>>(kW, vW, WkhiT, WkloT, WvhiT,
                                                 WvloT);
    cw_kernel<<<512, 64, 0, stream>>>(kW, rot, cw);
    rv_bucket_kernel<<<N_NODES, 64, 0, stream>>>(input, cw, buckets);
    sort_kernel<<<1, 256, 0, stream>>>(buckets, perm, iperm, meta, cmean);
    mfma_dual<<<dim3(64, 4, 2), 256, 0, stream>>>(Ahi, Alo, WkhiT, WkloT,
                                                  WvhiT, WvloT, iperm, khp,
                                                  vh);
    transpose_vhpT_kernel<<<dim3(VHPT_W / 64, FEAT / 64), 256, 0, stream>>>(
        vh, perm, meta, vhpT, cmean);
    maskpack_kernel<<<N_NODES, 256, 0, stream>>>(adj, perm, meta, maskbits);
    s_gemm<<<dim3(2080, 1, 4), 256, 0, stream>>>(khp, meta, maskbits, S);
    rowstats_kernel<<<N_NODES / 4, 256, 0, stream>>>(S, meta, flags, rowm,
                                                     rowinv);
    pv_fused<<<dim3(128, 4, 4), 256, 0, stream>>>(S, vhpT, meta, perm, flags,
                                                  cmean, rowm, rowinv, out);
  } else {
    float* kh = (float*)(ws + 0UL);
    float* vh = (float*)(ws + 16777216UL);
    int* buckets = (int*)(ws + 33554432UL);
    dim3 gemm_grid(N_NODES / 32, FEAT / 32);
    gemm_dual<<<gemm_grid, 256, 0, stream>>>(input, kW, vW, kh, vh);
    bucket_kernel<<<N_NODES, 64, 0, stream>>>(kh, rot, buckets);
    attn_kernel<<<N_NODES, 256, 0, stream>>>(kh, vh, adj, buckets, out);
  }
}

// Round 2
// 595.073 us; speedup vs baseline: 1.1359x; 1.1359x over previous
//
#include <hip/hip_runtime.h>
#include <hip/hip_bf16.h>
#include <math.h>

#define N_NODES 8192
#define FEAT 512
#define NEGV -9e15f
#define VHPT_W 8704

typedef __attribute__((ext_vector_type(8))) short short8;
typedef __attribute__((ext_vector_type(4))) float floatx4;

// ---- workspace layout (bytes) ----
#define OFF_KH    0UL          // (dead in fast path; kept for layout stability)
#define OFF_VH    16777216UL   // f32 vh [8192][512]
#define OFF_KHP   33554432UL   // bf16 [8320][512]
#define OFF_VHPT  42074112UL   // bf16 [512][8704]  (padded-position columns)
#define OFF_MASK  50987008UL   // u64 [8192][128]; head reused early for cw (f64[1024])
#define OFF_S     59375616UL   // bf16 S, cap 25165824 elems; head reused early for Ahi/Alo/W*T
#define OFF_PERM  109707264UL
#define OFF_FLAGS 109740032UL
#define OFF_BUCK  109772800UL
#define OFF_META  109805568UL  // ints: [0..4]=boff [5..8]=padded [9..13]=soff(+tot) [14..18]=poff
#define OFF_CMEAN 109806592UL
#define OFF_ROWM  109808640UL  // f32 [8192] (unused this round; layout stability)
#define OFF_ROWI  109841408UL  // f32 [8192] row 1/sum (normalization deferred to pv)
#define OFF_IPERM 109874176UL  // int [8192] inverse permutation
#define WS_NEEDED 109906944UL
#define CAP_S     25165824L

// aliased (early-lifetime) buffers inside the S region:
#define OFF_AHI   (OFF_S)                 // bf16 [8192][512]
#define OFF_ALO   (OFF_S + 8388608UL)
#define OFF_WKHI  (OFF_S + 16777216UL)    // bf16 [512][512] transposed
#define OFF_WKLO  (OFF_S + 17301504UL)
#define OFF_WVHI  (OFF_S + 17825792UL)
#define OFF_WVLO  (OFF_S + 18350080UL)
#define OFF_CW    (OFF_MASK)              // f64 [512][2] (dead before maskpack)

static __device__ __forceinline__ unsigned short f2bf_bits(float x) {
  __hip_bfloat16 h = __float2bfloat16(x);
  unsigned short u;
  __builtin_memcpy(&u, &h, 2);
  return u;
}
static __device__ __forceinline__ float bf_bits2f(unsigned short u) {
  __hip_bfloat16 h;
  __builtin_memcpy(&h, &u, 2);
  return __bfloat162float(h);
}

// Async 16B/lane global->LDS copy (global_load_lds_dwordx4). LDS side must be
// wave-uniform base + lane*16 — all call sites below satisfy this.
static __device__ __forceinline__ void async_copy16(const void* gptr,
                                                    void* lptr) {
  __builtin_amdgcn_global_load_lds(
      (const __attribute__((address_space(1))) unsigned int*)gptr,
      (__attribute__((address_space(3))) unsigned int*)lptr, 16, 0, 0);
}

// ---------------------------------------------------------------------------
// input f32 -> bf16 hi/lo split (hi = bf16(x), lo = bf16(x - hi))
// ---------------------------------------------------------------------------
__global__ __launch_bounds__(256) void convert_input(
    const float* __restrict__ A, __hip_bfloat16* __restrict__ Ahi,
    __hip_bfloat16* __restrict__ Alo) {
  const long idx = ((long)blockIdx.x * 256 + threadIdx.x) * 4;
  const float4 v = *(const float4*)&A[idx];
  const float vv[4] = {v.x, v.y, v.z, v.w};
  ushort4 hi, lo;
  unsigned short* hp = (unsigned short*)&hi;
  unsigned short* lp = (unsigned short*)&lo;
#pragma unroll
  for (int e = 0; e < 4; e++) {
    unsigned short h = f2bf_bits(vv[e]);
    hp[e] = h;
    lp[e] = f2bf_bits(vv[e] - bf_bits2f(h));
  }
  *(ushort4*)&Ahi[idx] = hi;
  *(ushort4*)&Alo[idx] = lo;
}

// ---------------------------------------------------------------------------
// W[k][n] f32 -> transposed bf16 hi/lo: WT[n][k]. z=0: kW, z=1: vW.
// ---------------------------------------------------------------------------
__global__ __launch_bounds__(256) void convert_w(
    const float* __restrict__ kW, const float* __restrict__ vW,
    __hip_bfloat16* __restrict__ WkhiT, __hip_bfloat16* __restrict__ WkloT,
    __hip_bfloat16* __restrict__ WvhiT, __hip_bfloat16* __restrict__ WvloT) {
  __shared__ float tile[64][65];
  const int z = blockIdx.z;
  const float* __restrict__ W = z ? vW : kW;
  __hip_bfloat16* __restrict__ HiT = z ? WvhiT : WkhiT;
  __hip_bfloat16* __restrict__ LoT = z ? WvloT : WkloT;
  const int k0 = blockIdx.x * 64, n0 = blockIdx.y * 64;
  const int t = threadIdx.x;
#pragma unroll
  for (int s = 0; s < 16; s++) {
    int idx = t + s * 256;
    int r = idx >> 6, c = idx & 63;
    tile[r][c] = W[(long)(k0 + r) * FEAT + n0 + c];
  }
  __syncthreads();
#pragma unroll
  for (int s = 0; s < 16; s++) {
    int idx = t + s * 256;
    int a = idx >> 6, b = idx & 63;
    float w = tile[b][a];
    unsigned short h = f2bf_bits(w);
    unsigned short l = f2bf_bits(w - bf_bits2f(h));
    __builtin_memcpy(&HiT[(long)(n0 + a) * FEAT + k0 + b], &h, 2);
    __builtin_memcpy(&LoT[(long)(n0 + a) * FEAT + k0 + b], &l, 2);
  }
}

// ---------------------------------------------------------------------------
// kh/vh = A@W via split-bf16 MFMA: Ahi*Whi + Ahi*Wlo + Alo*Whi (~f32 accurate)
// z=0: scatter bf16 rows directly to khp[iperm[r]] (gather_khp fused away).
// z=1: write vh f32 (needed for transpose+cmean).
// ---------------------------------------------------------------------------
__global__ __launch_bounds__(256) void mfma_dual(
    const __hip_bfloat16* __restrict__ Ahi, const __hip_bfloat16* __restrict__ Alo,
    const __hip_bfloat16* __restrict__ WkhiT, const __hip_bfloat16* __restrict__ WkloT,
    const __hip_bfloat16* __restrict__ WvhiT, const __hip_bfloat16* __restrict__ WvloT,
    const int* __restrict__ iperm, __hip_bfloat16* __restrict__ khp,
    float* __restrict__ vh) {
  const int z = blockIdx.z;
  const __hip_bfloat16* __restrict__ WhiT = z ? WvhiT : WkhiT;
  const __hip_bfloat16* __restrict__ WloT = z ? WvloT : WkloT;
  const int ti = blockIdx.x, tj = blockIdx.y;
  __shared__ __align__(16) __hip_bfloat16 Ah[128 * 32];
  __shared__ __align__(16) __hip_bfloat16 Al[128 * 32];
  __shared__ __align__(16) __hip_bfloat16 Wh[128 * 32];
  __shared__ __align__(16) __hip_bfloat16 Wl[128 * 32];
  const int t = threadIdx.x;
  const int lane = t & 63, w = t >> 6;
  const int wm = (w >> 1) * 64, wn = (w & 1) * 64;
  const int quad = lane >> 4, ln = lane & 15;
  const int qr = quad * 8;
  floatx4 acc[4][4];
#pragma unroll
  for (int mi = 0; mi < 4; mi++)
#pragma unroll
    for (int ni = 0; ni < 4; ni++) acc[mi][ni] = (floatx4)0.f;
  for (int k0 = 0; k0 < FEAT; k0 += 32) {
    __syncthreads();
#pragma unroll
    for (int s = 0; s < 2; s++) {
      int c = t + s * 256;
      int row = c >> 2, off8 = (c & 3) * 8;
      int lo = row * 32 + off8;  // LDS elem offset == 8c -> byte 16c
      async_copy16(&Ahi[(long)(ti * 128 + row) * FEAT + k0 + off8], &Ah[lo]);
      async_copy16(&Alo[(long)(ti * 128 + row) * FEAT + k0 + off8], &Al[lo]);
      async_copy16(&WhiT[(long)(tj * 128 + row) * FEAT + k0 + off8], &Wh[lo]);
      async_copy16(&WloT[(long)(tj * 128 + row) * FEAT + k0 + off8], &Wl[lo]);
    }
    __syncthreads();
    short8 ah[4], al[4], bh[4], bl[4];
#pragma unroll
    for (int mi = 0; mi < 4; mi++) {
      ah[mi] = *(const short8*)&Ah[(wm + mi * 16 + ln) * 32 + qr];
      al[mi] = *(const short8*)&Al[(wm + mi * 16 + ln) * 32 + qr];
    }
#pragma unroll
    for (int ni = 0; ni < 4; ni++) {
      bh[ni] = *(const short8*)&Wh[(wn + ni * 16 + ln) * 32 + qr];
      bl[ni] = *(const short8*)&Wl[(wn + ni * 16 + ln) * 32 + qr];
    }
#pragma unroll
    for (int mi = 0; mi < 4; mi++)
#pragma unroll
      for (int ni = 0; ni < 4; ni++) {
        acc[mi][ni] = __builtin_amdgcn_mfma_f32_16x16x32_bf16(
            ah[mi], bh[ni], acc[mi][ni], 0, 0, 0);
        acc[mi][ni] = __builtin_amdgcn_mfma_f32_16x16x32_bf16(
            ah[mi], bl[ni], acc[mi][ni], 0, 0, 0);
        acc[mi][ni] = __builtin_amdgcn_mfma_f32_16x16x32_bf16(
            al[mi], bh[ni], acc[mi][ni], 0, 0, 0);
      }
  }
  if (z == 0) {
#pragma unroll
    for (int mi = 0; mi < 4; mi++)
#pragma unroll
      for (int reg = 0; reg < 4; reg++) {
        int r = ti * 128 + wm + mi * 16 + quad * 4 + reg;
        long kr = (long)iperm[r] * FEAT;
#pragma unroll
        for (int ni = 0; ni < 4; ni++) {
          int cc = tj * 128 + wn + ni * 16 + ln;
          khp[kr + cc] = __float2bfloat16(acc[mi][ni][reg]);
        }
      }
  } else {
#pragma unroll
    for (int mi = 0; mi < 4; mi++)
#pragma unroll
      for (int ni = 0; ni < 4; ni++) {
        int cc = tj * 128 + wn + ni * 16 + ln;
#pragma unroll
        for (int reg = 0; reg < 4; reg++) {
          int r = ti * 128 + wm + mi * 16 + quad * 4 + reg;
          vh[(long)r * FEAT + cc] = acc[mi][ni][reg];
        }
      }
  }
}

// ---------------------------------------------------------------------------
// cw[f][b] = sum_h kW[f][h] * rot[h][b]  (fp64)
// ---------------------------------------------------------------------------
__global__ __launch_bounds__(64) void cw_kernel(
    const float* __restrict__ kW, const float* __restrict__ rot,
    double* __restrict__ cw) {
  const int f = blockIdx.x;
  const int lane = threadIdx.x;
  double r0 = 0.0, r1 = 0.0;
  for (int h = lane; h < FEAT; h += 64) {
    double a = (double)kW[(long)f * FEAT + h];
    r0 += a * (double)rot[2 * h];
    r1 += a * (double)rot[2 * h + 1];
  }
#pragma unroll
  for (int off = 32; off > 0; off >>= 1) {
    r0 += __shfl_down(r0, off);
    r1 += __shfl_down(r1, off);
  }
  if (lane == 0) {
    cw[2 * f] = r0;
    cw[2 * f + 1] = r1;
  }
}

// ---------------------------------------------------------------------------
// buckets from EXACT inputs: rv = input @ cw in fp64; argmax([r0,r1,-r0,-r1])
// ---------------------------------------------------------------------------
__global__ __launch_bounds__(64) void rv_bucket_kernel(
    const float* __restrict__ input, const double* __restrict__ cw,
    int* __restrict__ buckets) {
  const int i = blockIdx.x;
  const int lane = threadIdx.x;
  double r0 = 0.0, r1 = 0.0;
  for (int f = lane; f < FEAT; f += 64) {
    double a = (double)input[(long)i * FEAT + f];
    r0 += a * cw[2 * f];
    r1 += a * cw[2 * f + 1];
  }
#pragma unroll
  for (int off = 32; off > 0; off >>= 1) {
    r0 += __shfl_down(r0, off);
    r1 += __shfl_down(r1, off);
  }
  if (lane == 0) {
    int b = 0;
    double best = r0;
    if (r1 > best)  { best = r1;  b = 1; }
    if (-r0 > best) { best = -r0; b = 2; }
    if (-r1 > best) { best = -r1; b = 3; }
    buckets[i] = b;
  }
}

// ---------------------------------------------------------------------------
// Stable counting sort by bucket (1 block, parallel Hillis-Steele scan).
// Emits perm AND inverse perm. Also zeroes cmean.
// ---------------------------------------------------------------------------
__global__ __launch_bounds__(256) void sort_kernel(
    const int* __restrict__ buckets, int* __restrict__ perm,
    int* __restrict__ iperm, int* __restrict__ meta,
    float* __restrict__ cmean) {
  __shared__ int lc[4][256];
  __shared__ int sc[4][256];
  __shared__ int boff_sh[5];
  const int t = threadIdx.x;
  cmean[t] = 0.f;
  cmean[t + 256] = 0.f;
  const int base = t * 32;
  int c0 = 0, c1 = 0, c2 = 0, c3 = 0;
  for (int k = 0; k < 32; k++) {
    int b = buckets[base + k];
    c0 += (b == 0); c1 += (b == 1); c2 += (b == 2); c3 += (b == 3);
  }
  lc[0][t] = c0; lc[1][t] = c1; lc[2][t] = c2; lc[3][t] = c3;
  sc[0][t] = c0; sc[1][t] = c1; sc[2][t] = c2; sc[3][t] = c3;
  __syncthreads();
  for (int off = 1; off < 256; off <<= 1) {
    int a0 = (t >= off) ? sc[0][t - off] : 0;
    int a1 = (t >= off) ? sc[1][t - off] : 0;
    int a2 = (t >= off) ? sc[2][t - off] : 0;
    int a3 = (t >= off) ? sc[3][t - off] : 0;
    __syncthreads();
    sc[0][t] += a0; sc[1][t] += a1; sc[2][t] += a2; sc[3][t] += a3;
    __syncthreads();
  }
  if (t == 0) {
    int boff[5];
    boff[0] = 0;
    for (int b = 0; b < 4; b++) boff[b + 1] = boff[b] + sc[b][255];
    for (int b = 0; b < 5; b++) { meta[b] = boff[b]; boff_sh[b] = boff[b]; }
    long so = 0;
    int po = 0;
    for (int b = 0; b < 4; b++) {
      int tot = boff[b + 1] - boff[b];
      int pad = ((tot + 127) >> 7) << 7;
      meta[5 + b] = pad;
      meta[9 + b] = (int)so;
      meta[14 + b] = po;
      so += (long)pad * pad;
      po += pad;
    }
    meta[13] = (int)so;
    meta[18] = po;
    if (so > CAP_S)
      for (int b = 0; b < 4; b++) meta[5 + b] = 0;
  }
  __syncthreads();
  int s0 = boff_sh[0] + sc[0][t] - lc[0][t];
  int s1 = boff_sh[1] + sc[1][t] - lc[1][t];
  int s2 = boff_sh[2] + sc[2][t] - lc[2][t];
  int s3 = boff_sh[3] + sc[3][t] - lc[3][t];
  for (int k = 0; k < 32; k++) {
    int i = base + k;
    int b = buckets[i];
    int pos = (b == 0) ? s0++ : ((b == 1) ? s1++ : ((b == 2) ? s2++ : s3++));
    perm[pos] = i;
    iperm[i] = pos;
  }
}

// ---------------------------------------------------------------------------
// vhpT[f][poff_b + local] = bf16(vh[perm[boff_b + local]][f]); pads zeroed.
// Fused cmean column-sum accumulation (cmean pre-zeroed by sort_kernel).
// ---------------------------------------------------------------------------
__global__ __launch_bounds__(256) void transpose_vhpT_kernel(
    const float* __restrict__ vh, const int* __restrict__ perm,
    const int* __restrict__ meta, __hip_bfloat16* __restrict__ vhpT,
    float* __restrict__ cmean) {
  __shared__ float tile[64][65];
  __shared__ float cred[4][64];
  const int g0 = blockIdx.x * 64;
  const int f0 = blockIdx.y * 64;
  const int t = threadIdx.x;
#pragma unroll
  for (int s = 0; s < 16; s++) {
    int idx = t + s * 256;
    int r = idx >> 6, c = idx & 63;
    int pos = g0 + r;
    int b = (pos >= meta[15]) + (pos >= meta[16]) + (pos >= meta[17]);
    int local = pos - meta[14 + b];
    int n_b = meta[b + 1] - meta[b];
    float v = 0.f;
    if (local < n_b) v = vh[(long)perm[meta[b] + local] * FEAT + f0 + c];
    tile[r][c] = v;
  }
  __syncthreads();
  {
    const int c = t & 63, seg = t >> 6;
    float ps = 0.f;
#pragma unroll
    for (int rr = 0; rr < 16; rr++) ps += tile[seg * 16 + rr][c];
    cred[seg][c] = ps;
  }
  __syncthreads();
  if (t < 64)
    atomicAdd(&cmean[f0 + t],
              cred[0][t] + cred[1][t] + cred[2][t] + cred[3][t]);
#pragma unroll
  for (int s = 0; s < 16; s++) {
    int idx = t + s * 256;
    int fr = idx >> 6, gc = idx & 63;
    vhpT[(long)(f0 + fr) * VHPT_W + g0 + gc] = __float2bfloat16(tile[gc][fr]);
  }
}

// ---------------------------------------------------------------------------
// maskbits[g][jj] = (adj[perm[g]][perm[boff_b+jj]] > 0), bit-packed per 64.
// ---------------------------------------------------------------------------
__global__ __launch_bounds__(256) void maskpack_kernel(
    const int* __restrict__ adj, const int* __restrict__ perm,
    const int* __restrict__ meta, unsigned long long* __restrict__ maskbits) {
  __shared__ int adj_lds[N_NODES];
  const int g = blockIdx.x;
  const int t = threadIdx.x;
  const int b = (g >= meta[1]) + (g >= meta[2]) + (g >= meta[3]);
  const int boff = meta[b];
  const int n_b = meta[b + 1] - boff;
  const int padded = meta[5 + b];
  const int i = perm[g];
  const int* arow = adj + (long)i * N_NODES;
#pragma unroll
  for (int s = 0; s < 8; s++) {
    int idx = (t + s * 256) * 4;
    *(int4*)&adj_lds[idx] = *(const int4*)&arow[idx];
  }
  __syncthreads();
  const int lane = t & 63, w = t >> 6;
  for (int jj0 = w * 64; jj0 < padded; jj0 += 256) {
    int jj = jj0 + lane;
    int pred = 0;
    if (jj < n_b) pred = adj_lds[perm[boff + jj]] > 0;
    unsigned long long mword = __ballot(pred);
    if (lane == 0) maskbits[(long)g * 128 + (jj0 >> 6)] = mword;
  }
}

// ---------------------------------------------------------------------------
// S tile = khp_b . khp_b^T (bf16 MFMA, async staging, BK=64 dual-panel).
// SYMMETRY: triangular-linearized grid covers ti <= tj only; epilogue routes
// acc through an LDS tile and writes BOTH orientations with coalesced 16B
// stores, applying the orientation-specific mask via u16 bit-selects.
// ---------------------------------------------------------------------------
__global__ __launch_bounds__(256) void s_gemm(
    const __hip_bfloat16* __restrict__ khp, const int* __restrict__ meta,
    const unsigned long long* __restrict__ maskbits,
    __hip_bfloat16* __restrict__ S) {
  const int b = blockIdx.z;
  const int padded = meta[5 + b];
  const int T = padded >> 7;
  const int pairs = (T * (T + 1)) >> 1;
  int L = blockIdx.x;
  if (L >= pairs) return;
  int ti = 0;
  while (L >= T - ti) { L -= T - ti; ti++; }
  const int tj = ti + L;
  const int boff = meta[b];
  const long soff = meta[9 + b];
  // 34,816 B: As/Bs (2 panels x 8 KB each) during main loop; Ct[128][136].
  __shared__ __align__(16) __hip_bfloat16 smem[128 * 136];
  __hip_bfloat16* As = smem;                  // [2][128*32]
  __hip_bfloat16* Bs = smem + 2 * 128 * 32;   // [2][128*32]
  const int t = threadIdx.x;
  const int lane = t & 63, w = t >> 6;
  const int wm = (w >> 1) * 64, wn = (w & 1) * 64;
  const int quad = lane >> 4, ln = lane & 15;
  const int qr = quad * 8;
  floatx4 acc[4][4];
#pragma unroll
  for (int mi = 0; mi < 4; mi++)
#pragma unroll
    for (int ni = 0; ni < 4; ni++) acc[mi][ni] = (floatx4)0.f;
  const long a_g0 = boff + ti * 128;
  const long b_g0 = boff + tj * 128;
  for (int k0 = 0; k0 < FEAT; k0 += 64) {
    __syncthreads();
#pragma unroll
    for (int p = 0; p < 2; p++)
#pragma unroll
      for (int s = 0; s < 2; s++) {
        int c = t + s * 256;
        int row = c >> 2, off8 = (c & 3) * 8;
        int lo = p * 4096 + row * 32 + off8;  // wave-uniform + lane*16
        async_copy16(&khp[(a_g0 + row) * FEAT + k0 + p * 32 + off8], &As[lo]);
        async_copy16(&khp[(b_g0 + row) * FEAT + k0 + p * 32 + off8], &Bs[lo]);
      }
    __syncthreads();
#pragma unroll
    for (int p = 0; p < 2; p++) {
      short8 af[4], bfr[4];
#pragma unroll
      for (int mi = 0; mi < 4; mi++)
        af[mi] =
            *(const short8*)&As[p * 4096 + (wm + mi * 16 + ln) * 32 + qr];
#pragma unroll
      for (int ni = 0; ni < 4; ni++)
        bfr[ni] =
            *(const short8*)&Bs[p * 4096 + (wn + ni * 16 + ln) * 32 + qr];
#pragma unroll
      for (int mi = 0; mi < 4; mi++)
#pragma unroll
        for (int ni = 0; ni < 4; ni++)
          acc[mi][ni] = __builtin_amdgcn_mfma_f32_16x16x32_bf16(
              af[mi], bfr[ni], acc[mi][ni], 0, 0, 0);
    }
  }
  // ---- epilogue: acc -> LDS tile (scaled bf16, unmasked) ----
  const float scale = 0.04419417382415922f;  // 1/sqrt(512)
  __syncthreads();  // As/Bs dead; reuse as Ct
  __hip_bfloat16* Ct = smem;  // [128][136]
#pragma unroll
  for (int mi = 0; mi < 4; mi++)
#pragma unroll
    for (int ni = 0; ni < 4; ni++) {
      int col = wn + ni * 16 + ln;
#pragma unroll
      for (int reg = 0; reg < 4; reg++) {
        int row = wm + mi * 16 + quad * 4 + reg;
        Ct[row * 136 + col] = __float2bfloat16(acc[mi][ni][reg] * scale);
      }
    }
  __syncthreads();
  const unsigned short negb = f2bf_bits(NEGV);
  // normal orientation: coalesced 16B stores of rows of the ti-block
#pragma unroll
  for (int i = 0; i < 8; i++) {
    int idx = t + i * 256;
    int rl = idx >> 4, c8 = (idx & 15) * 8;
    int rg = ti * 128 + rl;
    int cg = tj * 128 + c8;
    union { short8 v; unsigned short u[8]; } pk;
    pk.v = *(const short8*)&Ct[rl * 136 + c8];
    unsigned long long wbits = maskbits[(long)(boff + rg) * 128 + (cg >> 6)];
#pragma unroll
    for (int e = 0; e < 8; e++)
      if (!((wbits >> ((cg & 63) + e)) & 1ULL)) pk.u[e] = negb;
    *(short8*)&S[soff + (long)rg * padded + cg] = pk.v;
  }
  // mirrored orientation (tj-block rows), skipped on diagonal
  if (ti != tj) {
#pragma unroll
    for (int i = 0; i < 8; i++) {
      int idx = t + i * 256;
      int cl = idx >> 4, r8 = (idx & 15) * 8;
      int rg = tj * 128 + cl;   // output row (column of the computed tile)
      int cg = ti * 128 + r8;   // output col base
      union { short8 v; unsigned short u[8]; } pk;
#pragma unroll
      for (int e = 0; e < 8; e++) {
        __hip_bfloat16 hv = Ct[(r8 + e) * 136 + cl];
        __builtin_memcpy(&pk.u[e], &hv, 2);
      }
      unsigned long long wbits = maskbits[(long)(boff + rg) * 128 + (cg >> 6)];
#pragma unroll
      for (int e = 0; e < 8; e++)
        if (!((wbits >> ((cg & 63) + e)) & 1ULL)) pk.u[e] = negb;
      *(short8*)&S[soff + (long)rg * padded + cg] = pk.v;
    }
  }
}

// ---------------------------------------------------------------------------
// Softmax, normalization deferred: pass 1 = row max; pass 2 = store
// P~ = bf16(exp(S - m)) in place and accumulate sum -> rowinv = 1/sum.
// The 1/sum scale is applied in pv_gemm's f32 epilogue (exact algebra).
// ONE WAVE PER ROW (4 rows/block), row (~16 KB) stays L1-hot across passes.
// Empty rows: flag only (their P~ garbage is discarded via the cmean path).
// ---------------------------------------------------------------------------
__global__ __launch_bounds__(256) void softmax2_kernel(
    __hip_bfloat16* __restrict__ S, const int* __restrict__ meta,
    int* __restrict__ flags, float* __restrict__ rowinv) {
  const int g = blockIdx.x * 4 + (threadIdx.x >> 6);
  const int lane = threadIdx.x & 63;
  const int b = (g >= meta[1]) + (g >= meta[2]) + (g >= meta[3]);
  const int boff = meta[b];
  const int padded = meta[5 + b];
  const long soff = meta[9 + b];
  __hip_bfloat16* row = S + soff + (long)(g - boff) * padded;
  // pass 1: row max
  float m = -INFINITY;
  for (int j0 = lane * 8; j0 < padded; j0 += 512) {
    union { short8 v; unsigned short u[8]; } pk;
    pk.v = *(const short8*)&row[j0];
#pragma unroll
    for (int e = 0; e < 8; e++) m = fmaxf(m, bf_bits2f(pk.u[e]));
  }
#pragma unroll
  for (int off = 32; off > 0; off >>= 1) m = fmaxf(m, __shfl_xor(m, off));
  if (m < -8e15f) {  // empty (or degenerate) row
    if (lane == 0) { flags[g] = 1; rowinv[g] = 0.f; }
    return;
  }
  // pass 2: store unnormalized exp, accumulate sum (row L1-hot from pass 1)
  float sum = 0.f;
  for (int j0 = lane * 8; j0 < padded; j0 += 512) {
    union { short8 v; unsigned short u[8]; } pk;
    pk.v = *(const short8*)&row[j0];
#pragma unroll
    for (int e = 0; e < 8; e++) {
      float p = expf(bf_bits2f(pk.u[e]) - m);
      sum += p;
      pk.u[e] = f2bf_bits(p);
    }
    *(short8*)&row[j0] = pk.v;
  }
#pragma unroll
  for (int off = 32; off > 0; off >>= 1) sum += __shfl_xor(sum, off);
  if (lane == 0) { flags[g] = 0; rowinv[g] = 1.f / sum; }
}

// ---------------------------------------------------------------------------
// O tile = P~ . vhp (pure bf16 GEMM), 64 rows x 128 features per block
// (4 f-blocks -> S read 4x instead of 8x). BK=64 dual-panel async staging.
// Epilogue: x rowinv (deferred softmax denom) + ELU + empty-row fallback +
// scatter to out[perm[g]].
// ---------------------------------------------------------------------------
__global__ __launch_bounds__(256) void pv_gemm(
    const __hip_bfloat16* __restrict__ S, const __hip_bfloat16* __restrict__ vhpT,
    const int* __restrict__ meta, const int* __restrict__ perm,
    const int* __restrict__ flags, const float* __restrict__ cmean,
    const float* __restrict__ rowinv, float* __restrict__ out) {
  const int b = blockIdx.z;
  const int padded = meta[5 + b];
  const int ti = blockIdx.x;
  if (ti * 64 >= padded) return;
  const int boff = meta[b];
  const int n_b = meta[b + 1] - boff;
  const long soff = meta[9 + b];
  const int poff = meta[14 + b];
  const int f0 = blockIdx.y * 128;
  __shared__ __align__(16) __hip_bfloat16 As[2 * 64 * 32];
  __shared__ __align__(16) __hip_bfloat16 Bs[2 * 128 * 32];
  const int t = threadIdx.x;
  const int lane = t & 63, w = t >> 6;
  const int wm = (w >> 1) * 32, wn = (w & 1) * 64;
  const int quad = lane >> 4, ln = lane & 15;
  const int qr = quad * 8;
  floatx4 acc[2][4];
#pragma unroll
  for (int mi = 0; mi < 2; mi++)
#pragma unroll
    for (int ni = 0; ni < 4; ni++) acc[mi][ni] = (floatx4)0.f;
  const long r0 = (long)ti * 64;
  for (int k0 = 0; k0 < padded; k0 += 64) {
    __syncthreads();
#pragma unroll
    for (int p = 0; p < 2; p++) {
      {
        int row = t >> 2, off8 = (t & 3) * 8;
        async_copy16(&S[soff + (r0 + row) * padded + k0 + p * 32 + off8],
                     &As[p * 2048 + row * 32 + off8]);
      }
#pragma unroll
      for (int s = 0; s < 2; s++) {
        int c = t + s * 256;
        int row = c >> 2, off8 = (c & 3) * 8;
        async_copy16(
            &vhpT[(long)(f0 + row) * VHPT_W + poff + k0 + p * 32 + off8],
            &Bs[p * 4096 + row * 32 + off8]);
      }
    }
    __syncthreads();
#pragma unroll
    for (int p = 0; p < 2; p++) {
      short8 af[2], bfr[4];
#pragma unroll
      for (int mi = 0; mi < 2; mi++)
        af[mi] = *(const short8*)&As[p * 2048 + (wm + mi * 16 + ln) * 32 + qr];
#pragma unroll
      for (int ni = 0; ni < 4; ni++)
        bfr[ni] = *(const short8*)&Bs[p * 4096 + (wn + ni * 16 + ln) * 32 + qr];
#pragma unroll
      for (int mi = 0; mi < 2; mi++)
#pragma unroll
        for (int ni = 0; ni < 4; ni++)
          acc[mi][ni] = __builtin_amdgcn_mfma_f32_16x16x32_bf16(
              af[mi], bfr[ni], acc[mi][ni], 0, 0, 0);
    }
  }
#pragma unroll
  for (int mi = 0; mi < 2; mi++) {
#pragma unroll
    for (int reg = 0; reg < 4; reg++) {
      int r = ti * 64 + wm + mi * 16 + quad * 4 + reg;
      if (r < n_b) {
        int g = boff + r;
        int node = perm[g];
        int fl = flags[g];
        float inv = rowinv[g];
#pragma unroll
        for (int ni = 0; ni < 4; ni++) {
          int fc = f0 + wn + ni * 16 + ln;
          float v = fl ? cmean[fc] * (1.f / (float)N_NODES)
                       : acc[mi][ni][reg] * inv;
          v = v > 0.f ? v : expm1f(v);
          out[(long)node * FEAT + fc] = v;
        }
      }
    }
  }
}

// ===========================================================================
// Slow-path fallback (only if ws_size < WS_NEEDED): round-1 implementation.
// ===========================================================================
__global__ __launch_bounds__(256) void gemm_dual(
    const float* __restrict__ A, const float* __restrict__ Wk,
    const float* __restrict__ Wv, float* __restrict__ kh,
    float* __restrict__ vh) {
  __shared__ float As[32][33];
  __shared__ float Bk[32][33];
  __shared__ float Bv[32][33];
  const int tid = threadIdx.x;
  const int row0 = blockIdx.x * 32;
  const int col0 = blockIdx.y * 32;
  const int tx = tid & 15, ty = tid >> 4;
  float ck00 = 0.f, ck01 = 0.f, ck10 = 0.f, ck11 = 0.f;
  float cv00 = 0.f, cv01 = 0.f, cv10 = 0.f, cv11 = 0.f;
  for (int kt = 0; kt < FEAT; kt += 32) {
#pragma unroll
    for (int t = 0; t < 4; t++) {
      int e = tid + t * 256;
      int r = e >> 5, c = e & 31;
      As[r][c] = A[(long)(row0 + r) * FEAT + kt + c];
      Bk[r][c] = Wk[(long)(kt + r) * FEAT + col0 + c];
      Bv[r][c] = Wv[(long)(kt + r) * FEAT + col0 + c];
    }
    __syncthreads();
#pragma unroll
    for (int kk = 0; kk < 32; kk++) {
      float a0 = As[ty * 2][kk], a1 = As[ty * 2 + 1][kk];
      float bk0 = Bk[kk][tx * 2], bk1 = Bk[kk][tx * 2 + 1];
      float bv0 = Bv[kk][tx * 2], bv1 = Bv[kk][tx * 2 + 1];
      ck00 += a0 * bk0; ck01 += a0 * bk1;
      ck10 += a1 * bk0; ck11 += a1 * bk1;
      cv00 += a0 * bv0; cv01 += a0 * bv1;
      cv10 += a1 * bv0; cv11 += a1 * bv1;
    }
    __syncthreads();
  }
  const int r0 = row0 + ty * 2, c0 = col0 + tx * 2;
  kh[(long)r0 * FEAT + c0] = ck00;       kh[(long)r0 * FEAT + c0 + 1] = ck01;
  kh[(long)(r0 + 1) * FEAT + c0] = ck10; kh[(long)(r0 + 1) * FEAT + c0 + 1] = ck11;
  vh[(long)r0 * FEAT + c0] = cv00;       vh[(long)r0 * FEAT + c0 + 1] = cv01;
  vh[(long)(r0 + 1) * FEAT + c0] = cv10; vh[(long)(r0 + 1) * FEAT + c0 + 1] = cv11;
}

__global__ __launch_bounds__(64) void bucket_kernel(
    const float* __restrict__ kh, const float* __restrict__ rot,
    int* __restrict__ buckets) {
  const int i = blockIdx.x;
  const int lane = threadIdx.x;
  double r0 = 0.0, r1 = 0.0;
  for (int h = lane; h < FEAT; h += 64) {
    double a = (double)kh[(long)i * FEAT + h];
    r0 += a * (double)rot[2 * h];
    r1 += a * (double)rot[2 * h + 1];
  }
#pragma unroll
  for (int off = 32; off > 0; off >>= 1) {
    r0 += __shfl_down(r0, off);
    r1 += __shfl_down(r1, off);
  }
  if (lane == 0) {
    int b = 0;
    double best = r0;
    if (r1 > best)  { best = r1;  b = 1; }
    if (-r0 > best) { best = -r0; b = 2; }
    if (-r1 > best) { best = -r1; b = 3; }
    buckets[i] = b;
  }
}

__global__ __launch_bounds__(256) void attn_kernel(
    const float* __restrict__ kh, const float* __restrict__ vh,
    const int* __restrict__ adj, const int* __restrict__ buckets,
    float* __restrict__ out) {
  __shared__ float khi[FEAT];
  __shared__ float pbuf[N_NODES];
  __shared__ unsigned short jlist[N_NODES];
  __shared__ int cnt_sh;
  __shared__ float red[256];
  const int i = blockIdx.x;
  const int tid = threadIdx.x;
  if (tid == 0) cnt_sh = 0;
  for (int k = tid; k < FEAT; k += 256) khi[k] = kh[(long)i * FEAT + k];
  const int mybucket = buckets[i];
  __syncthreads();
  const int* adjrow = adj + (long)i * N_NODES;
  for (int j = tid; j < N_NODES; j += 256) {
    if (adjrow[j] > 0 && buckets[j] == mybucket) {
      int idx = atomicAdd(&cnt_sh, 1);
      jlist[idx] = (unsigned short)j;
    }
  }
  __syncthreads();
  const int cnt = cnt_sh;
  float mloc = -INFINITY;
  for (int idx = tid; idx < cnt; idx += 256) {
    int j = jlist[idx];
    const float4* kj = (const float4*)(kh + (long)j * FEAT);
    const float4* ki = (const float4*)khi;
    float acc = 0.f;
#pragma unroll 8
    for (int k = 0; k < FEAT / 4; k++) {
      float4 a = ki[k];
      float4 b = kj[k];
      acc += a.x * b.x + a.y * b.y + a.z * b.z + a.w * b.w;
    }
    float s = acc * 0.04419417382415922f;
    pbuf[idx] = s;
    mloc = fmaxf(mloc, s);
  }
  red[tid] = mloc;
  __syncthreads();
#pragma unroll
  for (int off = 128; off > 0; off >>= 1) {
    if (tid < off) red[tid] = fmaxf(red[tid], red[tid + off]);
    __syncthreads();
  }
  const float m = red[0];
  __syncthreads();
  float lloc = 0.f;
  for (int idx = tid; idx < cnt; idx += 256) {
    float p = expf(pbuf[idx] - m);
    pbuf[idx] = p;
    lloc += p;
  }
  red[tid] = lloc;
  __syncthreads();
#pragma unroll
  for (int off = 128; off > 0; off >>= 1) {
    if (tid < off) red[tid] += red[tid + off];
    __syncthreads();
  }
  const float l = red[0];
  __syncthreads();
  const int f = 2 * tid;
  float acc0 = 0.f, acc1 = 0.f;
  if (cnt > 0) {
#pragma unroll 4
    for (int idx = 0; idx < cnt; idx++) {
      int j = jlist[idx];
      float p = pbuf[idx];
      float2 v = *(const float2*)(vh + (long)j * FEAT + f);
      acc0 += p * v.x;
      acc1 += p * v.y;
    }
    float invl = 1.f / l;
    acc0 *= invl;
    acc1 *= invl;
  } else {
    for (int j = 0; j < N_NODES; j++) {
      float2 v = *(const float2*)(vh + (long)j * FEAT + f);
      acc0 += v.x;
      acc1 += v.y;
    }
    acc0 *= (1.f / (float)N_NODES);
    acc1 *= (1.f / (float)N_NODES);
  }
  acc0 = acc0 > 0.f ? acc0 : expm1f(acc0);
  acc1 = acc1 > 0.f ? acc1 : expm1f(acc1);
  *(float2*)(out + (long)i * FEAT + f) = make_float2(acc0, acc1);
}

extern "C" void kernel_launch(void* const* d_in, const int* in_sizes, int n_in,
                              void* d_out, int out_size, void* d_ws,
                              size_t ws_size, hipStream_t stream) {
  const float* input = (const float*)d_in[0];
  const int* adj = (const int*)d_in[1];
  const float* rot = (const float*)d_in[2];
  const float* kW = (const float*)d_in[3];
  const float* vW = (const float*)d_in[4];
  float* out = (float*)d_out;

  char* ws = (char*)d_ws;

  if (ws_size >= WS_NEEDED) {
    float* vh = (float*)(ws + OFF_VH);
    __hip_bfloat16* khp = (__hip_bfloat16*)(ws + OFF_KHP);
    __hip_bfloat16* vhpT = (__hip_bfloat16*)(ws + OFF_VHPT);
    unsigned long long* maskbits = (unsigned long long*)(ws + OFF_MASK);
    __hip_bfloat16* S = (__hip_bfloat16*)(ws + OFF_S);
    int* perm = (int*)(ws + OFF_PERM);
    int* iperm = (int*)(ws + OFF_IPERM);
    int* flags = (int*)(ws + OFF_FLAGS);
    int* buckets = (int*)(ws + OFF_BUCK);
    int* meta = (int*)(ws + OFF_META);
    float* cmean = (float*)(ws + OFF_CMEAN);
    float* rowinv = (float*)(ws + OFF_ROWI);
    __hip_bfloat16* Ahi = (__hip_bfloat16*)(ws + OFF_AHI);
    __hip_bfloat16* Alo = (__hip_bfloat16*)(ws + OFF_ALO);
    __hip_bfloat16* WkhiT = (__hip_bfloat16*)(ws + OFF_WKHI);
    __hip_bfloat16* WkloT = (__hip_bfloat16*)(ws + OFF_WKLO);
    __hip_bfloat16* WvhiT = (__hip_bfloat16*)(ws + OFF_WVHI);
    __hip_bfloat16* WvloT = (__hip_bfloat16*)(ws + OFF_WVLO);
    double* cw = (double*)(ws + OFF_CW);

    // zero khp tail rows [8192, 8320) — read (masked) by s_gemm/pv when the
    // last bucket's padding spills past N.
    hipMemsetAsync(ws + OFF_KHP + (size_t)N_NODES * FEAT * 2, 0,
                   128 * FEAT * 2, stream);
    convert_input<<<4096, 256, 0, stream>>>(input, Ahi, Alo);
    convert_w<<<dim3(8, 8, 2), 256, 0, stream>>>(kW, vW, WkhiT, WkloT, WvhiT,
                                                 WvloT);
    cw_kernel<<<512, 64, 0, stream>>>(kW, rot, cw);
    rv_bucket_kernel<<<N_NODES, 64, 0, stream>>>(input, cw, buckets);
    sort_kernel<<<1, 256, 0, stream>>>(buckets, perm, iperm, meta, cmean);
    mfma_dual<<<dim3(64, 4, 2), 256, 0, stream>>>(Ahi, Alo, WkhiT, WkloT,
                                                  WvhiT, WvloT, iperm, khp,
                                                  vh);
    transpose_vhpT_kernel<<<dim3(VHPT_W / 64, FEAT / 64), 256, 0, stream>>>(
        vh, perm, meta, vhpT, cmean);
    maskpack_kernel<<<N_NODES, 256, 0, stream>>>(adj, perm, meta, maskbits);
    s_gemm<<<dim3(2080, 1, 4), 256, 0, stream>>>(khp, meta, maskbits, S);
    softmax2_kernel<<<N_NODES / 4, 256, 0, stream>>>(S, meta, flags, rowinv);
    pv_gemm<<<dim3(128, 4, 4), 256, 0, stream>>>(S, vhpT, meta, perm, flags,
                                                 cmean, rowinv, out);
  } else {
    float* kh = (float*)(ws + 0UL);
    float* vh = (float*)(ws + 16777216UL);
    int* buckets = (int*)(ws + 33554432UL);
    dim3 gemm_grid(N_NODES / 32, FEAT / 32);
    gemm_dual<<<gemm_grid, 256, 0, stream>>>(input, kW, vW, kh, vh);
    bucket_kernel<<<N_NODES, 64, 0, stream>>>(kh, rot, buckets);
    attn_kernel<<<N_NODES, 256, 0, stream>>>(kh, vh, adj, buckets, out);
  }
}

// Round 3
// 581.681 us; speedup vs baseline: 1.1620x; 1.0230x over previous
//
#include <hip/hip_runtime.h>
#include <hip/hip_bf16.h>
#include <math.h>

#define N_NODES 8192
#define FEAT 512
#define NEGV -9e15f
#define VHPT_W 8704

typedef __attribute__((ext_vector_type(8))) short short8;
typedef __attribute__((ext_vector_type(4))) float floatx4;

// ---- workspace layout (bytes) ----
#define OFF_KH    0UL          // (dead in fast path; kept for layout stability)
#define OFF_VH    16777216UL   // f32 vh [8192][512]
#define OFF_KHP   33554432UL   // bf16 [8320][512]
#define OFF_VHPT  42074112UL   // bf16 [512][8704]  (padded-position columns)
#define OFF_MASK  50987008UL   // u64 [8192][128]; head reused early for cw (f64[1024])
#define OFF_S     59375616UL   // bf16 S, cap 25165824 elems; head reused early for Ahi/Alo/W*T
#define OFF_PERM  109707264UL
#define OFF_FLAGS 109740032UL  // (unused this round)
#define OFF_BUCK  109772800UL
#define OFF_META  109805568UL  // ints: [0..4]=boff [5..8]=padded [9..13]=soff(+tot) [14..18]=poff
#define OFF_CMEAN 109806592UL
#define OFF_ROWM  109808640UL  // (unused this round)
#define OFF_ROWI  109841408UL  // f32 [8192] row sum of stored P~ (exp(S), masked->0)
#define OFF_IPERM 109874176UL  // int [8192] inverse permutation
#define WS_NEEDED 109906944UL
#define CAP_S     25165824L

// aliased (early-lifetime) buffers inside the S region:
#define OFF_AHI   (OFF_S)                 // bf16 [8192][512]
#define OFF_ALO   (OFF_S + 8388608UL)
#define OFF_WKHI  (OFF_S + 16777216UL)    // bf16 [512][512] transposed
#define OFF_WKLO  (OFF_S + 17301504UL)
#define OFF_WVHI  (OFF_S + 17825792UL)
#define OFF_WVLO  (OFF_S + 18350080UL)
#define OFF_CW    (OFF_MASK)              // f64 [512][2] (dead before maskpack)

static __device__ __forceinline__ unsigned short f2bf_bits(float x) {
  __hip_bfloat16 h = __float2bfloat16(x);
  unsigned short u;
  __builtin_memcpy(&u, &h, 2);
  return u;
}
static __device__ __forceinline__ float bf_bits2f(unsigned short u) {
  __hip_bfloat16 h;
  __builtin_memcpy(&h, &u, 2);
  return __bfloat162float(h);
}

// Async 16B/lane global->LDS copy (global_load_lds_dwordx4). LDS side must be
// wave-uniform base + lane*16 — all call sites below satisfy this.
static __device__ __forceinline__ void async_copy16(const void* gptr,
                                                    void* lptr) {
  __builtin_amdgcn_global_load_lds(
      (const __attribute__((address_space(1))) unsigned int*)gptr,
      (__attribute__((address_space(3))) unsigned int*)lptr, 16, 0, 0);
}

// ---------------------------------------------------------------------------
// input f32 -> bf16 hi/lo split (hi = bf16(x), lo = bf16(x - hi))
// ---------------------------------------------------------------------------
__global__ __launch_bounds__(256) void convert_input(
    const float* __restrict__ A, __hip_bfloat16* __restrict__ Ahi,
    __hip_bfloat16* __restrict__ Alo) {
  const long idx = ((long)blockIdx.x * 256 + threadIdx.x) * 4;
  const float4 v = *(const float4*)&A[idx];
  const float vv[4] = {v.x, v.y, v.z, v.w};
  ushort4 hi, lo;
  unsigned short* hp = (unsigned short*)&hi;
  unsigned short* lp = (unsigned short*)&lo;
#pragma unroll
  for (int e = 0; e < 4; e++) {
    unsigned short h = f2bf_bits(vv[e]);
    hp[e] = h;
    lp[e] = f2bf_bits(vv[e] - bf_bits2f(h));
  }
  *(ushort4*)&Ahi[idx] = hi;
  *(ushort4*)&Alo[idx] = lo;
}

// ---------------------------------------------------------------------------
// W[k][n] f32 -> transposed bf16 hi/lo: WT[n][k]. z=0: kW, z=1: vW.
// ---------------------------------------------------------------------------
__global__ __launch_bounds__(256) void convert_w(
    const float* __restrict__ kW, const float* __restrict__ vW,
    __hip_bfloat16* __restrict__ WkhiT, __hip_bfloat16* __restrict__ WkloT,
    __hip_bfloat16* __restrict__ WvhiT, __hip_bfloat16* __restrict__ WvloT) {
  __shared__ float tile[64][65];
  const int z = blockIdx.z;
  const float* __restrict__ W = z ? vW : kW;
  __hip_bfloat16* __restrict__ HiT = z ? WvhiT : WkhiT;
  __hip_bfloat16* __restrict__ LoT = z ? WvloT : WkloT;
  const int k0 = blockIdx.x * 64, n0 = blockIdx.y * 64;
  const int t = threadIdx.x;
#pragma unroll
  for (int s = 0; s < 16; s++) {
    int idx = t + s * 256;
    int r = idx >> 6, c = idx & 63;
    tile[r][c] = W[(long)(k0 + r) * FEAT + n0 + c];
  }
  __syncthreads();
#pragma unroll
  for (int s = 0; s < 16; s++) {
    int idx = t + s * 256;
    int a = idx >> 6, b = idx & 63;
    float w = tile[b][a];
    unsigned short h = f2bf_bits(w);
    unsigned short l = f2bf_bits(w - bf_bits2f(h));
    __builtin_memcpy(&HiT[(long)(n0 + a) * FEAT + k0 + b], &h, 2);
    __builtin_memcpy(&LoT[(long)(n0 + a) * FEAT + k0 + b], &l, 2);
  }
}

// ---------------------------------------------------------------------------
// kh/vh = A@W via split-bf16 MFMA: Ahi*Whi + Ahi*Wlo + Alo*Whi (~f32 accurate)
// z=0: acc -> LDS tile -> coalesced 16B row stores scattered to khp[iperm[r]]
//      (gather_khp fused; rows scattered but each row is a 256B run).
// z=1: write vh f32 (needed for transpose+cmean).
// ---------------------------------------------------------------------------
__global__ __launch_bounds__(256) void mfma_dual(
    const __hip_bfloat16* __restrict__ Ahi, const __hip_bfloat16* __restrict__ Alo,
    const __hip_bfloat16* __restrict__ WkhiT, const __hip_bfloat16* __restrict__ WkloT,
    const __hip_bfloat16* __restrict__ WvhiT, const __hip_bfloat16* __restrict__ WvloT,
    const int* __restrict__ iperm, __hip_bfloat16* __restrict__ khp,
    float* __restrict__ vh) {
  const int z = blockIdx.z;
  const __hip_bfloat16* __restrict__ WhiT = z ? WvhiT : WkhiT;
  const __hip_bfloat16* __restrict__ WloT = z ? WvloT : WkloT;
  const int ti = blockIdx.x, tj = blockIdx.y;
  // 34,816 B union: 4 staging panels (4 x 8 KB) during main loop; Ct[128][136]
  // for the z==0 epilogue transpose.
  __shared__ __align__(16) __hip_bfloat16 smem[128 * 136];
  __hip_bfloat16* Ah = smem;
  __hip_bfloat16* Al = smem + 4096;
  __hip_bfloat16* Wh = smem + 8192;
  __hip_bfloat16* Wl = smem + 12288;
  const int t = threadIdx.x;
  const int lane = t & 63, w = t >> 6;
  const int wm = (w >> 1) * 64, wn = (w & 1) * 64;
  const int quad = lane >> 4, ln = lane & 15;
  const int qr = quad * 8;
  floatx4 acc[4][4];
#pragma unroll
  for (int mi = 0; mi < 4; mi++)
#pragma unroll
    for (int ni = 0; ni < 4; ni++) acc[mi][ni] = (floatx4)0.f;
  for (int k0 = 0; k0 < FEAT; k0 += 32) {
    __syncthreads();
#pragma unroll
    for (int s = 0; s < 2; s++) {
      int c = t + s * 256;
      int row = c >> 2, off8 = (c & 3) * 8;
      int lo = row * 32 + off8;  // LDS elem offset == 8c -> byte 16c
      async_copy16(&Ahi[(long)(ti * 128 + row) * FEAT + k0 + off8], &Ah[lo]);
      async_copy16(&Alo[(long)(ti * 128 + row) * FEAT + k0 + off8], &Al[lo]);
      async_copy16(&WhiT[(long)(tj * 128 + row) * FEAT + k0 + off8], &Wh[lo]);
      async_copy16(&WloT[(long)(tj * 128 + row) * FEAT + k0 + off8], &Wl[lo]);
    }
    __syncthreads();
    short8 ah[4], al[4], bh[4], bl[4];
#pragma unroll
    for (int mi = 0; mi < 4; mi++) {
      ah[mi] = *(const short8*)&Ah[(wm + mi * 16 + ln) * 32 + qr];
      al[mi] = *(const short8*)&Al[(wm + mi * 16 + ln) * 32 + qr];
    }
#pragma unroll
    for (int ni = 0; ni < 4; ni++) {
      bh[ni] = *(const short8*)&Wh[(wn + ni * 16 + ln) * 32 + qr];
      bl[ni] = *(const short8*)&Wl[(wn + ni * 16 + ln) * 32 + qr];
    }
#pragma unroll
    for (int mi = 0; mi < 4; mi++)
#pragma unroll
      for (int ni = 0; ni < 4; ni++) {
        acc[mi][ni] = __builtin_amdgcn_mfma_f32_16x16x32_bf16(
            ah[mi], bh[ni], acc[mi][ni], 0, 0, 0);
        acc[mi][ni] = __builtin_amdgcn_mfma_f32_16x16x32_bf16(
            ah[mi], bl[ni], acc[mi][ni], 0, 0, 0);
        acc[mi][ni] = __builtin_amdgcn_mfma_f32_16x16x32_bf16(
            al[mi], bh[ni], acc[mi][ni], 0, 0, 0);
      }
  }
  if (z == 0) {
    // route through LDS so the scattered-row stores are 16B-coalesced
    __syncthreads();
    __hip_bfloat16* Ct = smem;  // [128][136]
#pragma unroll
    for (int mi = 0; mi < 4; mi++)
#pragma unroll
      for (int ni = 0; ni < 4; ni++) {
        int col = wn + ni * 16 + ln;
#pragma unroll
        for (int reg = 0; reg < 4; reg++) {
          int row = wm + mi * 16 + quad * 4 + reg;
          Ct[row * 136 + col] = __float2bfloat16(acc[mi][ni][reg]);
        }
      }
    __syncthreads();
#pragma unroll
    for (int i = 0; i < 8; i++) {
      int idx = t + i * 256;
      int rl = idx >> 4, c8 = (idx & 15) * 8;
      int gr = iperm[ti * 128 + rl];
      *(short8*)&khp[(long)gr * FEAT + tj * 128 + c8] =
          *(const short8*)&Ct[rl * 136 + c8];
    }
  } else {
#pragma unroll
    for (int mi = 0; mi < 4; mi++)
#pragma unroll
      for (int ni = 0; ni < 4; ni++) {
        int cc = tj * 128 + wn + ni * 16 + ln;
#pragma unroll
        for (int reg = 0; reg < 4; reg++) {
          int r = ti * 128 + wm + mi * 16 + quad * 4 + reg;
          vh[(long)r * FEAT + cc] = acc[mi][ni][reg];
        }
      }
  }
}

// ---------------------------------------------------------------------------
// cw[f][b] = sum_h kW[f][h] * rot[h][b]  (fp64)
// ---------------------------------------------------------------------------
__global__ __launch_bounds__(64) void cw_kernel(
    const float* __restrict__ kW, const float* __restrict__ rot,
    double* __restrict__ cw) {
  const int f = blockIdx.x;
  const int lane = threadIdx.x;
  double r0 = 0.0, r1 = 0.0;
  for (int h = lane; h < FEAT; h += 64) {
    double a = (double)kW[(long)f * FEAT + h];
    r0 += a * (double)rot[2 * h];
    r1 += a * (double)rot[2 * h + 1];
  }
#pragma unroll
  for (int off = 32; off > 0; off >>= 1) {
    r0 += __shfl_down(r0, off);
    r1 += __shfl_down(r1, off);
  }
  if (lane == 0) {
    cw[2 * f] = r0;
    cw[2 * f + 1] = r1;
  }
}

// ---------------------------------------------------------------------------
// buckets from EXACT inputs: rv = input @ cw in fp64; argmax([r0,r1,-r0,-r1])
// ---------------------------------------------------------------------------
__global__ __launch_bounds__(64) void rv_bucket_kernel(
    const float* __restrict__ input, const double* __restrict__ cw,
    int* __restrict__ buckets) {
  const int i = blockIdx.x;
  const int lane = threadIdx.x;
  double r0 = 0.0, r1 = 0.0;
  for (int f = lane; f < FEAT; f += 64) {
    double a = (double)input[(long)i * FEAT + f];
    r0 += a * cw[2 * f];
    r1 += a * cw[2 * f + 1];
  }
#pragma unroll
  for (int off = 32; off > 0; off >>= 1) {
    r0 += __shfl_down(r0, off);
    r1 += __shfl_down(r1, off);
  }
  if (lane == 0) {
    int b = 0;
    double best = r0;
    if (r1 > best)  { best = r1;  b = 1; }
    if (-r0 > best) { best = -r0; b = 2; }
    if (-r1 > best) { best = -r1; b = 3; }
    buckets[i] = b;
  }
}

// ---------------------------------------------------------------------------
// Stable counting sort by bucket (1 block, parallel Hillis-Steele scan).
// Emits perm AND inverse perm. Also zeroes cmean and rowsum.
// ---------------------------------------------------------------------------
__global__ __launch_bounds__(256) void sort_kernel(
    const int* __restrict__ buckets, int* __restrict__ perm,
    int* __restrict__ iperm, int* __restrict__ meta,
    float* __restrict__ cmean, float* __restrict__ rowsum) {
  __shared__ int lc[4][256];
  __shared__ int sc[4][256];
  __shared__ int boff_sh[5];
  const int t = threadIdx.x;
  cmean[t] = 0.f;
  cmean[t + 256] = 0.f;
  for (int k = t; k < N_NODES; k += 256) rowsum[k] = 0.f;
  const int base = t * 32;
  int c0 = 0, c1 = 0, c2 = 0, c3 = 0;
  for (int k = 0; k < 32; k++) {
    int b = buckets[base + k];
    c0 += (b == 0); c1 += (b == 1); c2 += (b == 2); c3 += (b == 3);
  }
  lc[0][t] = c0; lc[1][t] = c1; lc[2][t] = c2; lc[3][t] = c3;
  sc[0][t] = c0; sc[1][t] = c1; sc[2][t] = c2; sc[3][t] = c3;
  __syncthreads();
  for (int off = 1; off < 256; off <<= 1) {
    int a0 = (t >= off) ? sc[0][t - off] : 0;
    int a1 = (t >= off) ? sc[1][t - off] : 0;
    int a2 = (t >= off) ? sc[2][t - off] : 0;
    int a3 = (t >= off) ? sc[3][t - off] : 0;
    __syncthreads();
    sc[0][t] += a0; sc[1][t] += a1; sc[2][t] += a2; sc[3][t] += a3;
    __syncthreads();
  }
  if (t == 0) {
    int boff[5];
    boff[0] = 0;
    for (int b = 0; b < 4; b++) boff[b + 1] = boff[b] + sc[b][255];
    for (int b = 0; b < 5; b++) { meta[b] = boff[b]; boff_sh[b] = boff[b]; }
    long so = 0;
    int po = 0;
    for (int b = 0; b < 4; b++) {
      int tot = boff[b + 1] - boff[b];
      int pad = ((tot + 127) >> 7) << 7;
      meta[5 + b] = pad;
      meta[9 + b] = (int)so;
      meta[14 + b] = po;
      so += (long)pad * pad;
      po += pad;
    }
    meta[13] = (int)so;
    meta[18] = po;
    if (so > CAP_S)
      for (int b = 0; b < 4; b++) meta[5 + b] = 0;
  }
  __syncthreads();
  int s0 = boff_sh[0] + sc[0][t] - lc[0][t];
  int s1 = boff_sh[1] + sc[1][t] - lc[1][t];
  int s2 = boff_sh[2] + sc[2][t] - lc[2][t];
  int s3 = boff_sh[3] + sc[3][t] - lc[3][t];
  for (int k = 0; k < 32; k++) {
    int i = base + k;
    int b = buckets[i];
    int pos = (b == 0) ? s0++ : ((b == 1) ? s1++ : ((b == 2) ? s2++ : s3++));
    perm[pos] = i;
    iperm[i] = pos;
  }
}

// ---------------------------------------------------------------------------
// vhpT[f][poff_b + local] = bf16(vh[perm[boff_b + local]][f]); pads zeroed.
// Fused cmean column-sum accumulation (cmean pre-zeroed by sort_kernel).
// ---------------------------------------------------------------------------
__global__ __launch_bounds__(256) void transpose_vhpT_kernel(
    const float* __restrict__ vh, const int* __restrict__ perm,
    const int* __restrict__ meta, __hip_bfloat16* __restrict__ vhpT,
    float* __restrict__ cmean) {
  __shared__ float tile[64][65];
  __shared__ float cred[4][64];
  const int g0 = blockIdx.x * 64;
  const int f0 = blockIdx.y * 64;
  const int t = threadIdx.x;
#pragma unroll
  for (int s = 0; s < 16; s++) {
    int idx = t + s * 256;
    int r = idx >> 6, c = idx & 63;
    int pos = g0 + r;
    int b = (pos >= meta[15]) + (pos >= meta[16]) + (pos >= meta[17]);
    int local = pos - meta[14 + b];
    int n_b = meta[b + 1] - meta[b];
    float v = 0.f;
    if (local < n_b) v = vh[(long)perm[meta[b] + local] * FEAT + f0 + c];
    tile[r][c] = v;
  }
  __syncthreads();
  {
    const int c = t & 63, seg = t >> 6;
    float ps = 0.f;
#pragma unroll
    for (int rr = 0; rr < 16; rr++) ps += tile[seg * 16 + rr][c];
    cred[seg][c] = ps;
  }
  __syncthreads();
  if (t < 64)
    atomicAdd(&cmean[f0 + t],
              cred[0][t] + cred[1][t] + cred[2][t] + cred[3][t]);
#pragma unroll
  for (int s = 0; s < 16; s++) {
    int idx = t + s * 256;
    int fr = idx >> 6, gc = idx & 63;
    vhpT[(long)(f0 + fr) * VHPT_W + g0 + gc] = __float2bfloat16(tile[gc][fr]);
  }
}

// ---------------------------------------------------------------------------
// maskbits[g][jj] = (adj[perm[g]][perm[boff_b+jj]] > 0), bit-packed per 64.
// ---------------------------------------------------------------------------
__global__ __launch_bounds__(256) void maskpack_kernel(
    const int* __restrict__ adj, const int* __restrict__ perm,
    const int* __restrict__ meta, unsigned long long* __restrict__ maskbits) {
  __shared__ int adj_lds[N_NODES];
  const int g = blockIdx.x;
  const int t = threadIdx.x;
  const int b = (g >= meta[1]) + (g >= meta[2]) + (g >= meta[3]);
  const int boff = meta[b];
  const int n_b = meta[b + 1] - boff;
  const int padded = meta[5 + b];
  const int i = perm[g];
  const int* arow = adj + (long)i * N_NODES;
#pragma unroll
  for (int s = 0; s < 8; s++) {
    int idx = (t + s * 256) * 4;
    *(int4*)&adj_lds[idx] = *(const int4*)&arow[idx];
  }
  __syncthreads();
  const int lane = t & 63, w = t >> 6;
  for (int jj0 = w * 64; jj0 < padded; jj0 += 256) {
    int jj = jj0 + lane;
    int pred = 0;
    if (jj < n_b) pred = adj_lds[perm[boff + jj]] > 0;
    unsigned long long mword = __ballot(pred);
    if (lane == 0) maskbits[(long)g * 128 + (jj0 >> 6)] = mword;
  }
}

// ---------------------------------------------------------------------------
// S tile = khp_b . khp_b^T (bf16 MFMA, async staging, BK=64 dual-panel).
// FUSED NO-MAX SOFTMAX NUMERATOR: epilogue stores P~ = bf16(exp(S/sqrt(H)))
// (masked -> 0) and accumulates f32 row sums of the stored values via 16-lane
// shfl reduce + one atomicAdd per (row, tile). Scores here are bounded
// (max ~ ||kh||^2/sqrt(512) ~ 50 << 88), so exp cannot overflow f32, and
// exp(S)/sum(exp(S)) == softmax exactly (the max shift cancels).
// SYMMETRY: triangular grid covers ti <= tj; both orientations written from
// an LDS tile with coalesced 16B stores. Pad rows (rg >= n_b) are excluded
// from the row-sum atomics (they'd alias the NEXT bucket's rows).
// ---------------------------------------------------------------------------
__global__ __launch_bounds__(256) void s_gemm(
    const __hip_bfloat16* __restrict__ khp, const int* __restrict__ meta,
    const unsigned long long* __restrict__ maskbits,
    __hip_bfloat16* __restrict__ S, float* __restrict__ rowsum) {
  const int b = blockIdx.z;
  const int padded = meta[5 + b];
  const int T = padded >> 7;
  const int pairs = (T * (T + 1)) >> 1;
  int L = blockIdx.x;
  if (L >= pairs) return;
  int ti = 0;
  while (L >= T - ti) { L -= T - ti; ti++; }
  const int tj = ti + L;
  const int boff = meta[b];
  const int n_b = meta[b + 1] - boff;
  const long soff = meta[9 + b];
  // 34,816 B: As/Bs (2 panels x 8 KB each) during main loop; Ct[128][136].
  __shared__ __align__(16) __hip_bfloat16 smem[128 * 136];
  __hip_bfloat16* As = smem;                  // [2][128*32]
  __hip_bfloat16* Bs = smem + 2 * 128 * 32;   // [2][128*32]
  const int t = threadIdx.x;
  const int lane = t & 63, w = t >> 6;
  const int wm = (w >> 1) * 64, wn = (w & 1) * 64;
  const int quad = lane >> 4, ln = lane & 15;
  const int qr = quad * 8;
  floatx4 acc[4][4];
#pragma unroll
  for (int mi = 0; mi < 4; mi++)
#pragma unroll
    for (int ni = 0; ni < 4; ni++) acc[mi][ni] = (floatx4)0.f;
  const long a_g0 = boff + ti * 128;
  const long b_g0 = boff + tj * 128;
  for (int k0 = 0; k0 < FEAT; k0 += 64) {
    __syncthreads();
#pragma unroll
    for (int p = 0; p < 2; p++)
#pragma unroll
      for (int s = 0; s < 2; s++) {
        int c = t + s * 256;
        int row = c >> 2, off8 = (c & 3) * 8;
        int lo = p * 4096 + row * 32 + off8;  // wave-uniform + lane*16
        async_copy16(&khp[(a_g0 + row) * FEAT + k0 + p * 32 + off8], &As[lo]);
        async_copy16(&khp[(b_g0 + row) * FEAT + k0 + p * 32 + off8], &Bs[lo]);
      }
    __syncthreads();
#pragma unroll
    for (int p = 0; p < 2; p++) {
      short8 af[4], bfr[4];
#pragma unroll
      for (int mi = 0; mi < 4; mi++)
        af[mi] =
            *(const short8*)&As[p * 4096 + (wm + mi * 16 + ln) * 32 + qr];
#pragma unroll
      for (int ni = 0; ni < 4; ni++)
        bfr[ni] =
            *(const short8*)&Bs[p * 4096 + (wn + ni * 16 + ln) * 32 + qr];
#pragma unroll
      for (int mi = 0; mi < 4; mi++)
#pragma unroll
        for (int ni = 0; ni < 4; ni++)
          acc[mi][ni] = __builtin_amdgcn_mfma_f32_16x16x32_bf16(
              af[mi], bfr[ni], acc[mi][ni], 0, 0, 0);
    }
  }
  // ---- epilogue: P~ = bf16(exp(acc*scale)) -> LDS tile (unmasked) ----
  const float scale = 0.04419417382415922f;  // 1/sqrt(512)
  __syncthreads();  // As/Bs dead; reuse as Ct
  __hip_bfloat16* Ct = smem;  // [128][136]
#pragma unroll
  for (int mi = 0; mi < 4; mi++)
#pragma unroll
    for (int ni = 0; ni < 4; ni++) {
      int col = wn + ni * 16 + ln;
#pragma unroll
      for (int reg = 0; reg < 4; reg++) {
        int row = wm + mi * 16 + quad * 4 + reg;
        Ct[row * 136 + col] = __float2bfloat16(expf(acc[mi][ni][reg] * scale));
      }
    }
  __syncthreads();
  // normal orientation: coalesced 16B stores of rows of the ti-block
#pragma unroll
  for (int i = 0; i < 8; i++) {
    int idx = t + i * 256;
    int rl = idx >> 4, c8 = (idx & 15) * 8;
    int rg = ti * 128 + rl;
    int cg = tj * 128 + c8;
    union { short8 v; unsigned short u[8]; } pk;
    pk.v = *(const short8*)&Ct[rl * 136 + c8];
    unsigned long long wbits = maskbits[(long)(boff + rg) * 128 + (cg >> 6)];
    float ps = 0.f;
#pragma unroll
    for (int e = 0; e < 8; e++) {
      if (!((wbits >> ((cg & 63) + e)) & 1ULL)) pk.u[e] = 0;
      ps += bf_bits2f(pk.u[e]);
    }
    *(short8*)&S[soff + (long)rg * padded + cg] = pk.v;
    // per-row partial sum: 16 consecutive lanes share rg
#pragma unroll
    for (int off = 1; off < 16; off <<= 1) ps += __shfl_xor(ps, off);
    if (rg < n_b && (lane & 15) == 0)
      atomicAdd(&rowsum[boff + rg], ps);
  }
  // mirrored orientation (tj-block rows), skipped on diagonal
  if (ti != tj) {
#pragma unroll
    for (int i = 0; i < 8; i++) {
      int idx = t + i * 256;
      int cl = idx >> 4, r8 = (idx & 15) * 8;
      int rg = tj * 128 + cl;   // output row (column of the computed tile)
      int cg = ti * 128 + r8;   // output col base
      union { short8 v; unsigned short u[8]; } pk;
#pragma unroll
      for (int e = 0; e < 8; e++) {
        __hip_bfloat16 hv = Ct[(r8 + e) * 136 + cl];
        __builtin_memcpy(&pk.u[e], &hv, 2);
      }
      unsigned long long wbits = maskbits[(long)(boff + rg) * 128 + (cg >> 6)];
      float ps = 0.f;
#pragma unroll
      for (int e = 0; e < 8; e++) {
        if (!((wbits >> ((cg & 63) + e)) & 1ULL)) pk.u[e] = 0;
        ps += bf_bits2f(pk.u[e]);
      }
      *(short8*)&S[soff + (long)rg * padded + cg] = pk.v;
#pragma unroll
      for (int off = 1; off < 16; off <<= 1) ps += __shfl_xor(ps, off);
      if (rg < n_b && (lane & 15) == 0)
        atomicAdd(&rowsum[boff + rg], ps);
    }
  }
}

// ---------------------------------------------------------------------------
// O tile = P~ . vhp (pure bf16 GEMM), 64 rows x 128 features per block.
// BK=64 dual-panel async staging. Epilogue: x (1/rowsum) (softmax denom,
// exact) + ELU + empty-row (rowsum==0) cmean fallback + scatter to
// out[perm[g]].
// ---------------------------------------------------------------------------
__global__ __launch_bounds__(256) void pv_gemm(
    const __hip_bfloat16* __restrict__ S, const __hip_bfloat16* __restrict__ vhpT,
    const int* __restrict__ meta, const int* __restrict__ perm,
    const float* __restrict__ cmean, const float* __restrict__ rowsum,
    float* __restrict__ out) {
  const int b = blockIdx.z;
  const int padded = meta[5 + b];
  const int ti = blockIdx.x;
  if (ti * 64 >= padded) return;
  const int boff = meta[b];
  const int n_b = meta[b + 1] - boff;
  const long soff = meta[9 + b];
  const int poff = meta[14 + b];
  const int f0 = blockIdx.y * 128;
  __shared__ __align__(16) __hip_bfloat16 As[2 * 64 * 32];
  __shared__ __align__(16) __hip_bfloat16 Bs[2 * 128 * 32];
  const int t = threadIdx.x;
  const int lane = t & 63, w = t >> 6;
  const int wm = (w >> 1) * 32, wn = (w & 1) * 64;
  const int quad = lane >> 4, ln = lane & 15;
  const int qr = quad * 8;
  floatx4 acc[2][4];
#pragma unroll
  for (int mi = 0; mi < 2; mi++)
#pragma unroll
    for (int ni = 0; ni < 4; ni++) acc[mi][ni] = (floatx4)0.f;
  const long r0 = (long)ti * 64;
  for (int k0 = 0; k0 < padded; k0 += 64) {
    __syncthreads();
#pragma unroll
    for (int p = 0; p < 2; p++) {
      {
        int row = t >> 2, off8 = (t & 3) * 8;
        async_copy16(&S[soff + (r0 + row) * padded + k0 + p * 32 + off8],
                     &As[p * 2048 + row * 32 + off8]);
      }
#pragma unroll
      for (int s = 0; s < 2; s++) {
        int c = t + s * 256;
        int row = c >> 2, off8 = (c & 3) * 8;
        async_copy16(
            &vhpT[(long)(f0 + row) * VHPT_W + poff + k0 + p * 32 + off8],
            &Bs[p * 4096 + row * 32 + off8]);
      }
    }
    __syncthreads();
#pragma unroll
    for (int p = 0; p < 2; p++) {
      short8 af[2], bfr[4];
#pragma unroll
      for (int mi = 0; mi < 2; mi++)
        af[mi] = *(const short8*)&As[p * 2048 + (wm + mi * 16 + ln) * 32 + qr];
#pragma unroll
      for (int ni = 0; ni < 4; ni++)
        bfr[ni] = *(const short8*)&Bs[p * 4096 + (wn + ni * 16 + ln) * 32 + qr];
#pragma unroll
      for (int mi = 0; mi < 2; mi++)
#pragma unroll
        for (int ni = 0; ni < 4; ni++)
          acc[mi][ni] = __builtin_amdgcn_mfma_f32_16x16x32_bf16(
              af[mi], bfr[ni], acc[mi][ni], 0, 0, 0);
    }
  }
#pragma unroll
  for (int mi = 0; mi < 2; mi++) {
#pragma unroll
    for (int reg = 0; reg < 4; reg++) {
      int r = ti * 64 + wm + mi * 16 + quad * 4 + reg;
      if (r < n_b) {
        int g = boff + r;
        int node = perm[g];
        float rs = rowsum[g];
        int fl = (rs == 0.f);
        float inv = fl ? 0.f : 1.f / rs;
#pragma unroll
        for (int ni = 0; ni < 4; ni++) {
          int fc = f0 + wn + ni * 16 + ln;
          float v = fl ? cmean[fc] * (1.f / (float)N_NODES)
                       : acc[mi][ni][reg] * inv;
          v = v > 0.f ? v : expm1f(v);
          out[(long)node * FEAT + fc] = v;
        }
      }
    }
  }
}

// ===========================================================================
// Slow-path fallback (only if ws_size < WS_NEEDED): round-1 implementation.
// ===========================================================================
__global__ __launch_bounds__(256) void gemm_dual(
    const float* __restrict__ A, const float* __restrict__ Wk,
    const float* __restrict__ Wv, float* __restrict__ kh,
    float* __restrict__ vh) {
  __shared__ float As[32][33];
  __shared__ float Bk[32][33];
  __shared__ float Bv[32][33];
  const int tid = threadIdx.x;
  const int row0 = blockIdx.x * 32;
  const int col0 = blockIdx.y * 32;
  const int tx = tid & 15, ty = tid >> 4;
  float ck00 = 0.f, ck01 = 0.f, ck10 = 0.f, ck11 = 0.f;
  float cv00 = 0.f, cv01 = 0.f, cv10 = 0.f, cv11 = 0.f;
  for (int kt = 0; kt < FEAT; kt += 32) {
#pragma unroll
    for (int t = 0; t < 4; t++) {
      int e = tid + t * 256;
      int r = e >> 5, c = e & 31;
      As[r][c] = A[(long)(row0 + r) * FEAT + kt + c];
      Bk[r][c] = Wk[(long)(kt + r) * FEAT + col0 + c];
      Bv[r][c] = Wv[(long)(kt + r) * FEAT + col0 + c];
    }
    __syncthreads();
#pragma unroll
    for (int kk = 0; kk < 32; kk++) {
      float a0 = As[ty * 2][kk], a1 = As[ty * 2 + 1][kk];
      float bk0 = Bk[kk][tx * 2], bk1 = Bk[kk][tx * 2 + 1];
      float bv0 = Bv[kk][tx * 2], bv1 = Bv[kk][tx * 2 + 1];
      ck00 += a0 * bk0; ck01 += a0 * bk1;
      ck10 += a1 * bk0; ck11 += a1 * bk1;
      cv00 += a0 * bv0; cv01 += a0 * bv1;
      cv10 += a1 * bv0; cv11 += a1 * bv1;
    }
    __syncthreads();
  }
  const int r0 = row0 + ty * 2, c0 = col0 + tx * 2;
  kh[(long)r0 * FEAT + c0] = ck00;       kh[(long)r0 * FEAT + c0 + 1] = ck01;
  kh[(long)(r0 + 1) * FEAT + c0] = ck10; kh[(long)(r0 + 1) * FEAT + c0 + 1] = ck11;
  vh[(long)r0 * FEAT + c0] = cv00;       vh[(long)r0 * FEAT + c0 + 1] = cv01;
  vh[(long)(r0 + 1) * FEAT + c0] = cv10; vh[(long)(r0 + 1) * FEAT + c0 + 1] = cv11;
}

__global__ __launch_bounds__(64) void bucket_kernel(
    const float* __restrict__ kh, const float* __restrict__ rot,
    int* __restrict__ buckets) {
  const int i = blockIdx.x;
  const int lane = threadIdx.x;
  double r0 = 0.0, r1 = 0.0;
  for (int h = lane; h < FEAT; h += 64) {
    double a = (double)kh[(long)i * FEAT + h];
    r0 += a * (double)rot[2 * h];
    r1 += a * (double)rot[2 * h + 1];
  }
#pragma unroll
  for (int off = 32; off > 0; off >>= 1) {
    r0 += __shfl_down(r0, off);
    r1 += __shfl_down(r1, off);
  }
  if (lane == 0) {
    int b = 0;
    double best = r0;
    if (r1 > best)  { best = r1;  b = 1; }
    if (-r0 > best) { best = -r0; b = 2; }
    if (-r1 > best) { best = -r1; b = 3; }
    buckets[i] = b;
  }
}

__global__ __launch_bounds__(256) void attn_kernel(
    const float* __restrict__ kh, const float* __restrict__ vh,
    const int* __restrict__ adj, const int* __restrict__ buckets,
    float* __restrict__ out) {
  __shared__ float khi[FEAT];
  __shared__ float pbuf[N_NODES];
  __shared__ unsigned short jlist[N_NODES];
  __shared__ int cnt_sh;
  __shared__ float red[256];
  const int i = blockIdx.x;
  const int tid = threadIdx.x;
  if (tid == 0) cnt_sh = 0;
  for (int k = tid; k < FEAT; k += 256) khi[k] = kh[(long)i * FEAT + k];
  const int mybucket = buckets[i];
  __syncthreads();
  const int* adjrow = adj + (long)i * N_NODES;
  for (int j = tid; j < N_NODES; j += 256) {
    if (adjrow[j] > 0 && buckets[j] == mybucket) {
      int idx = atomicAdd(&cnt_sh, 1);
      jlist[idx] = (unsigned short)j;
    }
  }
  __syncthreads();
  const int cnt = cnt_sh;
  float mloc = -INFINITY;
  for (int idx = tid; idx < cnt; idx += 256) {
    int j = jlist[idx];
    const float4* kj = (const float4*)(kh + (long)j * FEAT);
    const float4* ki = (const float4*)khi;
    float acc = 0.f;
#pragma unroll 8
    for (int k = 0; k < FEAT / 4; k++) {
      float4 a = ki[k];
      float4 b = kj[k];
      acc += a.x * b.x + a.y * b.y + a.z * b.z + a.w * b.w;
    }
    float s = acc * 0.04419417382415922f;
    pbuf[idx] = s;
    mloc = fmaxf(mloc, s);
  }
  red[tid] = mloc;
  __syncthreads();
#pragma unroll
  for (int off = 128; off > 0; off >>= 1) {
    if (tid < off) red[tid] = fmaxf(red[tid], red[tid + off]);
    __syncthreads();
  }
  const float m = red[0];
  __syncthreads();
  float lloc = 0.f;
  for (int idx = tid; idx < cnt; idx += 256) {
    float p = expf(pbuf[idx] - m);
    pbuf[idx] = p;
    lloc += p;
  }
  red[tid] = lloc;
  __syncthreads();
#pragma unroll
  for (int off = 128; off > 0; off >>= 1) {
    if (tid < off) red[tid] += red[tid + off];
    __syncthreads();
  }
  const float l = red[0];
  __syncthreads();
  const int f = 2 * tid;
  float acc0 = 0.f, acc1 = 0.f;
  if (cnt > 0) {
#pragma unroll 4
    for (int idx = 0; idx < cnt; idx++) {
      int j = jlist[idx];
      float p = pbuf[idx];
      float2 v = *(const float2*)(vh + (long)j * FEAT + f);
      acc0 += p * v.x;
      acc1 += p * v.y;
    }
    float invl = 1.f / l;
    acc0 *= invl;
    acc1 *= invl;
  } else {
    for (int j = 0; j < N_NODES; j++) {
      float2 v = *(const float2*)(vh + (long)j * FEAT + f);
      acc0 += v.x;
      acc1 += v.y;
    }
    acc0 *= (1.f / (float)N_NODES);
    acc1 *= (1.f / (float)N_NODES);
  }
  acc0 = acc0 > 0.f ? acc0 : expm1f(acc0);
  acc1 = acc1 > 0.f ? acc1 : expm1f(acc1);
  *(float2*)(out + (long)i * FEAT + f) = make_float2(acc0, acc1);
}

extern "C" void kernel_launch(void* const* d_in, const int* in_sizes, int n_in,
                              void* d_out, int out_size, void* d_ws,
                              size_t ws_size, hipStream_t stream) {
  const float* input = (const float*)d_in[0];
  const int* adj = (const int*)d_in[1];
  const float* rot = (const float*)d_in[2];
  const float* kW = (const float*)d_in[3];
  const float* vW = (const float*)d_in[4];
  float* out = (float*)d_out;

  char* ws = (char*)d_ws;

  if (ws_size >= WS_NEEDED) {
    float* vh = (float*)(ws + OFF_VH);
    __hip_bfloat16* khp = (__hip_bfloat16*)(ws + OFF_KHP);
    __hip_bfloat16* vhpT = (__hip_bfloat16*)(ws + OFF_VHPT);
    unsigned long long* maskbits = (unsigned long long*)(ws + OFF_MASK);
    __hip_bfloat16* S = (__hip_bfloat16*)(ws + OFF_S);
    int* perm = (int*)(ws + OFF_PERM);
    int* iperm = (int*)(ws + OFF_IPERM);
    int* buckets = (int*)(ws + OFF_BUCK);
    int* meta = (int*)(ws + OFF_META);
    float* cmean = (float*)(ws + OFF_CMEAN);
    float* rowsum = (float*)(ws + OFF_ROWI);
    __hip_bfloat16* Ahi = (__hip_bfloat16*)(ws + OFF_AHI);
    __hip_bfloat16* Alo = (__hip_bfloat16*)(ws + OFF_ALO);
    __hip_bfloat16* WkhiT = (__hip_bfloat16*)(ws + OFF_WKHI);
    __hip_bfloat16* WkloT = (__hip_bfloat16*)(ws + OFF_WKLO);
    __hip_bfloat16* WvhiT = (__hip_bfloat16*)(ws + OFF_WVHI);
    __hip_bfloat16* WvloT = (__hip_bfloat16*)(ws + OFF_WVLO);
    double* cw = (double*)(ws + OFF_CW);

    // zero khp tail rows [8192, 8320) — read (masked) by s_gemm/pv when the
    // last bucket's padding spills past N.
    hipMemsetAsync(ws + OFF_KHP + (size_t)N_NODES * FEAT * 2, 0,
                   128 * FEAT * 2, stream);
    convert_input<<<4096, 256, 0, stream>>>(input, Ahi, Alo);
    convert_w<<<dim3(8, 8, 2), 256, 0, stream>>>(kW, vW, WkhiT, WkloT, WvhiT,
                                                 WvloT);
    cw_kernel<<<512, 64, 0, stream>>>(kW, rot, cw);
    rv_bucket_kernel<<<N_NODES, 64, 0, stream>>>(input, cw, buckets);
    sort_kernel<<<1, 256, 0, stream>>>(buckets, perm, iperm, meta, cmean,
                                       rowsum);
    mfma_dual<<<dim3(64, 4, 2), 256, 0, stream>>>(Ahi, Alo, WkhiT, WkloT,
                                                  WvhiT, WvloT, iperm, khp,
                                                  vh);
    transpose_vhpT_kernel<<<dim3(VHPT_W / 64, FEAT / 64), 256, 0, stream>>>(
        vh, perm, meta, vhpT, cmean);
    maskpack_kernel<<<N_NODES, 256, 0, stream>>>(adj, perm, meta, maskbits);
    s_gemm<<<dim3(2080, 1, 4), 256, 0, stream>>>(khp, meta, maskbits, S,
                                                 rowsum);
    pv_gemm<<<dim3(128, 4, 4), 256, 0, stream>>>(S, vhpT, meta, perm, cmean,
                                                 rowsum, out);
  } else {
    float* kh = (float*)(ws + 0UL);
    float* vh = (float*)(ws + 16777216UL);
    int* buckets = (int*)(ws + 33554432UL);
    dim3 gemm_grid(N_NODES / 32, FEAT / 32);
    gemm_dual<<<gemm_grid, 256, 0, stream>>>(input, kW, vW, kh, vh);
    bucket_kernel<<<N_NODES, 64, 0, stream>>>(kh, rot, buckets);
    attn_kernel<<<N_NODES, 256, 0, stream>>>(kh, vh, adj, buckets, out);
  }
}

// Round 4
// 566.288 us; speedup vs baseline: 1.1936x; 1.0272x over previous
//
#include <hip/hip_runtime.h>
#include <hip/hip_bf16.h>
#include <math.h>

#define N_NODES 8192
#define FEAT 512
#define NEGV -9e15f
#define VHPT_W 8704

typedef __attribute__((ext_vector_type(8))) short short8;
typedef __attribute__((ext_vector_type(4))) float floatx4;

// ---- workspace layout (bytes) ----
#define OFF_KH    0UL          // (dead in fast path; kept for layout stability)
#define OFF_VH    16777216UL   // f32 vh [8192][512]
#define OFF_KHP   33554432UL   // bf16 [8320][512]
#define OFF_VHPT  42074112UL   // bf16 [512][8704]  (padded-position columns)
#define OFF_MASK  50987008UL   // u64 [8192][128]; head reused early for cw (f64[1024])
#define OFF_S     59375616UL   // bf16 S, cap 25165824 elems; head reused early for Ahi/Alo/W*T
#define OFF_PERM  109707264UL
#define OFF_FLAGS 109740032UL  // (unused)
#define OFF_BUCK  109772800UL
#define OFF_META  109805568UL  // ints: [0..4]=boff [5..8]=padded [9..13]=soff(+tot) [14..18]=poff
#define OFF_CMEAN 109806592UL
#define OFF_ROWM  109808640UL  // (unused)
#define OFF_ROWI  109841408UL  // f32 [8192] row sum of stored P~ (exp(S), masked->0)
#define OFF_IPERM 109874176UL  // int [8192] inverse permutation
#define WS_NEEDED 109906944UL
#define CAP_S     25165824L

// aliased (early-lifetime) buffers inside the S region:
#define OFF_AHI   (OFF_S)                 // bf16 [8192][512]
#define OFF_ALO   (OFF_S + 8388608UL)
#define OFF_WKHI  (OFF_S + 16777216UL)    // bf16 [512][512] transposed
#define OFF_WKLO  (OFF_S + 17301504UL)
#define OFF_WVHI  (OFF_S + 17825792UL)
#define OFF_WVLO  (OFF_S + 18350080UL)
#define OFF_CW    (OFF_MASK)              // f64 [512][2] (dead before maskpack)

static __device__ __forceinline__ unsigned short f2bf_bits(float x) {
  __hip_bfloat16 h = __float2bfloat16(x);
  unsigned short u;
  __builtin_memcpy(&u, &h, 2);
  return u;
}
static __device__ __forceinline__ float bf_bits2f(unsigned short u) {
  __hip_bfloat16 h;
  __builtin_memcpy(&h, &u, 2);
  return __bfloat162float(h);
}

// Async 16B/lane global->LDS copy (global_load_lds_dwordx4). LDS side must be
// wave-uniform base + lane*16 — all call sites below satisfy this.
static __device__ __forceinline__ void async_copy16(const void* gptr,
                                                    void* lptr) {
  __builtin_amdgcn_global_load_lds(
      (const __attribute__((address_space(1))) unsigned int*)gptr,
      (__attribute__((address_space(3))) unsigned int*)lptr, 16, 0, 0);
}

// ---------------------------------------------------------------------------
// input f32 -> bf16 hi/lo split (hi = bf16(x), lo = bf16(x - hi))
// ---------------------------------------------------------------------------
__global__ __launch_bounds__(256) void convert_input(
    const float* __restrict__ A, __hip_bfloat16* __restrict__ Ahi,
    __hip_bfloat16* __restrict__ Alo) {
  const long idx = ((long)blockIdx.x * 256 + threadIdx.x) * 4;
  const float4 v = *(const float4*)&A[idx];
  const float vv[4] = {v.x, v.y, v.z, v.w};
  ushort4 hi, lo;
  unsigned short* hp = (unsigned short*)&hi;
  unsigned short* lp = (unsigned short*)&lo;
#pragma unroll
  for (int e = 0; e < 4; e++) {
    unsigned short h = f2bf_bits(vv[e]);
    hp[e] = h;
    lp[e] = f2bf_bits(vv[e] - bf_bits2f(h));
  }
  *(ushort4*)&Ahi[idx] = hi;
  *(ushort4*)&Alo[idx] = lo;
}

// ---------------------------------------------------------------------------
// W[k][n] f32 -> transposed bf16 hi/lo: WT[n][k]. z=0: kW, z=1: vW.
// ---------------------------------------------------------------------------
__global__ __launch_bounds__(256) void convert_w(
    const float* __restrict__ kW, const float* __restrict__ vW,
    __hip_bfloat16* __restrict__ WkhiT, __hip_bfloat16* __restrict__ WkloT,
    __hip_bfloat16* __restrict__ WvhiT, __hip_bfloat16* __restrict__ WvloT) {
  __shared__ float tile[64][65];
  const int z = blockIdx.z;
  const float* __restrict__ W = z ? vW : kW;
  __hip_bfloat16* __restrict__ HiT = z ? WvhiT : WkhiT;
  __hip_bfloat16* __restrict__ LoT = z ? WvloT : WkloT;
  const int k0 = blockIdx.x * 64, n0 = blockIdx.y * 64;
  const int t = threadIdx.x;
#pragma unroll
  for (int s = 0; s < 16; s++) {
    int idx = t + s * 256;
    int r = idx >> 6, c = idx & 63;
    tile[r][c] = W[(long)(k0 + r) * FEAT + n0 + c];
  }
  __syncthreads();
#pragma unroll
  for (int s = 0; s < 16; s++) {
    int idx = t + s * 256;
    int a = idx >> 6, b = idx & 63;
    float w = tile[b][a];
    unsigned short h = f2bf_bits(w);
    unsigned short l = f2bf_bits(w - bf_bits2f(h));
    __builtin_memcpy(&HiT[(long)(n0 + a) * FEAT + k0 + b], &h, 2);
    __builtin_memcpy(&LoT[(long)(n0 + a) * FEAT + k0 + b], &l, 2);
  }
}

// ---------------------------------------------------------------------------
// kh/vh = A@W via split-bf16 MFMA: Ahi*Whi + Ahi*Wlo + Alo*Whi (~f32 accurate)
// BK=64 (2 sub-panels per operand per barrier -> half the sync points; LDS
// 64 KB, grid 512 = 2 blocks/CU either way).
// z=0: acc -> LDS tile -> coalesced 16B row stores scattered to khp[iperm[r]].
// z=1: write vh f32 (needed for transpose+cmean).
// ---------------------------------------------------------------------------
__global__ __launch_bounds__(256) void mfma_dual(
    const __hip_bfloat16* __restrict__ Ahi, const __hip_bfloat16* __restrict__ Alo,
    const __hip_bfloat16* __restrict__ WkhiT, const __hip_bfloat16* __restrict__ WkloT,
    const __hip_bfloat16* __restrict__ WvhiT, const __hip_bfloat16* __restrict__ WvloT,
    const int* __restrict__ iperm, __hip_bfloat16* __restrict__ khp,
    float* __restrict__ vh) {
  const int z = blockIdx.z;
  const __hip_bfloat16* __restrict__ WhiT = z ? WvhiT : WkhiT;
  const __hip_bfloat16* __restrict__ WloT = z ? WvloT : WkloT;
  const int ti = blockIdx.x, tj = blockIdx.y;
  // 64 KB union: 4 operand types x [2 sub-panels][128*32]; Ct[128][136] epi.
  __shared__ __align__(16) __hip_bfloat16 smem[32768];
  __hip_bfloat16* Ah = smem;
  __hip_bfloat16* Al = smem + 8192;
  __hip_bfloat16* Wh = smem + 16384;
  __hip_bfloat16* Wl = smem + 24576;
  const int t = threadIdx.x;
  const int lane = t & 63, w = t >> 6;
  const int wm = (w >> 1) * 64, wn = (w & 1) * 64;
  const int quad = lane >> 4, ln = lane & 15;
  const int qr = quad * 8;
  floatx4 acc[4][4];
#pragma unroll
  for (int mi = 0; mi < 4; mi++)
#pragma unroll
    for (int ni = 0; ni < 4; ni++) acc[mi][ni] = (floatx4)0.f;
  for (int k0 = 0; k0 < FEAT; k0 += 64) {
    __syncthreads();
#pragma unroll
    for (int p = 0; p < 2; p++)
#pragma unroll
      for (int s = 0; s < 2; s++) {
        int c = t + s * 256;
        int row = c >> 2, off8 = (c & 3) * 8;
        int lo = p * 4096 + row * 32 + off8;  // wave-uniform + lane*16
        long ga = (long)(ti * 128 + row) * FEAT + k0 + p * 32 + off8;
        long gw = (long)(tj * 128 + row) * FEAT + k0 + p * 32 + off8;
        async_copy16(&Ahi[ga], &Ah[lo]);
        async_copy16(&Alo[ga], &Al[lo]);
        async_copy16(&WhiT[gw], &Wh[lo]);
        async_copy16(&WloT[gw], &Wl[lo]);
      }
    __syncthreads();
#pragma unroll
    for (int p = 0; p < 2; p++) {
      short8 ah[4], al[4], bh[4], bl[4];
#pragma unroll
      for (int mi = 0; mi < 4; mi++) {
        ah[mi] = *(const short8*)&Ah[p * 4096 + (wm + mi * 16 + ln) * 32 + qr];
        al[mi] = *(const short8*)&Al[p * 4096 + (wm + mi * 16 + ln) * 32 + qr];
      }
#pragma unroll
      for (int ni = 0; ni < 4; ni++) {
        bh[ni] = *(const short8*)&Wh[p * 4096 + (wn + ni * 16 + ln) * 32 + qr];
        bl[ni] = *(const short8*)&Wl[p * 4096 + (wn + ni * 16 + ln) * 32 + qr];
      }
#pragma unroll
      for (int mi = 0; mi < 4; mi++)
#pragma unroll
        for (int ni = 0; ni < 4; ni++) {
          acc[mi][ni] = __builtin_amdgcn_mfma_f32_16x16x32_bf16(
              ah[mi], bh[ni], acc[mi][ni], 0, 0, 0);
          acc[mi][ni] = __builtin_amdgcn_mfma_f32_16x16x32_bf16(
              ah[mi], bl[ni], acc[mi][ni], 0, 0, 0);
          acc[mi][ni] = __builtin_amdgcn_mfma_f32_16x16x32_bf16(
              al[mi], bh[ni], acc[mi][ni], 0, 0, 0);
        }
    }
  }
  if (z == 0) {
    // route through LDS so the scattered-row stores are 16B-coalesced
    __syncthreads();
    __hip_bfloat16* Ct = smem;  // [128][136]
#pragma unroll
    for (int mi = 0; mi < 4; mi++)
#pragma unroll
      for (int ni = 0; ni < 4; ni++) {
        int col = wn + ni * 16 + ln;
#pragma unroll
        for (int reg = 0; reg < 4; reg++) {
          int row = wm + mi * 16 + quad * 4 + reg;
          Ct[row * 136 + col] = __float2bfloat16(acc[mi][ni][reg]);
        }
      }
    __syncthreads();
#pragma unroll
    for (int i = 0; i < 8; i++) {
      int idx = t + i * 256;
      int rl = idx >> 4, c8 = (idx & 15) * 8;
      int gr = iperm[ti * 128 + rl];
      *(short8*)&khp[(long)gr * FEAT + tj * 128 + c8] =
          *(const short8*)&Ct[rl * 136 + c8];
    }
  } else {
#pragma unroll
    for (int mi = 0; mi < 4; mi++)
#pragma unroll
      for (int ni = 0; ni < 4; ni++) {
        int cc = tj * 128 + wn + ni * 16 + ln;
#pragma unroll
        for (int reg = 0; reg < 4; reg++) {
          int r = ti * 128 + wm + mi * 16 + quad * 4 + reg;
          vh[(long)r * FEAT + cc] = acc[mi][ni][reg];
        }
      }
  }
}

// ---------------------------------------------------------------------------
// cw[f][b] = sum_h kW[f][h] * rot[h][b]  (fp64)
// ---------------------------------------------------------------------------
__global__ __launch_bounds__(64) void cw_kernel(
    const float* __restrict__ kW, const float* __restrict__ rot,
    double* __restrict__ cw) {
  const int f = blockIdx.x;
  const int lane = threadIdx.x;
  double r0 = 0.0, r1 = 0.0;
  for (int h = lane; h < FEAT; h += 64) {
    double a = (double)kW[(long)f * FEAT + h];
    r0 += a * (double)rot[2 * h];
    r1 += a * (double)rot[2 * h + 1];
  }
#pragma unroll
  for (int off = 32; off > 0; off >>= 1) {
    r0 += __shfl_down(r0, off);
    r1 += __shfl_down(r1, off);
  }
  if (lane == 0) {
    cw[2 * f] = r0;
    cw[2 * f + 1] = r1;
  }
}

// ---------------------------------------------------------------------------
// buckets from EXACT inputs: rv = input @ cw in fp64; argmax([r0,r1,-r0,-r1])
// ---------------------------------------------------------------------------
__global__ __launch_bounds__(64) void rv_bucket_kernel(
    const float* __restrict__ input, const double* __restrict__ cw,
    int* __restrict__ buckets) {
  const int i = blockIdx.x;
  const int lane = threadIdx.x;
  double r0 = 0.0, r1 = 0.0;
  for (int f = lane; f < FEAT; f += 64) {
    double a = (double)input[(long)i * FEAT + f];
    r0 += a * cw[2 * f];
    r1 += a * cw[2 * f + 1];
  }
#pragma unroll
  for (int off = 32; off > 0; off >>= 1) {
    r0 += __shfl_down(r0, off);
    r1 += __shfl_down(r1, off);
  }
  if (lane == 0) {
    int b = 0;
    double best = r0;
    if (r1 > best)  { best = r1;  b = 1; }
    if (-r0 > best) { best = -r0; b = 2; }
    if (-r1 > best) { best = -r1; b = 3; }
    buckets[i] = b;
  }
}

// ---------------------------------------------------------------------------
// Stable counting sort by bucket (1 block, parallel Hillis-Steele scan).
// Emits perm AND inverse perm. Also zeroes cmean and rowsum.
// ---------------------------------------------------------------------------
__global__ __launch_bounds__(256) void sort_kernel(
    const int* __restrict__ buckets, int* __restrict__ perm,
    int* __restrict__ iperm, int* __restrict__ meta,
    float* __restrict__ cmean, float* __restrict__ rowsum) {
  __shared__ int lc[4][256];
  __shared__ int sc[4][256];
  __shared__ int boff_sh[5];
  const int t = threadIdx.x;
  cmean[t] = 0.f;
  cmean[t + 256] = 0.f;
  for (int k = t; k < N_NODES; k += 256) rowsum[k] = 0.f;
  const int base = t * 32;
  int c0 = 0, c1 = 0, c2 = 0, c3 = 0;
  for (int k = 0; k < 32; k++) {
    int b = buckets[base + k];
    c0 += (b == 0); c1 += (b == 1); c2 += (b == 2); c3 += (b == 3);
  }
  lc[0][t] = c0; lc[1][t] = c1; lc[2][t] = c2; lc[3][t] = c3;
  sc[0][t] = c0; sc[1][t] = c1; sc[2][t] = c2; sc[3][t] = c3;
  __syncthreads();
  for (int off = 1; off < 256; off <<= 1) {
    int a0 = (t >= off) ? sc[0][t - off] : 0;
    int a1 = (t >= off) ? sc[1][t - off] : 0;
    int a2 = (t >= off) ? sc[2][t - off] : 0;
    int a3 = (t >= off) ? sc[3][t - off] : 0;
    __syncthreads();
    sc[0][t] += a0; sc[1][t] += a1; sc[2][t] += a2; sc[3][t] += a3;
    __syncthreads();
  }
  if (t == 0) {
    int boff[5];
    boff[0] = 0;
    for (int b = 0; b < 4; b++) boff[b + 1] = boff[b] + sc[b][255];
    for (int b = 0; b < 5; b++) { meta[b] = boff[b]; boff_sh[b] = boff[b]; }
    long so = 0;
    int po = 0;
    for (int b = 0; b < 4; b++) {
      int tot = boff[b + 1] - boff[b];
      int pad = ((tot + 127) >> 7) << 7;
      meta[5 + b] = pad;
      meta[9 + b] = (int)so;
      meta[14 + b] = po;
      so += (long)pad * pad;
      po += pad;
    }
    meta[13] = (int)so;
    meta[18] = po;
    if (so > CAP_S)
      for (int b = 0; b < 4; b++) meta[5 + b] = 0;
  }
  __syncthreads();
  int s0 = boff_sh[0] + sc[0][t] - lc[0][t];
  int s1 = boff_sh[1] + sc[1][t] - lc[1][t];
  int s2 = boff_sh[2] + sc[2][t] - lc[2][t];
  int s3 = boff_sh[3] + sc[3][t] - lc[3][t];
  for (int k = 0; k < 32; k++) {
    int i = base + k;
    int b = buckets[i];
    int pos = (b == 0) ? s0++ : ((b == 1) ? s1++ : ((b == 2) ? s2++ : s3++));
    perm[pos] = i;
    iperm[i] = pos;
  }
}

// ---------------------------------------------------------------------------
// vhpT[f][poff_b + local] = bf16(vh[perm[boff_b + local]][f]); pads zeroed.
// Fused cmean column-sum accumulation (cmean pre-zeroed by sort_kernel).
// ---------------------------------------------------------------------------
__global__ __launch_bounds__(256) void transpose_vhpT_kernel(
    const float* __restrict__ vh, const int* __restrict__ perm,
    const int* __restrict__ meta, __hip_bfloat16* __restrict__ vhpT,
    float* __restrict__ cmean) {
  __shared__ float tile[64][65];
  __shared__ float cred[4][64];
  const int g0 = blockIdx.x * 64;
  const int f0 = blockIdx.y * 64;
  const int t = threadIdx.x;
#pragma unroll
  for (int s = 0; s < 16; s++) {
    int idx = t + s * 256;
    int r = idx >> 6, c = idx & 63;
    int pos = g0 + r;
    int b = (pos >= meta[15]) + (pos >= meta[16]) + (pos >= meta[17]);
    int local = pos - meta[14 + b];
    int n_b = meta[b + 1] - meta[b];
    float v = 0.f;
    if (local < n_b) v = vh[(long)perm[meta[b] + local] * FEAT + f0 + c];
    tile[r][c] = v;
  }
  __syncthreads();
  {
    const int c = t & 63, seg = t >> 6;
    float ps = 0.f;
#pragma unroll
    for (int rr = 0; rr < 16; rr++) ps += tile[seg * 16 + rr][c];
    cred[seg][c] = ps;
  }
  __syncthreads();
  if (t < 64)
    atomicAdd(&cmean[f0 + t],
              cred[0][t] + cred[1][t] + cred[2][t] + cred[3][t]);
#pragma unroll
  for (int s = 0; s < 16; s++) {
    int idx = t + s * 256;
    int fr = idx >> 6, gc = idx & 63;
    vhpT[(long)(f0 + fr) * VHPT_W + g0 + gc] = __float2bfloat16(tile[gc][fr]);
  }
}

// ---------------------------------------------------------------------------
// maskbits[g][jj] = (adj[perm[g]][perm[boff_b+jj]] > 0), bit-packed per 64.
// Runs EARLY (right after sort): its 268 MB adj stream evicts L3, so all
// later producer->consumer buffers (khp, vhpT, S) stay L3-resident.
// ---------------------------------------------------------------------------
__global__ __launch_bounds__(256) void maskpack_kernel(
    const int* __restrict__ adj, const int* __restrict__ perm,
    const int* __restrict__ meta, unsigned long long* __restrict__ maskbits) {
  __shared__ int adj_lds[N_NODES];
  const int g = blockIdx.x;
  const int t = threadIdx.x;
  const int b = (g >= meta[1]) + (g >= meta[2]) + (g >= meta[3]);
  const int boff = meta[b];
  const int n_b = meta[b + 1] - boff;
  const int padded = meta[5 + b];
  const int i = perm[g];
  const int* arow = adj + (long)i * N_NODES;
#pragma unroll
  for (int s = 0; s < 8; s++) {
    int idx = (t + s * 256) * 4;
    *(int4*)&adj_lds[idx] = *(const int4*)&arow[idx];
  }
  __syncthreads();
  const int lane = t & 63, w = t >> 6;
  for (int jj0 = w * 64; jj0 < padded; jj0 += 256) {
    int jj = jj0 + lane;
    int pred = 0;
    if (jj < n_b) pred = adj_lds[perm[boff + jj]] > 0;
    unsigned long long mword = __ballot(pred);
    if (lane == 0) maskbits[(long)g * 128 + (jj0 >> 6)] = mword;
  }
}

// ---------------------------------------------------------------------------
// S tile = khp_b . khp_b^T (bf16 MFMA, async staging, BK=128 quad-panel:
// 4 barrier-pairs total for K=512). FUSED NO-MAX SOFTMAX NUMERATOR:
// epilogue stores P~ = bf16(exp(S/sqrt(H))) (masked -> 0) and accumulates f32
// row sums via 16-lane shfl reduce + one atomicAdd per (row, tile). Scores
// are bounded (~50 << 88) so f32 exp cannot overflow; exp(S)/sum == softmax
// exactly. Triangular grid ti <= tj; both orientations written from an LDS
// tile with coalesced 16B stores. Pad rows excluded from row-sum atomics.
// ---------------------------------------------------------------------------
__global__ __launch_bounds__(256) void s_gemm(
    const __hip_bfloat16* __restrict__ khp, const int* __restrict__ meta,
    const unsigned long long* __restrict__ maskbits,
    __hip_bfloat16* __restrict__ S, float* __restrict__ rowsum) {
  const int b = blockIdx.z;
  const int padded = meta[5 + b];
  const int T = padded >> 7;
  const int pairs = (T * (T + 1)) >> 1;
  int L = blockIdx.x;
  if (L >= pairs) return;
  int ti = 0;
  while (L >= T - ti) { L -= T - ti; ti++; }
  const int tj = ti + L;
  const int boff = meta[b];
  const int n_b = meta[b + 1] - boff;
  const long soff = meta[9 + b];
  // 64 KB: As/Bs (4 panels x 8 KB each) during main loop; Ct[128][136] epi.
  __shared__ __align__(16) __hip_bfloat16 smem[32768];
  __hip_bfloat16* As = smem;                  // [4][128*32]
  __hip_bfloat16* Bs = smem + 4 * 128 * 32;   // [4][128*32]
  const int t = threadIdx.x;
  const int lane = t & 63, w = t >> 6;
  const int wm = (w >> 1) * 64, wn = (w & 1) * 64;
  const int quad = lane >> 4, ln = lane & 15;
  const int qr = quad * 8;
  floatx4 acc[4][4];
#pragma unroll
  for (int mi = 0; mi < 4; mi++)
#pragma unroll
    for (int ni = 0; ni < 4; ni++) acc[mi][ni] = (floatx4)0.f;
  const long a_g0 = boff + ti * 128;
  const long b_g0 = boff + tj * 128;
  for (int k0 = 0; k0 < FEAT; k0 += 128) {
    __syncthreads();
#pragma unroll
    for (int p = 0; p < 4; p++)
#pragma unroll
      for (int s = 0; s < 2; s++) {
        int c = t + s * 256;
        int row = c >> 2, off8 = (c & 3) * 8;
        int lo = p * 4096 + row * 32 + off8;  // wave-uniform + lane*16
        async_copy16(&khp[(a_g0 + row) * FEAT + k0 + p * 32 + off8], &As[lo]);
        async_copy16(&khp[(b_g0 + row) * FEAT + k0 + p * 32 + off8], &Bs[lo]);
      }
    __syncthreads();
#pragma unroll
    for (int p = 0; p < 4; p++) {
      short8 af[4], bfr[4];
#pragma unroll
      for (int mi = 0; mi < 4; mi++)
        af[mi] =
            *(const short8*)&As[p * 4096 + (wm + mi * 16 + ln) * 32 + qr];
#pragma unroll
      for (int ni = 0; ni < 4; ni++)
        bfr[ni] =
            *(const short8*)&Bs[p * 4096 + (wn + ni * 16 + ln) * 32 + qr];
#pragma unroll
      for (int mi = 0; mi < 4; mi++)
#pragma unroll
        for (int ni = 0; ni < 4; ni++)
          acc[mi][ni] = __builtin_amdgcn_mfma_f32_16x16x32_bf16(
              af[mi], bfr[ni], acc[mi][ni], 0, 0, 0);
    }
  }
  // ---- epilogue: P~ = bf16(exp(acc*scale)) -> LDS tile (unmasked) ----
  const float scale = 0.04419417382415922f;  // 1/sqrt(512)
  __syncthreads();  // As/Bs dead; reuse as Ct
  __hip_bfloat16* Ct = smem;  // [128][136]
#pragma unroll
  for (int mi = 0; mi < 4; mi++)
#pragma unroll
    for (int ni = 0; ni < 4; ni++) {
      int col = wn + ni * 16 + ln;
#pragma unroll
      for (int reg = 0; reg < 4; reg++) {
        int row = wm + mi * 16 + quad * 4 + reg;
        Ct[row * 136 + col] =
            __float2bfloat16(__expf(acc[mi][ni][reg] * scale));
      }
    }
  __syncthreads();
  // normal orientation: coalesced 16B stores of rows of the ti-block
#pragma unroll
  for (int i = 0; i < 8; i++) {
    int idx = t + i * 256;
    int rl = idx >> 4, c8 = (idx & 15) * 8;
    int rg = ti * 128 + rl;
    int cg = tj * 128 + c8;
    union { short8 v; unsigned short u[8]; } pk;
    pk.v = *(const short8*)&Ct[rl * 136 + c8];
    unsigned long long wbits = maskbits[(long)(boff + rg) * 128 + (cg >> 6)];
    float ps = 0.f;
#pragma unroll
    for (int e = 0; e < 8; e++) {
      if (!((wbits >> ((cg & 63) + e)) & 1ULL)) pk.u[e] = 0;
      ps += bf_bits2f(pk.u[e]);
    }
    *(short8*)&S[soff + (long)rg * padded + cg] = pk.v;
    // per-row partial sum: 16 consecutive lanes share rg
#pragma unroll
    for (int off = 1; off < 16; off <<= 1) ps += __shfl_xor(ps, off);
    if (rg < n_b && (lane & 15) == 0)
      atomicAdd(&rowsum[boff + rg], ps);
  }
  // mirrored orientation (tj-block rows), skipped on diagonal
  if (ti != tj) {
#pragma unroll
    for (int i = 0; i < 8; i++) {
      int idx = t + i * 256;
      int cl = idx >> 4, r8 = (idx & 15) * 8;
      int rg = tj * 128 + cl;   // output row (column of the computed tile)
      int cg = ti * 128 + r8;   // output col base
      union { short8 v; unsigned short u[8]; } pk;
#pragma unroll
      for (int e = 0; e < 8; e++) {
        __hip_bfloat16 hv = Ct[(r8 + e) * 136 + cl];
        __builtin_memcpy(&pk.u[e], &hv, 2);
      }
      unsigned long long wbits = maskbits[(long)(boff + rg) * 128 + (cg >> 6)];
      float ps = 0.f;
#pragma unroll
      for (int e = 0; e < 8; e++) {
        if (!((wbits >> ((cg & 63) + e)) & 1ULL)) pk.u[e] = 0;
        ps += bf_bits2f(pk.u[e]);
      }
      *(short8*)&S[soff + (long)rg * padded + cg] = pk.v;
#pragma unroll
      for (int off = 1; off < 16; off <<= 1) ps += __shfl_xor(ps, off);
      if (rg < n_b && (lane & 15) == 0)
        atomicAdd(&rowsum[boff + rg], ps);
    }
  }
}

// ---------------------------------------------------------------------------
// O tile = P~ . vhp (pure bf16 GEMM), 64 rows x 128 features per block.
// BK=128 quad-panel async staging (half the barrier-pairs of BK=64; LDS 48 KB,
// grid-limited to 2 blocks/CU either way). Epilogue: x (1/rowsum) (softmax
// denom, exact) + ELU + empty-row (rowsum==0) cmean fallback + scatter to
// out[perm[g]].
// ---------------------------------------------------------------------------
__global__ __launch_bounds__(256) void pv_gemm(
    const __hip_bfloat16* __restrict__ S, const __hip_bfloat16* __restrict__ vhpT,
    const int* __restrict__ meta, const int* __restrict__ perm,
    const float* __restrict__ cmean, const float* __restrict__ rowsum,
    float* __restrict__ out) {
  const int b = blockIdx.z;
  const int padded = meta[5 + b];
  const int ti = blockIdx.x;
  if (ti * 64 >= padded) return;
  const int boff = meta[b];
  const int n_b = meta[b + 1] - boff;
  const long soff = meta[9 + b];
  const int poff = meta[14 + b];
  const int f0 = blockIdx.y * 128;
  __shared__ __align__(16) __hip_bfloat16 As[4 * 64 * 32];
  __shared__ __align__(16) __hip_bfloat16 Bs[4 * 128 * 32];
  const int t = threadIdx.x;
  const int lane = t & 63, w = t >> 6;
  const int wm = (w >> 1) * 32, wn = (w & 1) * 64;
  const int quad = lane >> 4, ln = lane & 15;
  const int qr = quad * 8;
  floatx4 acc[2][4];
#pragma unroll
  for (int mi = 0; mi < 2; mi++)
#pragma unroll
    for (int ni = 0; ni < 4; ni++) acc[mi][ni] = (floatx4)0.f;
  const long r0 = (long)ti * 64;
  for (int k0 = 0; k0 < padded; k0 += 128) {
    __syncthreads();
#pragma unroll
    for (int p = 0; p < 4; p++) {
      {
        int row = t >> 2, off8 = (t & 3) * 8;
        async_copy16(&S[soff + (r0 + row) * padded + k0 + p * 32 + off8],
                     &As[p * 2048 + row * 32 + off8]);
      }
#pragma unroll
      for (int s = 0; s < 2; s++) {
        int c = t + s * 256;
        int row = c >> 2, off8 = (c & 3) * 8;
        async_copy16(
            &vhpT[(long)(f0 + row) * VHPT_W + poff + k0 + p * 32 + off8],
            &Bs[p * 4096 + row * 32 + off8]);
      }
    }
    __syncthreads();
#pragma unroll
    for (int p = 0; p < 4; p++) {
      short8 af[2], bfr[4];
#pragma unroll
      for (int mi = 0; mi < 2; mi++)
        af[mi] = *(const short8*)&As[p * 2048 + (wm + mi * 16 + ln) * 32 + qr];
#pragma unroll
      for (int ni = 0; ni < 4; ni++)
        bfr[ni] = *(const short8*)&Bs[p * 4096 + (wn + ni * 16 + ln) * 32 + qr];
#pragma unroll
      for (int mi = 0; mi < 2; mi++)
#pragma unroll
        for (int ni = 0; ni < 4; ni++)
          acc[mi][ni] = __builtin_amdgcn_mfma_f32_16x16x32_bf16(
              af[mi], bfr[ni], acc[mi][ni], 0, 0, 0);
    }
  }
#pragma unroll
  for (int mi = 0; mi < 2; mi++) {
#pragma unroll
    for (int reg = 0; reg < 4; reg++) {
      int r = ti * 64 + wm + mi * 16 + quad * 4 + reg;
      if (r < n_b) {
        int g = boff + r;
        int node = perm[g];
        float rs = rowsum[g];
        int fl = (rs == 0.f);
        float inv = fl ? 0.f : 1.f / rs;
#pragma unroll
        for (int ni = 0; ni < 4; ni++) {
          int fc = f0 + wn + ni * 16 + ln;
          float v = fl ? cmean[fc] * (1.f / (float)N_NODES)
                       : acc[mi][ni][reg] * inv;
          v = v > 0.f ? v : expm1f(v);
          out[(long)node * FEAT + fc] = v;
        }
      }
    }
  }
}

// ===========================================================================
// Slow-path fallback (only if ws_size < WS_NEEDED): round-1 implementation.
// ===========================================================================
__global__ __launch_bounds__(256) void gemm_dual(
    const float* __restrict__ A, const float* __restrict__ Wk,
    const float* __restrict__ Wv, float* __restrict__ kh,
    float* __restrict__ vh) {
  __shared__ float As[32][33];
  __shared__ float Bk[32][33];
  __shared__ float Bv[32][33];
  const int tid = threadIdx.x;
  const int row0 = blockIdx.x * 32;
  const int col0 = blockIdx.y * 32;
  const int tx = tid & 15, ty = tid >> 4;
  float ck00 = 0.f, ck01 = 0.f, ck10 = 0.f, ck11 = 0.f;
  float cv00 = 0.f, cv01 = 0.f, cv10 = 0.f, cv11 = 0.f;
  for (int kt = 0; kt < FEAT; kt += 32) {
#pragma unroll
    for (int t = 0; t < 4; t++) {
      int e = tid + t * 256;
      int r = e >> 5, c = e & 31;
      As[r][c] = A[(long)(row0 + r) * FEAT + kt + c];
      Bk[r][c] = Wk[(long)(kt + r) * FEAT + col0 + c];
      Bv[r][c] = Wv[(long)(kt + r) * FEAT + col0 + c];
    }
    __syncthreads();
#pragma unroll
    for (int kk = 0; kk < 32; kk++) {
      float a0 = As[ty * 2][kk], a1 = As[ty * 2 + 1][kk];
      float bk0 = Bk[kk][tx * 2], bk1 = Bk[kk][tx * 2 + 1];
      float bv0 = Bv[kk][tx * 2], bv1 = Bv[kk][tx * 2 + 1];
      ck00 += a0 * bk0; ck01 += a0 * bk1;
      ck10 += a1 * bk0; ck11 += a1 * bk1;
      cv00 += a0 * bv0; cv01 += a0 * bv1;
      cv10 += a1 * bv0; cv11 += a1 * bv1;
    }
    __syncthreads();
  }
  const int r0 = row0 + ty * 2, c0 = col0 + tx * 2;
  kh[(long)r0 * FEAT + c0] = ck00;       kh[(long)r0 * FEAT + c0 + 1] = ck01;
  kh[(long)(r0 + 1) * FEAT + c0] = ck10; kh[(long)(r0 + 1) * FEAT + c0 + 1] = ck11;
  vh[(long)r0 * FEAT + c0] = cv00;       vh[(long)r0 * FEAT + c0 + 1] = cv01;
  vh[(long)(r0 + 1) * FEAT + c0] = cv10; vh[(long)(r0 + 1) * FEAT + c0 + 1] = cv11;
}

__global__ __launch_bounds__(64) void bucket_kernel(
    const float* __restrict__ kh, const float* __restrict__ rot,
    int* __restrict__ buckets) {
  const int i = blockIdx.x;
  const int lane = threadIdx.x;
  double r0 = 0.0, r1 = 0.0;
  for (int h = lane; h < FEAT; h += 64) {
    double a = (double)kh[(long)i * FEAT + h];
    r0 += a * (double)rot[2 * h];
    r1 += a * (double)rot[2 * h + 1];
  }
#pragma unroll
  for (int off = 32; off > 0; off >>= 1) {
    r0 += __shfl_down(r0, off);
    r1 += __shfl_down(r1, off);
  }
  if (lane == 0) {
    int b = 0;
    double best = r0;
    if (r1 > best)  { best = r1;  b = 1; }
    if (-r0 > best) { best = -r0; b = 2; }
    if (-r1 > best) { best = -r1; b = 3; }
    buckets[i] = b;
  }
}

__global__ __launch_bounds__(256) void attn_kernel(
    const float* __restrict__ kh, const float* __restrict__ vh,
    const int* __restrict__ adj, const int* __restrict__ buckets,
    float* __restrict__ out) {
  __shared__ float khi[FEAT];
  __shared__ float pbuf[N_NODES];
  __shared__ unsigned short jlist[N_NODES];
  __shared__ int cnt_sh;
  __shared__ float red[256];
  const int i = blockIdx.x;
  const int tid = threadIdx.x;
  if (tid == 0) cnt_sh = 0;
  for (int k = tid; k < FEAT; k += 256) khi[k] = kh[(long)i * FEAT + k];
  const int mybucket = buckets[i];
  __syncthreads();
  const int* adjrow = adj + (long)i * N_NODES;
  for (int j = tid; j < N_NODES; j += 256) {
    if (adjrow[j] > 0 && buckets[j] == mybucket) {
      int idx = atomicAdd(&cnt_sh, 1);
      jlist[idx] = (unsigned short)j;
    }
  }
  __syncthreads();
  const int cnt = cnt_sh;
  float mloc = -INFINITY;
  for (int idx = tid; idx < cnt; idx += 256) {
    int j = jlist[idx];
    const float4* kj = (const float4*)(kh + (long)j * FEAT);
    const float4* ki = (const float4*)khi;
    float acc = 0.f;
#pragma unroll 8
    for (int k = 0; k < FEAT / 4; k++) {
      float4 a = ki[k];
      float4 b = kj[k];
      acc += a.x * b.x + a.y * b.y + a.z * b.z + a.w * b.w;
    }
    float s = acc * 0.04419417382415922f;
    pbuf[idx] = s;
    mloc = fmaxf(mloc, s);
  }
  red[tid] = mloc;
  __syncthreads();
#pragma unroll
  for (int off = 128; off > 0; off >>= 1) {
    if (tid < off) red[tid] = fmaxf(red[tid], red[tid + off]);
    __syncthreads();
  }
  const float m = red[0];
  __syncthreads();
  float lloc = 0.f;
  for (int idx = tid; idx < cnt; idx += 256) {
    float p = expf(pbuf[idx] - m);
    pbuf[idx] = p;
    lloc += p;
  }
  red[tid] = lloc;
  __syncthreads();
#pragma unroll
  for (int off = 128; off > 0; off >>= 1) {
    if (tid < off) red[tid] += red[tid + off];
    __syncthreads();
  }
  const float l = red[0];
  __syncthreads();
  const int f = 2 * tid;
  float acc0 = 0.f, acc1 = 0.f;
  if (cnt > 0) {
#pragma unroll 4
    for (int idx = 0; idx < cnt; idx++) {
      int j = jlist[idx];
      float p = pbuf[idx];
      float2 v = *(const float2*)(vh + (long)j * FEAT + f);
      acc0 += p * v.x;
      acc1 += p * v.y;
    }
    float invl = 1.f / l;
    acc0 *= invl;
    acc1 *= invl;
  } else {
    for (int j = 0; j < N_NODES; j++) {
      float2 v = *(const float2*)(vh + (long)j * FEAT + f);
      acc0 += v.x;
      acc1 += v.y;
    }
    acc0 *= (1.f / (float)N_NODES);
    acc1 *= (1.f / (float)N_NODES);
  }
  acc0 = acc0 > 0.f ? acc0 : expm1f(acc0);
  acc1 = acc1 > 0.f ? acc1 : expm1f(acc1);
  *(float2*)(out + (long)i * FEAT + f) = make_float2(acc0, acc1);
}

extern "C" void kernel_launch(void* const* d_in, const int* in_sizes, int n_in,
                              void* d_out, int out_size, void* d_ws,
                              size_t ws_size, hipStream_t stream) {
  const float* input = (const float*)d_in[0];
  const int* adj = (const int*)d_in[1];
  const float* rot = (const float*)d_in[2];
  const float* kW = (const float*)d_in[3];
  const float* vW = (const float*)d_in[4];
  float* out = (float*)d_out;

  char* ws = (char*)d_ws;

  if (ws_size >= WS_NEEDED) {
    float* vh = (float*)(ws + OFF_VH);
    __hip_bfloat16* khp = (__hip_bfloat16*)(ws + OFF_KHP);
    __hip_bfloat16* vhpT = (__hip_bfloat16*)(ws + OFF_VHPT);
    unsigned long long* maskbits = (unsigned long long*)(ws + OFF_MASK);
    __hip_bfloat16* S = (__hip_bfloat16*)(ws + OFF_S);
    int* perm = (int*)(ws + OFF_PERM);
    int* iperm = (int*)(ws + OFF_IPERM);
    int* buckets = (int*)(ws + OFF_BUCK);
    int* meta = (int*)(ws + OFF_META);
    float* cmean = (float*)(ws + OFF_CMEAN);
    float* rowsum = (float*)(ws + OFF_ROWI);
    __hip_bfloat16* Ahi = (__hip_bfloat16*)(ws + OFF_AHI);
    __hip_bfloat16* Alo = (__hip_bfloat16*)(ws + OFF_ALO);
    __hip_bfloat16* WkhiT = (__hip_bfloat16*)(ws + OFF_WKHI);
    __hip_bfloat16* WkloT = (__hip_bfloat16*)(ws + OFF_WKLO);
    __hip_bfloat16* WvhiT = (__hip_bfloat16*)(ws + OFF_WVHI);
    __hip_bfloat16* WvloT = (__hip_bfloat16*)(ws + OFF_WVLO);
    double* cw = (double*)(ws + OFF_CW);

    // zero khp tail rows [8192, 8320) — read (masked) by s_gemm/pv when the
    // last bucket's padding spills past N.
    hipMemsetAsync(ws + OFF_KHP + (size_t)N_NODES * FEAT * 2, 0,
                   128 * FEAT * 2, stream);
    // ---- L3-aware schedule: the 268 MB adj stream (maskpack) runs BEFORE
    // any producer->consumer bf16 buffers are written, so khp/vhpT/S stay
    // L3-resident through the GEMM back half.
    cw_kernel<<<512, 64, 0, stream>>>(kW, rot, cw);
    rv_bucket_kernel<<<N_NODES, 64, 0, stream>>>(input, cw, buckets);
    sort_kernel<<<1, 256, 0, stream>>>(buckets, perm, iperm, meta, cmean,
                                       rowsum);
    maskpack_kernel<<<N_NODES, 256, 0, stream>>>(adj, perm, meta, maskbits);
    convert_input<<<4096, 256, 0, stream>>>(input, Ahi, Alo);
    convert_w<<<dim3(8, 8, 2), 256, 0, stream>>>(kW, vW, WkhiT, WkloT, WvhiT,
                                                 WvloT);
    mfma_dual<<<dim3(64, 4, 2), 256, 0, stream>>>(Ahi, Alo, WkhiT, WkloT,
                                                  WvhiT, WvloT, iperm, khp,
                                                  vh);
    transpose_vhpT_kernel<<<dim3(VHPT_W / 64, FEAT / 64), 256, 0, stream>>>(
        vh, perm, meta, vhpT, cmean);
    s_gemm<<<dim3(2080, 1, 4), 256, 0, stream>>>(khp, meta, maskbits, S,
                                                 rowsum);
    pv_gemm<<<dim3(128, 4, 4), 256, 0, stream>>>(S, vhpT, meta, perm, cmean,
                                                 rowsum, out);
  } else {
    float* kh = (float*)(ws + 0UL);
    float* vh = (float*)(ws + 16777216UL);
    int* buckets = (int*)(ws + 33554432UL);
    dim3 gemm_grid(N_NODES / 32, FEAT / 32);
    gemm_dual<<<gemm_grid, 256, 0, stream>>>(input, kW, vW, kh, vh);
    bucket_kernel<<<N_NODES, 64, 0, stream>>>(kh, rot, buckets);
    attn_kernel<<<N_NODES, 256, 0, stream>>>(kh, vh, adj, buckets, out);
  }
}

// Round 5
// 562.359 us; speedup vs baseline: 1.2019x; 1.0070x over previous
//
#include <hip/hip_runtime.h>
#include <hip/hip_bf16.h>
#include <math.h>

#define N_NODES 8192
#define FEAT 512
#define NEGV -9e15f
#define VHPT_W 8704

typedef __attribute__((ext_vector_type(8))) short short8;
typedef __attribute__((ext_vector_type(4))) float floatx4;

// ---- workspace layout (bytes) ----
#define OFF_KH    0UL          // (dead in fast path; kept for layout stability)
#define OFF_VH    16777216UL   // f32 vh [8192][512]
#define OFF_KHP   33554432UL   // bf16 [8320][512]
#define OFF_VHPT  42074112UL   // bf16 [512][8704]  (padded-position columns)
#define OFF_MASK  50987008UL   // u64 [8192][128]; head reused early for cw (f64[1024])
#define OFF_S     59375616UL   // bf16 S, cap 25165824 elems; head reused early for Ahi/Alo/W*T
#define OFF_PERM  109707264UL
#define OFF_FLAGS 109740032UL  // (unused)
#define OFF_BUCK  109772800UL
#define OFF_META  109805568UL  // ints: [0..4]=boff [5..8]=padded [9..13]=soff(+tot) [14..18]=poff
#define OFF_CMEAN 109806592UL
#define OFF_ROWM  109808640UL  // (unused)
#define OFF_ROWI  109841408UL  // f32 [8192] row sum of stored P~ (exp(S), masked->0)
#define OFF_IPERM 109874176UL  // int [8192] inverse permutation
#define WS_NEEDED 109906944UL
#define CAP_S     25165824L

// aliased (early-lifetime) buffers inside the S region:
#define OFF_AHI   (OFF_S)                 // bf16 [8192][512]
#define OFF_ALO   (OFF_S + 8388608UL)
#define OFF_WKHI  (OFF_S + 16777216UL)    // bf16 [512][512] transposed
#define OFF_WKLO  (OFF_S + 17301504UL)
#define OFF_WVHI  (OFF_S + 17825792UL)
#define OFF_WVLO  (OFF_S + 18350080UL)
#define OFF_CW    (OFF_MASK)              // f64 [512][2] (dead before maskpack)

static __device__ __forceinline__ unsigned short f2bf_bits(float x) {
  __hip_bfloat16 h = __float2bfloat16(x);
  unsigned short u;
  __builtin_memcpy(&u, &h, 2);
  return u;
}
static __device__ __forceinline__ float bf_bits2f(unsigned short u) {
  __hip_bfloat16 h;
  __builtin_memcpy(&h, &u, 2);
  return __bfloat162float(h);
}

// Async 16B/lane global->LDS copy (global_load_lds_dwordx4). LDS side must be
// wave-uniform base + lane*16 — all call sites below satisfy this.
static __device__ __forceinline__ void async_copy16(const void* gptr,
                                                    void* lptr) {
  __builtin_amdgcn_global_load_lds(
      (const __attribute__((address_space(1))) unsigned int*)gptr,
      (__attribute__((address_space(3))) unsigned int*)lptr, 16, 0, 0);
}

// ---------------------------------------------------------------------------
// input f32 -> bf16 hi/lo split (hi = bf16(x), lo = bf16(x - hi))
// ---------------------------------------------------------------------------
__global__ __launch_bounds__(256) void convert_input(
    const float* __restrict__ A, __hip_bfloat16* __restrict__ Ahi,
    __hip_bfloat16* __restrict__ Alo) {
  const long idx = ((long)blockIdx.x * 256 + threadIdx.x) * 4;
  const float4 v = *(const float4*)&A[idx];
  const float vv[4] = {v.x, v.y, v.z, v.w};
  ushort4 hi, lo;
  unsigned short* hp = (unsigned short*)&hi;
  unsigned short* lp = (unsigned short*)&lo;
#pragma unroll
  for (int e = 0; e < 4; e++) {
    unsigned short h = f2bf_bits(vv[e]);
    hp[e] = h;
    lp[e] = f2bf_bits(vv[e] - bf_bits2f(h));
  }
  *(ushort4*)&Ahi[idx] = hi;
  *(ushort4*)&Alo[idx] = lo;
}

// ---------------------------------------------------------------------------
// W[k][n] f32 -> transposed bf16 hi/lo: WT[n][k]. z=0: kW, z=1: vW.
// ---------------------------------------------------------------------------
__global__ __launch_bounds__(256) void convert_w(
    const float* __restrict__ kW, const float* __restrict__ vW,
    __hip_bfloat16* __restrict__ WkhiT, __hip_bfloat16* __restrict__ WkloT,
    __hip_bfloat16* __restrict__ WvhiT, __hip_bfloat16* __restrict__ WvloT) {
  __shared__ float tile[64][65];
  const int z = blockIdx.z;
  const float* __restrict__ W = z ? vW : kW;
  __hip_bfloat16* __restrict__ HiT = z ? WvhiT : WkhiT;
  __hip_bfloat16* __restrict__ LoT = z ? WvloT : WkloT;
  const int k0 = blockIdx.x * 64, n0 = blockIdx.y * 64;
  const int t = threadIdx.x;
#pragma unroll
  for (int s = 0; s < 16; s++) {
    int idx = t + s * 256;
    int r = idx >> 6, c = idx & 63;
    tile[r][c] = W[(long)(k0 + r) * FEAT + n0 + c];
  }
  __syncthreads();
#pragma unroll
  for (int s = 0; s < 16; s++) {
    int idx = t + s * 256;
    int a = idx >> 6, b = idx & 63;
    float w = tile[b][a];
    unsigned short h = f2bf_bits(w);
    unsigned short l = f2bf_bits(w - bf_bits2f(h));
    __builtin_memcpy(&HiT[(long)(n0 + a) * FEAT + k0 + b], &h, 2);
    __builtin_memcpy(&LoT[(long)(n0 + a) * FEAT + k0 + b], &l, 2);
  }
}

// ---------------------------------------------------------------------------
// kh/vh = A@W via split-bf16 MFMA: Ahi*Whi + Ahi*Wlo + Alo*Whi (~f32 accurate)
// DOUBLE-BUFFERED prefetch (T3-minimum): per 32-wide K-step, issue next-step
// global_load_lds into buf^1 BEFORE computing buf -> staging latency hides
// under the 48 MFMAs; one barrier per step.
// z=0: acc -> LDS tile -> coalesced 16B row stores scattered to khp[iperm[r]].
// z=1: write vh f32 (needed for transpose+cmean).
// ---------------------------------------------------------------------------
__global__ __launch_bounds__(256) void mfma_dual(
    const __hip_bfloat16* __restrict__ Ahi, const __hip_bfloat16* __restrict__ Alo,
    const __hip_bfloat16* __restrict__ WkhiT, const __hip_bfloat16* __restrict__ WkloT,
    const __hip_bfloat16* __restrict__ WvhiT, const __hip_bfloat16* __restrict__ WvloT,
    const int* __restrict__ iperm, __hip_bfloat16* __restrict__ khp,
    float* __restrict__ vh) {
  const int z = blockIdx.z;
  const __hip_bfloat16* __restrict__ WhiT = z ? WvhiT : WkhiT;
  const __hip_bfloat16* __restrict__ WloT = z ? WvloT : WkloT;
  const int ti = blockIdx.x, tj = blockIdx.y;
  // 64 KB union: 4 operand types x [2 dbuf][128*32]; Ct[128][136] epilogue.
  __shared__ __align__(16) __hip_bfloat16 smem[32768];
  __hip_bfloat16* Ah = smem;            // [2][4096]
  __hip_bfloat16* Al = smem + 8192;
  __hip_bfloat16* Wh = smem + 16384;
  __hip_bfloat16* Wl = smem + 24576;
  const int t = threadIdx.x;
  const int lane = t & 63, w = t >> 6;
  const int wm = (w >> 1) * 64, wn = (w & 1) * 64;
  const int quad = lane >> 4, ln = lane & 15;
  const int qr = quad * 8;
  floatx4 acc[4][4];
#pragma unroll
  for (int mi = 0; mi < 4; mi++)
#pragma unroll
    for (int ni = 0; ni < 4; ni++) acc[mi][ni] = (floatx4)0.f;

  auto STAGE = [&](int st, int buf) {
    const int k0 = st * 32;
#pragma unroll
    for (int s = 0; s < 2; s++) {
      int c = t + s * 256;
      int row = c >> 2, off8 = (c & 3) * 8;
      int lo = buf * 4096 + row * 32 + off8;  // wave-uniform + lane*16
      long ga = (long)(ti * 128 + row) * FEAT + k0 + off8;
      long gw = (long)(tj * 128 + row) * FEAT + k0 + off8;
      async_copy16(&Ahi[ga], &Ah[lo]);
      async_copy16(&Alo[ga], &Al[lo]);
      async_copy16(&WhiT[gw], &Wh[lo]);
      async_copy16(&WloT[gw], &Wl[lo]);
    }
  };
  STAGE(0, 0);
  __syncthreads();  // drain prologue loads (compiler emits vmcnt(0))
  for (int st = 0; st < 16; st++) {
    const int buf = st & 1;
    if (st < 15) STAGE(st + 1, buf ^ 1);  // prefetch next into other buffer
    short8 ah[4], al[4], bh[4], bl[4];
#pragma unroll
    for (int mi = 0; mi < 4; mi++) {
      ah[mi] = *(const short8*)&Ah[buf * 4096 + (wm + mi * 16 + ln) * 32 + qr];
      al[mi] = *(const short8*)&Al[buf * 4096 + (wm + mi * 16 + ln) * 32 + qr];
    }
#pragma unroll
    for (int ni = 0; ni < 4; ni++) {
      bh[ni] = *(const short8*)&Wh[buf * 4096 + (wn + ni * 16 + ln) * 32 + qr];
      bl[ni] = *(const short8*)&Wl[buf * 4096 + (wn + ni * 16 + ln) * 32 + qr];
    }
#pragma unroll
    for (int mi = 0; mi < 4; mi++)
#pragma unroll
      for (int ni = 0; ni < 4; ni++) {
        acc[mi][ni] = __builtin_amdgcn_mfma_f32_16x16x32_bf16(
            ah[mi], bh[ni], acc[mi][ni], 0, 0, 0);
        acc[mi][ni] = __builtin_amdgcn_mfma_f32_16x16x32_bf16(
            ah[mi], bl[ni], acc[mi][ni], 0, 0, 0);
        acc[mi][ni] = __builtin_amdgcn_mfma_f32_16x16x32_bf16(
            al[mi], bh[ni], acc[mi][ni], 0, 0, 0);
      }
    __syncthreads();  // drains next-step loads + all waves' ds_reads of buf
  }
  if (z == 0) {
    // loop-end barrier already guarantees LDS reads drained -> safe to reuse
    __hip_bfloat16* Ct = smem;  // [128][136]
#pragma unroll
    for (int mi = 0; mi < 4; mi++)
#pragma unroll
      for (int ni = 0; ni < 4; ni++) {
        int col = wn + ni * 16 + ln;
#pragma unroll
        for (int reg = 0; reg < 4; reg++) {
          int row = wm + mi * 16 + quad * 4 + reg;
          Ct[row * 136 + col] = __float2bfloat16(acc[mi][ni][reg]);
        }
      }
    __syncthreads();
#pragma unroll
    for (int i = 0; i < 8; i++) {
      int idx = t + i * 256;
      int rl = idx >> 4, c8 = (idx & 15) * 8;
      int gr = iperm[ti * 128 + rl];
      *(short8*)&khp[(long)gr * FEAT + tj * 128 + c8] =
          *(const short8*)&Ct[rl * 136 + c8];
    }
  } else {
#pragma unroll
    for (int mi = 0; mi < 4; mi++)
#pragma unroll
      for (int ni = 0; ni < 4; ni++) {
        int cc = tj * 128 + wn + ni * 16 + ln;
#pragma unroll
        for (int reg = 0; reg < 4; reg++) {
          int r = ti * 128 + wm + mi * 16 + quad * 4 + reg;
          vh[(long)r * FEAT + cc] = acc[mi][ni][reg];
        }
      }
  }
}

// ---------------------------------------------------------------------------
// cw[f][b] = sum_h kW[f][h] * rot[h][b]  (fp64)
// ---------------------------------------------------------------------------
__global__ __launch_bounds__(64) void cw_kernel(
    const float* __restrict__ kW, const float* __restrict__ rot,
    double* __restrict__ cw) {
  const int f = blockIdx.x;
  const int lane = threadIdx.x;
  double r0 = 0.0, r1 = 0.0;
  for (int h = lane; h < FEAT; h += 64) {
    double a = (double)kW[(long)f * FEAT + h];
    r0 += a * (double)rot[2 * h];
    r1 += a * (double)rot[2 * h + 1];
  }
#pragma unroll
  for (int off = 32; off > 0; off >>= 1) {
    r0 += __shfl_down(r0, off);
    r1 += __shfl_down(r1, off);
  }
  if (lane == 0) {
    cw[2 * f] = r0;
    cw[2 * f + 1] = r1;
  }
}

// ---------------------------------------------------------------------------
// buckets from EXACT inputs: rv = input @ cw in fp64; argmax([r0,r1,-r0,-r1])
// ---------------------------------------------------------------------------
__global__ __launch_bounds__(64) void rv_bucket_kernel(
    const float* __restrict__ input, const double* __restrict__ cw,
    int* __restrict__ buckets) {
  const int i = blockIdx.x;
  const int lane = threadIdx.x;
  double r0 = 0.0, r1 = 0.0;
  for (int f = lane; f < FEAT; f += 64) {
    double a = (double)input[(long)i * FEAT + f];
    r0 += a * cw[2 * f];
    r1 += a * cw[2 * f + 1];
  }
#pragma unroll
  for (int off = 32; off > 0; off >>= 1) {
    r0 += __shfl_down(r0, off);
    r1 += __shfl_down(r1, off);
  }
  if (lane == 0) {
    int b = 0;
    double best = r0;
    if (r1 > best)  { best = r1;  b = 1; }
    if (-r0 > best) { best = -r0; b = 2; }
    if (-r1 > best) { best = -r1; b = 3; }
    buckets[i] = b;
  }
}

// ---------------------------------------------------------------------------
// Stable counting sort by bucket (1 block, parallel Hillis-Steele scan).
// Emits perm AND inverse perm. Also zeroes cmean and rowsum.
// ---------------------------------------------------------------------------
__global__ __launch_bounds__(256) void sort_kernel(
    const int* __restrict__ buckets, int* __restrict__ perm,
    int* __restrict__ iperm, int* __restrict__ meta,
    float* __restrict__ cmean, float* __restrict__ rowsum) {
  __shared__ int lc[4][256];
  __shared__ int sc[4][256];
  __shared__ int boff_sh[5];
  const int t = threadIdx.x;
  cmean[t] = 0.f;
  cmean[t + 256] = 0.f;
  for (int k = t; k < N_NODES; k += 256) rowsum[k] = 0.f;
  const int base = t * 32;
  int c0 = 0, c1 = 0, c2 = 0, c3 = 0;
  for (int k = 0; k < 32; k++) {
    int b = buckets[base + k];
    c0 += (b == 0); c1 += (b == 1); c2 += (b == 2); c3 += (b == 3);
  }
  lc[0][t] = c0; lc[1][t] = c1; lc[2][t] = c2; lc[3][t] = c3;
  sc[0][t] = c0; sc[1][t] = c1; sc[2][t] = c2; sc[3][t] = c3;
  __syncthreads();
  for (int off = 1; off < 256; off <<= 1) {
    int a0 = (t >= off) ? sc[0][t - off] : 0;
    int a1 = (t >= off) ? sc[1][t - off] : 0;
    int a2 = (t >= off) ? sc[2][t - off] : 0;
    int a3 = (t >= off) ? sc[3][t - off] : 0;
    __syncthreads();
    sc[0][t] += a0; sc[1][t] += a1; sc[2][t] += a2; sc[3][t] += a3;
    __syncthreads();
  }
  if (t == 0) {
    int boff[5];
    boff[0] = 0;
    for (int b = 0; b < 4; b++) boff[b + 1] = boff[b] + sc[b][255];
    for (int b = 0; b < 5; b++) { meta[b] = boff[b]; boff_sh[b] = boff[b]; }
    long so = 0;
    int po = 0;
    for (int b = 0; b < 4; b++) {
      int tot = boff[b + 1] - boff[b];
      int pad = ((tot + 127) >> 7) << 7;
      meta[5 + b] = pad;
      meta[9 + b] = (int)so;
      meta[14 + b] = po;
      so += (long)pad * pad;
      po += pad;
    }
    meta[13] = (int)so;
    meta[18] = po;
    if (so > CAP_S)
      for (int b = 0; b < 4; b++) meta[5 + b] = 0;
  }
  __syncthreads();
  int s0 = boff_sh[0] + sc[0][t] - lc[0][t];
  int s1 = boff_sh[1] + sc[1][t] - lc[1][t];
  int s2 = boff_sh[2] + sc[2][t] - lc[2][t];
  int s3 = boff_sh[3] + sc[3][t] - lc[3][t];
  for (int k = 0; k < 32; k++) {
    int i = base + k;
    int b = buckets[i];
    int pos = (b == 0) ? s0++ : ((b == 1) ? s1++ : ((b == 2) ? s2++ : s3++));
    perm[pos] = i;
    iperm[i] = pos;
  }
}

// ---------------------------------------------------------------------------
// vhpT[f][poff_b + local] = bf16(vh[perm[boff_b + local]][f]); pads zeroed.
// Fused cmean column-sum accumulation (cmean pre-zeroed by sort_kernel).
// ---------------------------------------------------------------------------
__global__ __launch_bounds__(256) void transpose_vhpT_kernel(
    const float* __restrict__ vh, const int* __restrict__ perm,
    const int* __restrict__ meta, __hip_bfloat16* __restrict__ vhpT,
    float* __restrict__ cmean) {
  __shared__ float tile[64][65];
  __shared__ float cred[4][64];
  const int g0 = blockIdx.x * 64;
  const int f0 = blockIdx.y * 64;
  const int t = threadIdx.x;
#pragma unroll
  for (int s = 0; s < 16; s++) {
    int idx = t + s * 256;
    int r = idx >> 6, c = idx & 63;
    int pos = g0 + r;
    int b = (pos >= meta[15]) + (pos >= meta[16]) + (pos >= meta[17]);
    int local = pos - meta[14 + b];
    int n_b = meta[b + 1] - meta[b];
    float v = 0.f;
    if (local < n_b) v = vh[(long)perm[meta[b] + local] * FEAT + f0 + c];
    tile[r][c] = v;
  }
  __syncthreads();
  {
    const int c = t & 63, seg = t >> 6;
    float ps = 0.f;
#pragma unroll
    for (int rr = 0; rr < 16; rr++) ps += tile[seg * 16 + rr][c];
    cred[seg][c] = ps;
  }
  __syncthreads();
  if (t < 64)
    atomicAdd(&cmean[f0 + t],
              cred[0][t] + cred[1][t] + cred[2][t] + cred[3][t]);
#pragma unroll
  for (int s = 0; s < 16; s++) {
    int idx = t + s * 256;
    int fr = idx >> 6, gc = idx & 63;
    vhpT[(long)(f0 + fr) * VHPT_W + g0 + gc] = __float2bfloat16(tile[gc][fr]);
  }
}

// ---------------------------------------------------------------------------
// maskbits[g][jj] = (adj[perm[g]][perm[boff_b+jj]] > 0), bit-packed per 64.
// Runs EARLY (right after sort): its 268 MB adj stream evicts L3, so all
// later producer->consumer buffers (khp, vhpT, S) stay L3-resident.
// ---------------------------------------------------------------------------
__global__ __launch_bounds__(256) void maskpack_kernel(
    const int* __restrict__ adj, const int* __restrict__ perm,
    const int* __restrict__ meta, unsigned long long* __restrict__ maskbits) {
  __shared__ int adj_lds[N_NODES];
  const int g = blockIdx.x;
  const int t = threadIdx.x;
  const int b = (g >= meta[1]) + (g >= meta[2]) + (g >= meta[3]);
  const int boff = meta[b];
  const int n_b = meta[b + 1] - boff;
  const int padded = meta[5 + b];
  const int i = perm[g];
  const int* arow = adj + (long)i * N_NODES;
#pragma unroll
  for (int s = 0; s < 8; s++) {
    int idx = (t + s * 256) * 4;
    *(int4*)&adj_lds[idx] = *(const int4*)&arow[idx];
  }
  __syncthreads();
  const int lane = t & 63, w = t >> 6;
  for (int jj0 = w * 64; jj0 < padded; jj0 += 256) {
    int jj = jj0 + lane;
    int pred = 0;
    if (jj < n_b) pred = adj_lds[perm[boff + jj]] > 0;
    unsigned long long mword = __ballot(pred);
    if (lane == 0) maskbits[(long)g * 128 + (jj0 >> 6)] = mword;
  }
}

// ---------------------------------------------------------------------------
// S tile = khp_b . khp_b^T (bf16 MFMA). DOUBLE-BUFFERED prefetch: per 64-wide
// K-step, issue next-step loads into buf^1 before computing buf; one barrier
// per step. FUSED NO-MAX SOFTMAX NUMERATOR: epilogue stores
// P~ = bf16(exp(S/sqrt(H))) (masked -> 0) and accumulates f32 row sums via
// 16-lane shfl reduce + one atomicAdd per (row, tile). Scores are bounded
// (~50 << 88) so f32 exp cannot overflow; exp(S)/sum == softmax exactly.
// Triangular grid ti <= tj; both orientations written from an LDS tile with
// coalesced 16B stores. Pad rows excluded from row-sum atomics.
// ---------------------------------------------------------------------------
__global__ __launch_bounds__(256) void s_gemm(
    const __hip_bfloat16* __restrict__ khp, const int* __restrict__ meta,
    const unsigned long long* __restrict__ maskbits,
    __hip_bfloat16* __restrict__ S, float* __restrict__ rowsum) {
  const int b = blockIdx.z;
  const int padded = meta[5 + b];
  const int T = padded >> 7;
  const int pairs = (T * (T + 1)) >> 1;
  int L = blockIdx.x;
  if (L >= pairs) return;
  int ti = 0;
  while (L >= T - ti) { L -= T - ti; ti++; }
  const int tj = ti + L;
  const int boff = meta[b];
  const int n_b = meta[b + 1] - boff;
  const long soff = meta[9 + b];
  // 64 KB: As/Bs each [2 dbuf][2 panels][4096]; Ct[128][136] epilogue.
  __shared__ __align__(16) __hip_bfloat16 smem[32768];
  __hip_bfloat16* As = smem;            // [2][2][4096]
  __hip_bfloat16* Bs = smem + 16384;    // [2][2][4096]
  const int t = threadIdx.x;
  const int lane = t & 63, w = t >> 6;
  const int wm = (w >> 1) * 64, wn = (w & 1) * 64;
  const int quad = lane >> 4, ln = lane & 15;
  const int qr = quad * 8;
  floatx4 acc[4][4];
#pragma unroll
  for (int mi = 0; mi < 4; mi++)
#pragma unroll
    for (int ni = 0; ni < 4; ni++) acc[mi][ni] = (floatx4)0.f;
  const long a_g0 = boff + ti * 128;
  const long b_g0 = boff + tj * 128;

  auto STAGE = [&](int st, int buf) {
    const int k0 = st * 64;
#pragma unroll
    for (int p = 0; p < 2; p++)
#pragma unroll
      for (int s = 0; s < 2; s++) {
        int c = t + s * 256;
        int row = c >> 2, off8 = (c & 3) * 8;
        int lo = buf * 8192 + p * 4096 + row * 32 + off8;
        async_copy16(&khp[(a_g0 + row) * FEAT + k0 + p * 32 + off8], &As[lo]);
        async_copy16(&khp[(b_g0 + row) * FEAT + k0 + p * 32 + off8], &Bs[lo]);
      }
  };
  STAGE(0, 0);
  __syncthreads();
  for (int st = 0; st < 8; st++) {
    const int buf = st & 1;
    if (st < 7) STAGE(st + 1, buf ^ 1);
#pragma unroll
    for (int p = 0; p < 2; p++) {
      short8 af[4], bfr[4];
#pragma unroll
      for (int mi = 0; mi < 4; mi++)
        af[mi] = *(const short8*)&As[buf * 8192 + p * 4096 +
                                     (wm + mi * 16 + ln) * 32 + qr];
#pragma unroll
      for (int ni = 0; ni < 4; ni++)
        bfr[ni] = *(const short8*)&Bs[buf * 8192 + p * 4096 +
                                      (wn + ni * 16 + ln) * 32 + qr];
#pragma unroll
      for (int mi = 0; mi < 4; mi++)
#pragma unroll
        for (int ni = 0; ni < 4; ni++)
          acc[mi][ni] = __builtin_amdgcn_mfma_f32_16x16x32_bf16(
              af[mi], bfr[ni], acc[mi][ni], 0, 0, 0);
    }
    __syncthreads();
  }
  // ---- epilogue: P~ = bf16(exp(acc*scale)) -> LDS tile (unmasked) ----
  // loop-end barrier already drained all ds_reads -> safe to reuse smem.
  const float scale = 0.04419417382415922f;  // 1/sqrt(512)
  __hip_bfloat16* Ct = smem;  // [128][136]
#pragma unroll
  for (int mi = 0; mi < 4; mi++)
#pragma unroll
    for (int ni = 0; ni < 4; ni++) {
      int col = wn + ni * 16 + ln;
#pragma unroll
      for (int reg = 0; reg < 4; reg++) {
        int row = wm + mi * 16 + quad * 4 + reg;
        Ct[row * 136 + col] =
            __float2bfloat16(__expf(acc[mi][ni][reg] * scale));
      }
    }
  __syncthreads();
  // normal orientation: coalesced 16B stores of rows of the ti-block
#pragma unroll
  for (int i = 0; i < 8; i++) {
    int idx = t + i * 256;
    int rl = idx >> 4, c8 = (idx & 15) * 8;
    int rg = ti * 128 + rl;
    int cg = tj * 128 + c8;
    union { short8 v; unsigned short u[8]; } pk;
    pk.v = *(const short8*)&Ct[rl * 136 + c8];
    unsigned long long wbits = maskbits[(long)(boff + rg) * 128 + (cg >> 6)];
    float ps = 0.f;
#pragma unroll
    for (int e = 0; e < 8; e++) {
      if (!((wbits >> ((cg & 63) + e)) & 1ULL)) pk.u[e] = 0;
      ps += bf_bits2f(pk.u[e]);
    }
    *(short8*)&S[soff + (long)rg * padded + cg] = pk.v;
    // per-row partial sum: 16 consecutive lanes share rg
#pragma unroll
    for (int off = 1; off < 16; off <<= 1) ps += __shfl_xor(ps, off);
    if (rg < n_b && (lane & 15) == 0)
      atomicAdd(&rowsum[boff + rg], ps);
  }
  // mirrored orientation (tj-block rows), skipped on diagonal
  if (ti != tj) {
#pragma unroll
    for (int i = 0; i < 8; i++) {
      int idx = t + i * 256;
      int cl = idx >> 4, r8 = (idx & 15) * 8;
      int rg = tj * 128 + cl;   // output row (column of the computed tile)
      int cg = ti * 128 + r8;   // output col base
      union { short8 v; unsigned short u[8]; } pk;
#pragma unroll
      for (int e = 0; e < 8; e++) {
        __hip_bfloat16 hv = Ct[(r8 + e) * 136 + cl];
        __builtin_memcpy(&pk.u[e], &hv, 2);
      }
      unsigned long long wbits = maskbits[(long)(boff + rg) * 128 + (cg >> 6)];
      float ps = 0.f;
#pragma unroll
      for (int e = 0; e < 8; e++) {
        if (!((wbits >> ((cg & 63) + e)) & 1ULL)) pk.u[e] = 0;
        ps += bf_bits2f(pk.u[e]);
      }
      *(short8*)&S[soff + (long)rg * padded + cg] = pk.v;
#pragma unroll
      for (int off = 1; off < 16; off <<= 1) ps += __shfl_xor(ps, off);
      if (rg < n_b && (lane & 15) == 0)
        atomicAdd(&rowsum[boff + rg], ps);
    }
  }
}

// ---------------------------------------------------------------------------
// O tile = P~ . vhp (pure bf16 GEMM), 64 rows x 128 features per block.
// DOUBLE-BUFFERED prefetch per 64-wide K-step, one barrier per step.
// Epilogue: x (1/rowsum) (softmax denom, exact) + ELU + empty-row
// (rowsum==0) cmean fallback + scatter to out[perm[g]].
// ---------------------------------------------------------------------------
__global__ __launch_bounds__(256) void pv_gemm(
    const __hip_bfloat16* __restrict__ S, const __hip_bfloat16* __restrict__ vhpT,
    const int* __restrict__ meta, const int* __restrict__ perm,
    const float* __restrict__ cmean, const float* __restrict__ rowsum,
    float* __restrict__ out) {
  const int b = blockIdx.z;
  const int padded = meta[5 + b];
  const int ti = blockIdx.x;
  if (ti * 64 >= padded) return;
  const int boff = meta[b];
  const int n_b = meta[b + 1] - boff;
  const long soff = meta[9 + b];
  const int poff = meta[14 + b];
  const int f0 = blockIdx.y * 128;
  __shared__ __align__(16) __hip_bfloat16 As[2 * 2 * 2048];  // 16 KB
  __shared__ __align__(16) __hip_bfloat16 Bs[2 * 2 * 4096];  // 32 KB
  const int t = threadIdx.x;
  const int lane = t & 63, w = t >> 6;
  const int wm = (w >> 1) * 32, wn = (w & 1) * 64;
  const int quad = lane >> 4, ln = lane & 15;
  const int qr = quad * 8;
  floatx4 acc[2][4];
#pragma unroll
  for (int mi = 0; mi < 2; mi++)
#pragma unroll
    for (int ni = 0; ni < 4; ni++) acc[mi][ni] = (floatx4)0.f;
  const long r0 = (long)ti * 64;

  auto STAGE = [&](int st, int buf) {
    const int k0 = st * 64;
#pragma unroll
    for (int p = 0; p < 2; p++) {
      {
        int row = t >> 2, off8 = (t & 3) * 8;
        async_copy16(&S[soff + (r0 + row) * padded + k0 + p * 32 + off8],
                     &As[buf * 4096 + p * 2048 + row * 32 + off8]);
      }
#pragma unroll
      for (int s = 0; s < 2; s++) {
        int c = t + s * 256;
        int row = c >> 2, off8 = (c & 3) * 8;
        async_copy16(
            &vhpT[(long)(f0 + row) * VHPT_W + poff + k0 + p * 32 + off8],
            &Bs[buf * 8192 + p * 4096 + row * 32 + off8]);
      }
    }
  };
  const int NS = padded >> 6;
  STAGE(0, 0);
  __syncthreads();
  for (int st = 0; st < NS; st++) {
    const int buf = st & 1;
    if (st + 1 < NS) STAGE(st + 1, buf ^ 1);
#pragma unroll
    for (int p = 0; p < 2; p++) {
      short8 af[2], bfr[4];
#pragma unroll
      for (int mi = 0; mi < 2; mi++)
        af[mi] = *(const short8*)&As[buf * 4096 + p * 2048 +
                                     (wm + mi * 16 + ln) * 32 + qr];
#pragma unroll
      for (int ni = 0; ni < 4; ni++)
        bfr[ni] = *(const short8*)&Bs[buf * 8192 + p * 4096 +
                                      (wn + ni * 16 + ln) * 32 + qr];
#pragma unroll
      for (int mi = 0; mi < 2; mi++)
#pragma unroll
        for (int ni = 0; ni < 4; ni++)
          acc[mi][ni] = __builtin_amdgcn_mfma_f32_16x16x32_bf16(
              af[mi], bfr[ni], acc[mi][ni], 0, 0, 0);
    }
    __syncthreads();
  }
#pragma unroll
  for (int mi = 0; mi < 2; mi++) {
#pragma unroll
    for (int reg = 0; reg < 4; reg++) {
      int r = ti * 64 + wm + mi * 16 + quad * 4 + reg;
      if (r < n_b) {
        int g = boff + r;
        int node = perm[g];
        float rs = rowsum[g];
        int fl = (rs == 0.f);
        float inv = fl ? 0.f : 1.f / rs;
#pragma unroll
        for (int ni = 0; ni < 4; ni++) {
          int fc = f0 + wn + ni * 16 + ln;
          float v = fl ? cmean[fc] * (1.f / (float)N_NODES)
                       : acc[mi][ni][reg] * inv;
          v = v > 0.f ? v : expm1f(v);
          out[(long)node * FEAT + fc] = v;
        }
      }
    }
  }
}

// ===========================================================================
// Slow-path fallback (only if ws_size < WS_NEEDED): round-1 implementation.
// ===========================================================================
__global__ __launch_bounds__(256) void gemm_dual(
    const float* __restrict__ A, const float* __restrict__ Wk,
    const float* __restrict__ Wv, float* __restrict__ kh,
    float* __restrict__ vh) {
  __shared__ float As[32][33];
  __shared__ float Bk[32][33];
  __shared__ float Bv[32][33];
  const int tid = threadIdx.x;
  const int row0 = blockIdx.x * 32;
  const int col0 = blockIdx.y * 32;
  const int tx = tid & 15, ty = tid >> 4;
  float ck00 = 0.f, ck01 = 0.f, ck10 = 0.f, ck11 = 0.f;
  float cv00 = 0.f, cv01 = 0.f, cv10 = 0.f, cv11 = 0.f;
  for (int kt = 0; kt < FEAT; kt += 32) {
#pragma unroll
    for (int t = 0; t < 4; t++) {
      int e = tid + t * 256;
      int r = e >> 5, c = e & 31;
      As[r][c] = A[(long)(row0 + r) * FEAT + kt + c];
      Bk[r][c] = Wk[(long)(kt + r) * FEAT + col0 + c];
      Bv[r][c] = Wv[(long)(kt + r) * FEAT + col0 + c];
    }
    __syncthreads();
#pragma unroll
    for (int kk = 0; kk < 32; kk++) {
      float a0 = As[ty * 2][kk], a1 = As[ty * 2 + 1][kk];
      float bk0 = Bk[kk][tx * 2], bk1 = Bk[kk][tx * 2 + 1];
      float bv0 = Bv[kk][tx * 2], bv1 = Bv[kk][tx * 2 + 1];
      ck00 += a0 * bk0; ck01 += a0 * bk1;
      ck10 += a1 * bk0; ck11 += a1 * bk1;
      cv00 += a0 * bv0; cv01 += a0 * bv1;
      cv10 += a1 * bv0; cv11 += a1 * bv1;
    }
    __syncthreads();
  }
  const int r0 = row0 + ty * 2, c0 = col0 + tx * 2;
  kh[(long)r0 * FEAT + c0] = ck00;       kh[(long)r0 * FEAT + c0 + 1] = ck01;
  kh[(long)(r0 + 1) * FEAT + c0] = ck10; kh[(long)(r0 + 1) * FEAT + c0 + 1] = ck11;
  vh[(long)r0 * FEAT + c0] = cv00;       vh[(long)r0 * FEAT + c0 + 1] = cv01;
  vh[(long)(r0 + 1) * FEAT + c0] = cv10; vh[(long)(r0 + 1) * FEAT + c0 + 1] = cv11;
}

__global__ __launch_bounds__(64) void bucket_kernel(
    const float* __restrict__ kh, const float* __restrict__ rot,
    int* __restrict__ buckets) {
  const int i = blockIdx.x;
  const int lane = threadIdx.x;
  double r0 = 0.0, r1 = 0.0;
  for (int h = lane; h < FEAT; h += 64) {
    double a = (double)kh[(long)i * FEAT + h];
    r0 += a * (double)rot[2 * h];
    r1 += a * (double)rot[2 * h + 1];
  }
#pragma unroll
  for (int off = 32; off > 0; off >>= 1) {
    r0 += __shfl_down(r0, off);
    r1 += __shfl_down(r1, off);
  }
  if (lane == 0) {
    int b = 0;
    double best = r0;
    if (r1 > best)  { best = r1;  b = 1; }
    if (-r0 > best) { best = -r0; b = 2; }
    if (-r1 > best) { best = -r1; b = 3; }
    buckets[i] = b;
  }
}

__global__ __launch_bounds__(256) void attn_kernel(
    const float* __restrict__ kh, const float* __restrict__ vh,
    const int* __restrict__ adj, const int* __restrict__ buckets,
    float* __restrict__ out) {
  __shared__ float khi[FEAT];
  __shared__ float pbuf[N_NODES];
  __shared__ unsigned short jlist[N_NODES];
  __shared__ int cnt_sh;
  __shared__ float red[256];
  const int i = blockIdx.x;
  const int tid = threadIdx.x;
  if (tid == 0) cnt_sh = 0;
  for (int k = tid; k < FEAT; k += 256) khi[k] = kh[(long)i * FEAT + k];
  const int mybucket = buckets[i];
  __syncthreads();
  const int* adjrow = adj + (long)i * N_NODES;
  for (int j = tid; j < N_NODES; j += 256) {
    if (adjrow[j] > 0 && buckets[j] == mybucket) {
      int idx = atomicAdd(&cnt_sh, 1);
      jlist[idx] = (unsigned short)j;
    }
  }
  __syncthreads();
  const int cnt = cnt_sh;
  float mloc = -INFINITY;
  for (int idx = tid; idx < cnt; idx += 256) {
    int j = jlist[idx];
    const float4* kj = (const float4*)(kh + (long)j * FEAT);
    const float4* ki = (const float4*)khi;
    float acc = 0.f;
#pragma unroll 8
    for (int k = 0; k < FEAT / 4; k++) {
      float4 a = ki[k];
      float4 b = kj[k];
      acc += a.x * b.x + a.y * b.y + a.z * b.z + a.w * b.w;
    }
    float s = acc * 0.04419417382415922f;
    pbuf[idx] = s;
    mloc = fmaxf(mloc, s);
  }
  red[tid] = mloc;
  __syncthreads();
#pragma unroll
  for (int off = 128; off > 0; off >>= 1) {
    if (tid < off) red[tid] = fmaxf(red[tid], red[tid + off]);
    __syncthreads();
  }
  const float m = red[0];
  __syncthreads();
  float lloc = 0.f;
  for (int idx = tid; idx < cnt; idx += 256) {
    float p = expf(pbuf[idx] - m);
    pbuf[idx] = p;
    lloc += p;
  }
  red[tid] = lloc;
  __syncthreads();
#pragma unroll
  for (int off = 128; off > 0; off >>= 1) {
    if (tid < off) red[tid] += red[tid + off];
    __syncthreads();
  }
  const float l = red[0];
  __syncthreads();
  const int f = 2 * tid;
  float acc0 = 0.f, acc1 = 0.f;
  if (cnt > 0) {
#pragma unroll 4
    for (int idx = 0; idx < cnt; idx++) {
      int j = jlist[idx];
      float p = pbuf[idx];
      float2 v = *(const float2*)(vh + (long)j * FEAT + f);
      acc0 += p * v.x;
      acc1 += p * v.y;
    }
    float invl = 1.f / l;
    acc0 *= invl;
    acc1 *= invl;
  } else {
    for (int j = 0; j < N_NODES; j++) {
      float2 v = *(const float2*)(vh + (long)j * FEAT + f);
      acc0 += v.x;
      acc1 += v.y;
    }
    acc0 *= (1.f / (float)N_NODES);
    acc1 *= (1.f / (float)N_NODES);
  }
  acc0 = acc0 > 0.f ? acc0 : expm1f(acc0);
  acc1 = acc1 > 0.f ? acc1 : expm1f(acc1);
  *(float2*)(out + (long)i * FEAT + f) = make_float2(acc0, acc1);
}

extern "C" void kernel_launch(void* const* d_in, const int* in_sizes, int n_in,
                              void* d_out, int out_size, void* d_ws,
                              size_t ws_size, hipStream_t stream) {
  const float* input = (const float*)d_in[0];
  const int* adj = (const int*)d_in[1];
  const float* rot = (const float*)d_in[2];
  const float* kW = (const float*)d_in[3];
  const float* vW = (const float*)d_in[4];
  float* out = (float*)d_out;

  char* ws = (char*)d_ws;

  if (ws_size >= WS_NEEDED) {
    float* vh = (float*)(ws + OFF_VH);
    __hip_bfloat16* khp = (__hip_bfloat16*)(ws + OFF_KHP);
    __hip_bfloat16* vhpT = (__hip_bfloat16*)(ws + OFF_VHPT);
    unsigned long long* maskbits = (unsigned long long*)(ws + OFF_MASK);
    __hip_bfloat16* S = (__hip_bfloat16*)(ws + OFF_S);
    int* perm = (int*)(ws + OFF_PERM);
    int* iperm = (int*)(ws + OFF_IPERM);
    int* buckets = (int*)(ws + OFF_BUCK);
    int* meta = (int*)(ws + OFF_META);
    float* cmean = (float*)(ws + OFF_CMEAN);
    float* rowsum = (float*)(ws + OFF_ROWI);
    __hip_bfloat16* Ahi = (__hip_bfloat16*)(ws + OFF_AHI);
    __hip_bfloat16* Alo = (__hip_bfloat16*)(ws + OFF_ALO);
    __hip_bfloat16* WkhiT = (__hip_bfloat16*)(ws + OFF_WKHI);
    __hip_bfloat16* WkloT = (__hip_bfloat16*)(ws + OFF_WKLO);
    __hip_bfloat16* WvhiT = (__hip_bfloat16*)(ws + OFF_WVHI);
    __hip_bfloat16* WvloT = (__hip_bfloat16*)(ws + OFF_WVLO);
    double* cw = (double*)(ws + OFF_CW);

    // zero khp tail rows [8192, 8320) — read (masked) by s_gemm/pv when the
    // last bucket's padding spills past N.
    hipMemsetAsync(ws + OFF_KHP + (size_t)N_NODES * FEAT * 2, 0,
                   128 * FEAT * 2, stream);
    // ---- L3-aware schedule: the 268 MB adj stream (maskpack) runs BEFORE
    // any producer->consumer bf16 buffers are written, so khp/vhpT/S stay
    // L3-resident through the GEMM back half.
    cw_kernel<<<512, 64, 0, stream>>>(kW, rot, cw);
    rv_bucket_kernel<<<N_NODES, 64, 0, stream>>>(input, cw, buckets);
    sort_kernel<<<1, 256, 0, stream>>>(buckets, perm, iperm, meta, cmean,
                                       rowsum);
    maskpack_kernel<<<N_NODES, 256, 0, stream>>>(adj, perm, meta, maskbits);
    convert_input<<<4096, 256, 0, stream>>>(input, Ahi, Alo);
    convert_w<<<dim3(8, 8, 2), 256, 0, stream>>>(kW, vW, WkhiT, WkloT, WvhiT,
                                                 WvloT);
    mfma_dual<<<dim3(64, 4, 2), 256, 0, stream>>>(Ahi, Alo, WkhiT, WkloT,
                                                  WvhiT, WvloT, iperm, khp,
                                                  vh);
    transpose_vhpT_kernel<<<dim3(VHPT_W / 64, FEAT / 64), 256, 0, stream>>>(
        vh, perm, meta, vhpT, cmean);
    s_gemm<<<dim3(2080, 1, 4), 256, 0, stream>>>(khp, meta, maskbits, S,
                                                 rowsum);
    pv_gemm<<<dim3(128, 4, 4), 256, 0, stream>>>(S, vhpT, meta, perm, cmean,
                                                 rowsum, out);
  } else {
    float* kh = (float*)(ws + 0UL);
    float* vh = (float*)(ws + 16777216UL);
    int* buckets = (int*)(ws + 33554432UL);
    dim3 gemm_grid(N_NODES / 32, FEAT / 32);
    gemm_dual<<<gemm_grid, 256, 0, stream>>>(input, kW, vW, kh, vh);
    bucket_kernel<<<N_NODES, 64, 0, stream>>>(kh, rot, buckets);
    attn_kernel<<<N_NODES, 256, 0, stream>>>(kh, vh, adj, buckets, out);
  }
}

// Round 6
// 545.824 us; speedup vs baseline: 1.2383x; 1.0303x over previous
//
#include <hip/hip_runtime.h>
#include <hip/hip_bf16.h>
#include <math.h>

#define N_NODES 8192
#define FEAT 512
#define NEGV -9e15f
#define VHPT_W 8704

typedef __attribute__((ext_vector_type(8))) short short8;
typedef __attribute__((ext_vector_type(4))) float floatx4;

// ---- workspace layout (bytes) ----
#define OFF_KH    0UL          // (dead in fast path; kept for layout stability)
#define OFF_VH    16777216UL   // f32 vh [8192][512]
#define OFF_KHP   33554432UL   // bf16 [8320][512]
#define OFF_VHPT  42074112UL   // bf16 [512][8704]  (padded-position columns)
#define OFF_MASK  50987008UL   // u64 [8192][128]; head reused early for cw (f64[1024])
#define OFF_S     59375616UL   // bf16 S, cap 25165824 elems; head reused early for Ab/W*T
#define OFF_PERM  109707264UL
#define OFF_FLAGS 109740032UL  // (unused)
#define OFF_BUCK  109772800UL
#define OFF_META  109805568UL  // ints: [0..4]=boff [5..8]=padded [9..13]=soff(+tot) [14..18]=poff
#define OFF_CMEAN 109806592UL
#define OFF_ROWM  109808640UL  // (unused)
#define OFF_ROWI  109841408UL  // f32 [8192] row sum of stored P~ (exp(S), masked->0)
#define OFF_IPERM 109874176UL  // int [8192] inverse permutation
#define WS_NEEDED 109906944UL
#define CAP_S     25165824L

// aliased (early-lifetime) buffers inside the S region:
#define OFF_AB    (OFF_S)                 // bf16 [8192][512] input, bf16
#define OFF_WKT   (OFF_S + 16777216UL)    // bf16 [512][512] kW transposed
#define OFF_WVT   (OFF_S + 17825792UL)    // bf16 [512][512] vW transposed
#define OFF_CW    (OFF_MASK)              // f64 [512][2] (dead before maskpack)

static __device__ __forceinline__ unsigned short f2bf_bits(float x) {
  __hip_bfloat16 h = __float2bfloat16(x);
  unsigned short u;
  __builtin_memcpy(&u, &h, 2);
  return u;
}
static __device__ __forceinline__ float bf_bits2f(unsigned short u) {
  __hip_bfloat16 h;
  __builtin_memcpy(&h, &u, 2);
  return __bfloat162float(h);
}

// Async 16B/lane global->LDS copy (global_load_lds_dwordx4). LDS side must be
// wave-uniform base + lane*16 — all call sites below satisfy this.
static __device__ __forceinline__ void async_copy16(const void* gptr,
                                                    void* lptr) {
  __builtin_amdgcn_global_load_lds(
      (const __attribute__((address_space(1))) unsigned int*)gptr,
      (__attribute__((address_space(3))) unsigned int*)lptr, 16, 0, 0);
}

// ---------------------------------------------------------------------------
// input f32 -> bf16. (kh/vh consumers only ever see bf16 data downstream, so
// the hi/lo split was precision thrown away one kernel later — dropped.)
// ---------------------------------------------------------------------------
__global__ __launch_bounds__(256) void convert_input(
    const float* __restrict__ A, __hip_bfloat16* __restrict__ Ab) {
  const long idx = ((long)blockIdx.x * 256 + threadIdx.x) * 8;
  const float4 v0 = *(const float4*)&A[idx];
  const float4 v1 = *(const float4*)&A[idx + 4];
  const float vv[8] = {v0.x, v0.y, v0.z, v0.w, v1.x, v1.y, v1.z, v1.w};
  union { short8 s; unsigned short u[8]; } o;
#pragma unroll
  for (int e = 0; e < 8; e++) o.u[e] = f2bf_bits(vv[e]);
  *(short8*)&Ab[idx] = o.s;
}

// ---------------------------------------------------------------------------
// W[k][n] f32 -> transposed bf16: WT[n][k]. z=0: kW, z=1: vW.
// ---------------------------------------------------------------------------
__global__ __launch_bounds__(256) void convert_w(
    const float* __restrict__ kW, const float* __restrict__ vW,
    __hip_bfloat16* __restrict__ WkT, __hip_bfloat16* __restrict__ WvT) {
  __shared__ float tile[64][65];
  const int z = blockIdx.z;
  const float* __restrict__ W = z ? vW : kW;
  __hip_bfloat16* __restrict__ T = z ? WvT : WkT;
  const int k0 = blockIdx.x * 64, n0 = blockIdx.y * 64;
  const int t = threadIdx.x;
#pragma unroll
  for (int s = 0; s < 16; s++) {
    int idx = t + s * 256;
    int r = idx >> 6, c = idx & 63;
    tile[r][c] = W[(long)(k0 + r) * FEAT + n0 + c];
  }
  __syncthreads();
#pragma unroll
  for (int s = 0; s < 16; s++) {
    int idx = t + s * 256;
    int a = idx >> 6, b = idx & 63;
    unsigned short h = f2bf_bits(tile[b][a]);
    __builtin_memcpy(&T[(long)(n0 + a) * FEAT + k0 + b], &h, 2);
  }
}

// ---------------------------------------------------------------------------
// kh/vh = A@W, plain bf16 MFMA (1 MFMA per output; kh error ~2^-9 relative,
// the same scale as the bf16 rounding khp/vhpT apply anyway). BK=64 dbuf,
// 32 MFMAs per barrier, 8 K-steps.
// z=0: acc -> LDS tile -> coalesced 16B row stores scattered to khp[iperm[r]].
// z=1: write vh f32 (needed for transpose+cmean).
// ---------------------------------------------------------------------------
__global__ __launch_bounds__(256) void mfma_dual(
    const __hip_bfloat16* __restrict__ Ab, const __hip_bfloat16* __restrict__ WkT,
    const __hip_bfloat16* __restrict__ WvT, const int* __restrict__ iperm,
    __hip_bfloat16* __restrict__ khp, float* __restrict__ vh) {
  const int z = blockIdx.z;
  const __hip_bfloat16* __restrict__ WT = z ? WvT : WkT;
  const int ti = blockIdx.x, tj = blockIdx.y;
  // 64 KB union: As/Ws each [2 dbuf][2 panels][4096]; Ct[128][136] epilogue.
  __shared__ __align__(16) __hip_bfloat16 smem[32768];
  __hip_bfloat16* As = smem;            // [2][2][4096]
  __hip_bfloat16* Ws = smem + 16384;    // [2][2][4096]
  const int t = threadIdx.x;
  const int lane = t & 63, w = t >> 6;
  const int wm = (w >> 1) * 64, wn = (w & 1) * 64;
  const int quad = lane >> 4, ln = lane & 15;
  const int qr = quad * 8;
  floatx4 acc[4][4];
#pragma unroll
  for (int mi = 0; mi < 4; mi++)
#pragma unroll
    for (int ni = 0; ni < 4; ni++) acc[mi][ni] = (floatx4)0.f;

  auto STAGE = [&](int st, int buf) {
    const int k0 = st * 64;
#pragma unroll
    for (int p = 0; p < 2; p++)
#pragma unroll
      for (int s = 0; s < 2; s++) {
        int c = t + s * 256;
        int row = c >> 2, off8 = (c & 3) * 8;
        int lo = buf * 8192 + p * 4096 + row * 32 + off8;
        async_copy16(&Ab[(long)(ti * 128 + row) * FEAT + k0 + p * 32 + off8],
                     &As[lo]);
        async_copy16(&WT[(long)(tj * 128 + row) * FEAT + k0 + p * 32 + off8],
                     &Ws[lo]);
      }
  };
  STAGE(0, 0);
  __syncthreads();
  for (int st = 0; st < 8; st++) {
    const int buf = st & 1;
    if (st < 7) STAGE(st + 1, buf ^ 1);
#pragma unroll
    for (int p = 0; p < 2; p++) {
      short8 af[4], bfr[4];
#pragma unroll
      for (int mi = 0; mi < 4; mi++)
        af[mi] = *(const short8*)&As[buf * 8192 + p * 4096 +
                                     (wm + mi * 16 + ln) * 32 + qr];
#pragma unroll
      for (int ni = 0; ni < 4; ni++)
        bfr[ni] = *(const short8*)&Ws[buf * 8192 + p * 4096 +
                                      (wn + ni * 16 + ln) * 32 + qr];
#pragma unroll
      for (int mi = 0; mi < 4; mi++)
#pragma unroll
        for (int ni = 0; ni < 4; ni++)
          acc[mi][ni] = __builtin_amdgcn_mfma_f32_16x16x32_bf16(
              af[mi], bfr[ni], acc[mi][ni], 0, 0, 0);
    }
    __syncthreads();
  }
  if (z == 0) {
    // loop-end barrier already drained LDS reads -> safe to reuse smem as Ct
    __hip_bfloat16* Ct = smem;  // [128][136]
#pragma unroll
    for (int mi = 0; mi < 4; mi++)
#pragma unroll
      for (int ni = 0; ni < 4; ni++) {
        int col = wn + ni * 16 + ln;
#pragma unroll
        for (int reg = 0; reg < 4; reg++) {
          int row = wm + mi * 16 + quad * 4 + reg;
          Ct[row * 136 + col] = __float2bfloat16(acc[mi][ni][reg]);
        }
      }
    __syncthreads();
#pragma unroll
    for (int i = 0; i < 8; i++) {
      int idx = t + i * 256;
      int rl = idx >> 4, c8 = (idx & 15) * 8;
      int gr = iperm[ti * 128 + rl];
      *(short8*)&khp[(long)gr * FEAT + tj * 128 + c8] =
          *(const short8*)&Ct[rl * 136 + c8];
    }
  } else {
#pragma unroll
    for (int mi = 0; mi < 4; mi++)
#pragma unroll
      for (int ni = 0; ni < 4; ni++) {
        int cc = tj * 128 + wn + ni * 16 + ln;
#pragma unroll
        for (int reg = 0; reg < 4; reg++) {
          int r = ti * 128 + wm + mi * 16 + quad * 4 + reg;
          vh[(long)r * FEAT + cc] = acc[mi][ni][reg];
        }
      }
  }
}

// ---------------------------------------------------------------------------
// cw[f][b] = sum_h kW[f][h] * rot[h][b]  (fp64)
// ---------------------------------------------------------------------------
__global__ __launch_bounds__(64) void cw_kernel(
    const float* __restrict__ kW, const float* __restrict__ rot,
    double* __restrict__ cw) {
  const int f = blockIdx.x;
  const int lane = threadIdx.x;
  double r0 = 0.0, r1 = 0.0;
  for (int h = lane; h < FEAT; h += 64) {
    double a = (double)kW[(long)f * FEAT + h];
    r0 += a * (double)rot[2 * h];
    r1 += a * (double)rot[2 * h + 1];
  }
#pragma unroll
  for (int off = 32; off > 0; off >>= 1) {
    r0 += __shfl_down(r0, off);
    r1 += __shfl_down(r1, off);
  }
  if (lane == 0) {
    cw[2 * f] = r0;
    cw[2 * f + 1] = r1;
  }
}

// ---------------------------------------------------------------------------
// buckets from EXACT inputs: rv = input @ cw in fp64; argmax([r0,r1,-r0,-r1])
// ---------------------------------------------------------------------------
__global__ __launch_bounds__(64) void rv_bucket_kernel(
    const float* __restrict__ input, const double* __restrict__ cw,
    int* __restrict__ buckets) {
  const int i = blockIdx.x;
  const int lane = threadIdx.x;
  double r0 = 0.0, r1 = 0.0;
  for (int f = lane; f < FEAT; f += 64) {
    double a = (double)input[(long)i * FEAT + f];
    r0 += a * cw[2 * f];
    r1 += a * cw[2 * f + 1];
  }
#pragma unroll
  for (int off = 32; off > 0; off >>= 1) {
    r0 += __shfl_down(r0, off);
    r1 += __shfl_down(r1, off);
  }
  if (lane == 0) {
    int b = 0;
    double best = r0;
    if (r1 > best)  { best = r1;  b = 1; }
    if (-r0 > best) { best = -r0; b = 2; }
    if (-r1 > best) { best = -r1; b = 3; }
    buckets[i] = b;
  }
}

// ---------------------------------------------------------------------------
// Stable counting sort by bucket (1 block, parallel Hillis-Steele scan).
// Emits perm AND inverse perm. Also zeroes cmean and rowsum.
// ---------------------------------------------------------------------------
__global__ __launch_bounds__(256) void sort_kernel(
    const int* __restrict__ buckets, int* __restrict__ perm,
    int* __restrict__ iperm, int* __restrict__ meta,
    float* __restrict__ cmean, float* __restrict__ rowsum) {
  __shared__ int lc[4][256];
  __shared__ int sc[4][256];
  __shared__ int boff_sh[5];
  const int t = threadIdx.x;
  cmean[t] = 0.f;
  cmean[t + 256] = 0.f;
  for (int k = t; k < N_NODES; k += 256) rowsum[k] = 0.f;
  const int base = t * 32;
  int c0 = 0, c1 = 0, c2 = 0, c3 = 0;
  for (int k = 0; k < 32; k++) {
    int b = buckets[base + k];
    c0 += (b == 0); c1 += (b == 1); c2 += (b == 2); c3 += (b == 3);
  }
  lc[0][t] = c0; lc[1][t] = c1; lc[2][t] = c2; lc[3][t] = c3;
  sc[0][t] = c0; sc[1][t] = c1; sc[2][t] = c2; sc[3][t] = c3;
  __syncthreads();
  for (int off = 1; off < 256; off <<= 1) {
    int a0 = (t >= off) ? sc[0][t - off] : 0;
    int a1 = (t >= off) ? sc[1][t - off] : 0;
    int a2 = (t >= off) ? sc[2][t - off] : 0;
    int a3 = (t >= off) ? sc[3][t - off] : 0;
    __syncthreads();
    sc[0][t] += a0; sc[1][t] += a1; sc[2][t] += a2; sc[3][t] += a3;
    __syncthreads();
  }
  if (t == 0) {
    int boff[5];
    boff[0] = 0;
    for (int b = 0; b < 4; b++) boff[b + 1] = boff[b] + sc[b][255];
    for (int b = 0; b < 5; b++) { meta[b] = boff[b]; boff_sh[b] = boff[b]; }
    long so = 0;
    int po = 0;
    for (int b = 0; b < 4; b++) {
      int tot = boff[b + 1] - boff[b];
      int pad = ((tot + 127) >> 7) << 7;
      meta[5 + b] = pad;
      meta[9 + b] = (int)so;
      meta[14 + b] = po;
      so += (long)pad * pad;
      po += pad;
    }
    meta[13] = (int)so;
    meta[18] = po;
    if (so > CAP_S)
      for (int b = 0; b < 4; b++) meta[5 + b] = 0;
  }
  __syncthreads();
  int s0 = boff_sh[0] + sc[0][t] - lc[0][t];
  int s1 = boff_sh[1] + sc[1][t] - lc[1][t];
  int s2 = boff_sh[2] + sc[2][t] - lc[2][t];
  int s3 = boff_sh[3] + sc[3][t] - lc[3][t];
  for (int k = 0; k < 32; k++) {
    int i = base + k;
    int b = buckets[i];
    int pos = (b == 0) ? s0++ : ((b == 1) ? s1++ : ((b == 2) ? s2++ : s3++));
    perm[pos] = i;
    iperm[i] = pos;
  }
}

// ---------------------------------------------------------------------------
// vhpT[f][poff_b + local] = bf16(vh[perm[boff_b + local]][f]); pads zeroed.
// Fused cmean column-sum accumulation (cmean pre-zeroed by sort_kernel).
// ---------------------------------------------------------------------------
__global__ __launch_bounds__(256) void transpose_vhpT_kernel(
    const float* __restrict__ vh, const int* __restrict__ perm,
    const int* __restrict__ meta, __hip_bfloat16* __restrict__ vhpT,
    float* __restrict__ cmean) {
  __shared__ float tile[64][65];
  __shared__ float cred[4][64];
  const int g0 = blockIdx.x * 64;
  const int f0 = blockIdx.y * 64;
  const int t = threadIdx.x;
#pragma unroll
  for (int s = 0; s < 16; s++) {
    int idx = t + s * 256;
    int r = idx >> 6, c = idx & 63;
    int pos = g0 + r;
    int b = (pos >= meta[15]) + (pos >= meta[16]) + (pos >= meta[17]);
    int local = pos - meta[14 + b];
    int n_b = meta[b + 1] - meta[b];
    float v = 0.f;
    if (local < n_b) v = vh[(long)perm[meta[b] + local] * FEAT + f0 + c];
    tile[r][c] = v;
  }
  __syncthreads();
  {
    const int c = t & 63, seg = t >> 6;
    float ps = 0.f;
#pragma unroll
    for (int rr = 0; rr < 16; rr++) ps += tile[seg * 16 + rr][c];
    cred[seg][c] = ps;
  }
  __syncthreads();
  if (t < 64)
    atomicAdd(&cmean[f0 + t],
              cred[0][t] + cred[1][t] + cred[2][t] + cred[3][t]);
#pragma unroll
  for (int s = 0; s < 16; s++) {
    int idx = t + s * 256;
    int fr = idx >> 6, gc = idx & 63;
    vhpT[(long)(f0 + fr) * VHPT_W + g0 + gc] = __float2bfloat16(tile[gc][fr]);
  }
}

// ---------------------------------------------------------------------------
// maskbits[g][jj] = (adj[perm[g]][perm[boff_b+jj]] > 0), bit-packed per 64.
// Runs EARLY (right after sort): its 268 MB adj stream evicts L3, so all
// later producer->consumer buffers (khp, vhpT, S) stay L3-resident.
// ---------------------------------------------------------------------------
__global__ __launch_bounds__(256) void maskpack_kernel(
    const int* __restrict__ adj, const int* __restrict__ perm,
    const int* __restrict__ meta, unsigned long long* __restrict__ maskbits) {
  __shared__ int adj_lds[N_NODES];
  const int g = blockIdx.x;
  const int t = threadIdx.x;
  const int b = (g >= meta[1]) + (g >= meta[2]) + (g >= meta[3]);
  const int boff = meta[b];
  const int n_b = meta[b + 1] - boff;
  const int padded = meta[5 + b];
  const int i = perm[g];
  const int* arow = adj + (long)i * N_NODES;
#pragma unroll
  for (int s = 0; s < 8; s++) {
    int idx = (t + s * 256) * 4;
    *(int4*)&adj_lds[idx] = *(const int4*)&arow[idx];
  }
  __syncthreads();
  const int lane = t & 63, w = t >> 6;
  for (int jj0 = w * 64; jj0 < padded; jj0 += 256) {
    int jj = jj0 + lane;
    int pred = 0;
    if (jj < n_b) pred = adj_lds[perm[boff + jj]] > 0;
    unsigned long long mword = __ballot(pred);
    if (lane == 0) maskbits[(long)g * 128 + (jj0 >> 6)] = mword;
  }
}

// ---------------------------------------------------------------------------
// S tile = khp_b . khp_b^T (bf16 MFMA). DOUBLE-BUFFERED prefetch: per 64-wide
// K-step, issue next-step loads into buf^1 before computing buf; one barrier
// per step. FUSED NO-MAX SOFTMAX NUMERATOR: epilogue stores
// P~ = bf16(exp(S/sqrt(H))) (masked -> 0) and accumulates f32 row sums via
// 16-lane shfl reduce + one atomicAdd per (row, tile). Scores are bounded
// (~50 << 88) so f32 exp cannot overflow; exp(S)/sum == softmax exactly.
// Triangular grid ti <= tj; both orientations written from an LDS tile with
// coalesced 16B stores. Pad rows excluded from row-sum atomics.
// ---------------------------------------------------------------------------
__global__ __launch_bounds__(256) void s_gemm(
    const __hip_bfloat16* __restrict__ khp, const int* __restrict__ meta,
    const unsigned long long* __restrict__ maskbits,
    __hip_bfloat16* __restrict__ S, float* __restrict__ rowsum) {
  const int b = blockIdx.z;
  const int padded = meta[5 + b];
  const int T = padded >> 7;
  const int pairs = (T * (T + 1)) >> 1;
  int L = blockIdx.x;
  if (L >= pairs) return;
  int ti = 0;
  while (L >= T - ti) { L -= T - ti; ti++; }
  const int tj = ti + L;
  const int boff = meta[b];
  const int n_b = meta[b + 1] - boff;
  const long soff = meta[9 + b];
  // 64 KB: As/Bs each [2 dbuf][2 panels][4096]; Ct[128][136] epilogue.
  __shared__ __align__(16) __hip_bfloat16 smem[32768];
  __hip_bfloat16* As = smem;            // [2][2][4096]
  __hip_bfloat16* Bs = smem + 16384;    // [2][2][4096]
  const int t = threadIdx.x;
  const int lane = t & 63, w = t >> 6;
  const int wm = (w >> 1) * 64, wn = (w & 1) * 64;
  const int quad = lane >> 4, ln = lane & 15;
  const int qr = quad * 8;
  floatx4 acc[4][4];
#pragma unroll
  for (int mi = 0; mi < 4; mi++)
#pragma unroll
    for (int ni = 0; ni < 4; ni++) acc[mi][ni] = (floatx4)0.f;
  const long a_g0 = boff + ti * 128;
  const long b_g0 = boff + tj * 128;

  auto STAGE = [&](int st, int buf) {
    const int k0 = st * 64;
#pragma unroll
    for (int p = 0; p < 2; p++)
#pragma unroll
      for (int s = 0; s < 2; s++) {
        int c = t + s * 256;
        int row = c >> 2, off8 = (c & 3) * 8;
        int lo = buf * 8192 + p * 4096 + row * 32 + off8;
        async_copy16(&khp[(a_g0 + row) * FEAT + k0 + p * 32 + off8], &As[lo]);
        async_copy16(&khp[(b_g0 + row) * FEAT + k0 + p * 32 + off8], &Bs[lo]);
      }
  };
  STAGE(0, 0);
  __syncthreads();
  for (int st = 0; st < 8; st++) {
    const int buf = st & 1;
    if (st < 7) STAGE(st + 1, buf ^ 1);
#pragma unroll
    for (int p = 0; p < 2; p++) {
      short8 af[4], bfr[4];
#pragma unroll
      for (int mi = 0; mi < 4; mi++)
        af[mi] = *(const short8*)&As[buf * 8192 + p * 4096 +
                                     (wm + mi * 16 + ln) * 32 + qr];
#pragma unroll
      for (int ni = 0; ni < 4; ni++)
        bfr[ni] = *(const short8*)&Bs[buf * 8192 + p * 4096 +
                                      (wn + ni * 16 + ln) * 32 + qr];
#pragma unroll
      for (int mi = 0; mi < 4; mi++)
#pragma unroll
        for (int ni = 0; ni < 4; ni++)
          acc[mi][ni] = __builtin_amdgcn_mfma_f32_16x16x32_bf16(
              af[mi], bfr[ni], acc[mi][ni], 0, 0, 0);
    }
    __syncthreads();
  }
  // ---- epilogue: P~ = bf16(exp(acc*scale)) -> LDS tile (unmasked) ----
  // loop-end barrier already drained all ds_reads -> safe to reuse smem.
  const float scale = 0.04419417382415922f;  // 1/sqrt(512)
  __hip_bfloat16* Ct = smem;  // [128][136]
#pragma unroll
  for (int mi = 0; mi < 4; mi++)
#pragma unroll
    for (int ni = 0; ni < 4; ni++) {
      int col = wn + ni * 16 + ln;
#pragma unroll
      for (int reg = 0; reg < 4; reg++) {
        int row = wm + mi * 16 + quad * 4 + reg;
        Ct[row * 136 + col] =
            __float2bfloat16(__expf(acc[mi][ni][reg] * scale));
      }
    }
  __syncthreads();
  // normal orientation: coalesced 16B stores of rows of the ti-block
#pragma unroll
  for (int i = 0; i < 8; i++) {
    int idx = t + i * 256;
    int rl = idx >> 4, c8 = (idx & 15) * 8;
    int rg = ti * 128 + rl;
    int cg = tj * 128 + c8;
    union { short8 v; unsigned short u[8]; } pk;
    pk.v = *(const short8*)&Ct[rl * 136 + c8];
    unsigned long long wbits = maskbits[(long)(boff + rg) * 128 + (cg >> 6)];
    float ps = 0.f;
#pragma unroll
    for (int e = 0; e < 8; e++) {
      if (!((wbits >> ((cg & 63) + e)) & 1ULL)) pk.u[e] = 0;
      ps += bf_bits2f(pk.u[e]);
    }
    *(short8*)&S[soff + (long)rg * padded + cg] = pk.v;
    // per-row partial sum: 16 consecutive lanes share rg
#pragma unroll
    for (int off = 1; off < 16; off <<= 1) ps += __shfl_xor(ps, off);
    if (rg < n_b && (lane & 15) == 0)
      atomicAdd(&rowsum[boff + rg], ps);
  }
  // mirrored orientation (tj-block rows), skipped on diagonal
  if (ti != tj) {
#pragma unroll
    for (int i = 0; i < 8; i++) {
      int idx = t + i * 256;
      int cl = idx >> 4, r8 = (idx & 15) * 8;
      int rg = tj * 128 + cl;   // output row (column of the computed tile)
      int cg = ti * 128 + r8;   // output col base
      union { short8 v; unsigned short u[8]; } pk;
#pragma unroll
      for (int e = 0; e < 8; e++) {
        __hip_bfloat16 hv = Ct[(r8 + e) * 136 + cl];
        __builtin_memcpy(&pk.u[e], &hv, 2);
      }
      unsigned long long wbits = maskbits[(long)(boff + rg) * 128 + (cg >> 6)];
      float ps = 0.f;
#pragma unroll
      for (int e = 0; e < 8; e++) {
        if (!((wbits >> ((cg & 63) + e)) & 1ULL)) pk.u[e] = 0;
        ps += bf_bits2f(pk.u[e]);
      }
      *(short8*)&S[soff + (long)rg * padded + cg] = pk.v;
#pragma unroll
      for (int off = 1; off < 16; off <<= 1) ps += __shfl_xor(ps, off);
      if (rg < n_b && (lane & 15) == 0)
        atomicAdd(&rowsum[boff + rg], ps);
    }
  }
}

// ---------------------------------------------------------------------------
// O tile = P~ . vhp (pure bf16 GEMM), 64 rows x 128 features per block.
// DOUBLE-BUFFERED prefetch per 64-wide K-step, one barrier per step.
// Epilogue: x (1/rowsum) (softmax denom, exact) + ELU + empty-row
// (rowsum==0) cmean fallback + scatter to out[perm[g]].
// ---------------------------------------------------------------------------
__global__ __launch_bounds__(256) void pv_gemm(
    const __hip_bfloat16* __restrict__ S, const __hip_bfloat16* __restrict__ vhpT,
    const int* __restrict__ meta, const int* __restrict__ perm,
    const float* __restrict__ cmean, const float* __restrict__ rowsum,
    float* __restrict__ out) {
  const int b = blockIdx.z;
  const int padded = meta[5 + b];
  const int ti = blockIdx.x;
  if (ti * 64 >= padded) return;
  const int boff = meta[b];
  const int n_b = meta[b + 1] - boff;
  const long soff = meta[9 + b];
  const int poff = meta[14 + b];
  const int f0 = blockIdx.y * 128;
  __shared__ __align__(16) __hip_bfloat16 As[2 * 2 * 2048];  // 16 KB
  __shared__ __align__(16) __hip_bfloat16 Bs[2 * 2 * 4096];  // 32 KB
  const int t = threadIdx.x;
  const int lane = t & 63, w = t >> 6;
  const int wm = (w >> 1) * 32, wn = (w & 1) * 64;
  const int quad = lane >> 4, ln = lane & 15;
  const int qr = quad * 8;
  floatx4 acc[2][4];
#pragma unroll
  for (int mi = 0; mi < 2; mi++)
#pragma unroll
    for (int ni = 0; ni < 4; ni++) acc[mi][ni] = (floatx4)0.f;
  const long r0 = (long)ti * 64;

  auto STAGE = [&](int st, int buf) {
    const int k0 = st * 64;
#pragma unroll
    for (int p = 0; p < 2; p++) {
      {
        int row = t >> 2, off8 = (t & 3) * 8;
        async_copy16(&S[soff + (r0 + row) * padded + k0 + p * 32 + off8],
                     &As[buf * 4096 + p * 2048 + row * 32 + off8]);
      }
#pragma unroll
      for (int s = 0; s < 2; s++) {
        int c = t + s * 256;
        int row = c >> 2, off8 = (c & 3) * 8;
        async_copy16(
            &vhpT[(long)(f0 + row) * VHPT_W + poff + k0 + p * 32 + off8],
            &Bs[buf * 8192 + p * 4096 + row * 32 + off8]);
      }
    }
  };
  const int NS = padded >> 6;
  STAGE(0, 0);
  __syncthreads();
  for (int st = 0; st < NS; st++) {
    const int buf = st & 1;
    if (st + 1 < NS) STAGE(st + 1, buf ^ 1);
#pragma unroll
    for (int p = 0; p < 2; p++) {
      short8 af[2], bfr[4];
#pragma unroll
      for (int mi = 0; mi < 2; mi++)
        af[mi] = *(const short8*)&As[buf * 4096 + p * 2048 +
                                     (wm + mi * 16 + ln) * 32 + qr];
#pragma unroll
      for (int ni = 0; ni < 4; ni++)
        bfr[ni] = *(const short8*)&Bs[buf * 8192 + p * 4096 +
                                      (wn + ni * 16 + ln) * 32 + qr];
#pragma unroll
      for (int mi = 0; mi < 2; mi++)
#pragma unroll
        for (int ni = 0; ni < 4; ni++)
          acc[mi][ni] = __builtin_amdgcn_mfma_f32_16x16x32_bf16(
              af[mi], bfr[ni], acc[mi][ni], 0, 0, 0);
    }
    __syncthreads();
  }
#pragma unroll
  for (int mi = 0; mi < 2; mi++) {
#pragma unroll
    for (int reg = 0; reg < 4; reg++) {
      int r = ti * 64 + wm + mi * 16 + quad * 4 + reg;
      if (r < n_b) {
        int g = boff + r;
        int node = perm[g];
        float rs = rowsum[g];
        int fl = (rs == 0.f);
        float inv = fl ? 0.f : 1.f / rs;
#pragma unroll
        for (int ni = 0; ni < 4; ni++) {
          int fc = f0 + wn + ni * 16 + ln;
          float v = fl ? cmean[fc] * (1.f / (float)N_NODES)
                       : acc[mi][ni][reg] * inv;
          v = v > 0.f ? v : expm1f(v);
          out[(long)node * FEAT + fc] = v;
        }
      }
    }
  }
}

// ===========================================================================
// Slow-path fallback (only if ws_size < WS_NEEDED): round-1 implementation.
// ===========================================================================
__global__ __launch_bounds__(256) void gemm_dual(
    const float* __restrict__ A, const float* __restrict__ Wk,
    const float* __restrict__ Wv, float* __restrict__ kh,
    float* __restrict__ vh) {
  __shared__ float As[32][33];
  __shared__ float Bk[32][33];
  __shared__ float Bv[32][33];
  const int tid = threadIdx.x;
  const int row0 = blockIdx.x * 32;
  const int col0 = blockIdx.y * 32;
  const int tx = tid & 15, ty = tid >> 4;
  float ck00 = 0.f, ck01 = 0.f, ck10 = 0.f, ck11 = 0.f;
  float cv00 = 0.f, cv01 = 0.f, cv10 = 0.f, cv11 = 0.f;
  for (int kt = 0; kt < FEAT; kt += 32) {
#pragma unroll
    for (int t = 0; t < 4; t++) {
      int e = tid + t * 256;
      int r = e >> 5, c = e & 31;
      As[r][c] = A[(long)(row0 + r) * FEAT + kt + c];
      Bk[r][c] = Wk[(long)(kt + r) * FEAT + col0 + c];
      Bv[r][c] = Wv[(long)(kt + r) * FEAT + col0 + c];
    }
    __syncthreads();
#pragma unroll
    for (int kk = 0; kk < 32; kk++) {
      float a0 = As[ty * 2][kk], a1 = As[ty * 2 + 1][kk];
      float bk0 = Bk[kk][tx * 2], bk1 = Bk[kk][tx * 2 + 1];
      float bv0 = Bv[kk][tx * 2], bv1 = Bv[kk][tx * 2 + 1];
      ck00 += a0 * bk0; ck01 += a0 * bk1;
      ck10 += a1 * bk0; ck11 += a1 * bk1;
      cv00 += a0 * bv0; cv01 += a0 * bv1;
      cv10 += a1 * bv0; cv11 += a1 * bv1;
    }
    __syncthreads();
  }
  const int r0 = row0 + ty * 2, c0 = col0 + tx * 2;
  kh[(long)r0 * FEAT + c0] = ck00;       kh[(long)r0 * FEAT + c0 + 1] = ck01;
  kh[(long)(r0 + 1) * FEAT + c0] = ck10; kh[(long)(r0 + 1) * FEAT + c0 + 1] = ck11;
  vh[(long)r0 * FEAT + c0] = cv00;       vh[(long)r0 * FEAT + c0 + 1] = cv01;
  vh[(long)(r0 + 1) * FEAT + c0] = cv10; vh[(long)(r0 + 1) * FEAT + c0 + 1] = cv11;
}

__global__ __launch_bounds__(64) void bucket_kernel(
    const float* __restrict__ kh, const float* __restrict__ rot,
    int* __restrict__ buckets) {
  const int i = blockIdx.x;
  const int lane = threadIdx.x;
  double r0 = 0.0, r1 = 0.0;
  for (int h = lane; h < FEAT; h += 64) {
    double a = (double)kh[(long)i * FEAT + h];
    r0 += a * (double)rot[2 * h];
    r1 += a * (double)rot[2 * h + 1];
  }
#pragma unroll
  for (int off = 32; off > 0; off >>= 1) {
    r0 += __shfl_down(r0, off);
    r1 += __shfl_down(r1, off);
  }
  if (lane == 0) {
    int b = 0;
    double best = r0;
    if (r1 > best)  { best = r1;  b = 1; }
    if (-r0 > best) { best = -r0; b = 2; }
    if (-r1 > best) { best = -r1; b = 3; }
    buckets[i] = b;
  }
}

__global__ __launch_bounds__(256) void attn_kernel(
    const float* __restrict__ kh, const float* __restrict__ vh,
    const int* __restrict__ adj, const int* __restrict__ buckets,
    float* __restrict__ out) {
  __shared__ float khi[FEAT];
  __shared__ float pbuf[N_NODES];
  __shared__ unsigned short jlist[N_NODES];
  __shared__ int cnt_sh;
  __shared__ float red[256];
  const int i = blockIdx.x;
  const int tid = threadIdx.x;
  if (tid == 0) cnt_sh = 0;
  for (int k = tid; k < FEAT; k += 256) khi[k] = kh[(long)i * FEAT + k];
  const int mybucket = buckets[i];
  __syncthreads();
  const int* adjrow = adj + (long)i * N_NODES;
  for (int j = tid; j < N_NODES; j += 256) {
    if (adjrow[j] > 0 && buckets[j] == mybucket) {
      int idx = atomicAdd(&cnt_sh, 1);
      jlist[idx] = (unsigned short)j;
    }
  }
  __syncthreads();
  const int cnt = cnt_sh;
  float mloc = -INFINITY;
  for (int idx = tid; idx < cnt; idx += 256) {
    int j = jlist[idx];
    const float4* kj = (const float4*)(kh + (long)j * FEAT);
    const float4* ki = (const float4*)khi;
    float acc = 0.f;
#pragma unroll 8
    for (int k = 0; k < FEAT / 4; k++) {
      float4 a = ki[k];
      float4 b = kj[k];
      acc += a.x * b.x + a.y * b.y + a.z * b.z + a.w * b.w;
    }
    float s = acc * 0.04419417382415922f;
    pbuf[idx] = s;
    mloc = fmaxf(mloc, s);
  }
  red[tid] = mloc;
  __syncthreads();
#pragma unroll
  for (int off = 128; off > 0; off >>= 1) {
    if (tid < off) red[tid] = fmaxf(red[tid], red[tid + off]);
    __syncthreads();
  }
  const float m = red[0];
  __syncthreads();
  float lloc = 0.f;
  for (int idx = tid; idx < cnt; idx += 256) {
    float p = expf(pbuf[idx] - m);
    pbuf[idx] = p;
    lloc += p;
  }
  red[tid] = lloc;
  __syncthreads();
#pragma unroll
  for (int off = 128; off > 0; off >>= 1) {
    if (tid < off) red[tid] += red[tid + off];
    __syncthreads();
  }
  const float l = red[0];
  __syncthreads();
  const int f = 2 * tid;
  float acc0 = 0.f, acc1 = 0.f;
  if (cnt > 0) {
#pragma unroll 4
    for (int idx = 0; idx < cnt; idx++) {
      int j = jlist[idx];
      float p = pbuf[idx];
      float2 v = *(const float2*)(vh + (long)j * FEAT + f);
      acc0 += p * v.x;
      acc1 += p * v.y;
    }
    float invl = 1.f / l;
    acc0 *= invl;
    acc1 *= invl;
  } else {
    for (int j = 0; j < N_NODES; j++) {
      float2 v = *(const float2*)(vh + (long)j * FEAT + f);
      acc0 += v.x;
      acc1 += v.y;
    }
    acc0 *= (1.f / (float)N_NODES);
    acc1 *= (1.f / (float)N_NODES);
  }
  acc0 = acc0 > 0.f ? acc0 : expm1f(acc0);
  acc1 = acc1 > 0.f ? acc1 : expm1f(acc1);
  *(float2*)(out + (long)i * FEAT + f) = make_float2(acc0, acc1);
}

extern "C" void kernel_launch(void* const* d_in, const int* in_sizes, int n_in,
                              void* d_out, int out_size, void* d_ws,
                              size_t ws_size, hipStream_t stream) {
  const float* input = (const float*)d_in[0];
  const int* adj = (const int*)d_in[1];
  const float* rot = (const float*)d_in[2];
  const float* kW = (const float*)d_in[3];
  const float* vW = (const float*)d_in[4];
  float* out = (float*)d_out;

  char* ws = (char*)d_ws;

  if (ws_size >= WS_NEEDED) {
    float* vh = (float*)(ws + OFF_VH);
    __hip_bfloat16* khp = (__hip_bfloat16*)(ws + OFF_KHP);
    __hip_bfloat16* vhpT = (__hip_bfloat16*)(ws + OFF_VHPT);
    unsigned long long* maskbits = (unsigned long long*)(ws + OFF_MASK);
    __hip_bfloat16* S = (__hip_bfloat16*)(ws + OFF_S);
    int* perm = (int*)(ws + OFF_PERM);
    int* iperm = (int*)(ws + OFF_IPERM);
    int* buckets = (int*)(ws + OFF_BUCK);
    int* meta = (int*)(ws + OFF_META);
    float* cmean = (float*)(ws + OFF_CMEAN);
    float* rowsum = (float*)(ws + OFF_ROWI);
    __hip_bfloat16* Ab = (__hip_bfloat16*)(ws + OFF_AB);
    __hip_bfloat16* WkT = (__hip_bfloat16*)(ws + OFF_WKT);
    __hip_bfloat16* WvT = (__hip_bfloat16*)(ws + OFF_WVT);
    double* cw = (double*)(ws + OFF_CW);

    // zero khp tail rows [8192, 8320) — read (masked) by s_gemm/pv when the
    // last bucket's padding spills past N.
    hipMemsetAsync(ws + OFF_KHP + (size_t)N_NODES * FEAT * 2, 0,
                   128 * FEAT * 2, stream);
    // ---- L3-aware schedule: the 268 MB adj stream (maskpack) runs BEFORE
    // any producer->consumer bf16 buffers are written, so khp/vhpT/S stay
    // L3-resident through the GEMM back half.
    cw_kernel<<<512, 64, 0, stream>>>(kW, rot, cw);
    rv_bucket_kernel<<<N_NODES, 64, 0, stream>>>(input, cw, buckets);
    sort_kernel<<<1, 256, 0, stream>>>(buckets, perm, iperm, meta, cmean,
                                       rowsum);
    maskpack_kernel<<<N_NODES, 256, 0, stream>>>(adj, perm, meta, maskbits);
    convert_input<<<2048, 256, 0, stream>>>(input, Ab);
    convert_w<<<dim3(8, 8, 2), 256, 0, stream>>>(kW, vW, WkT, WvT);
    mfma_dual<<<dim3(64, 4, 2), 256, 0, stream>>>(Ab, WkT, WvT, iperm, khp,
                                                  vh);
    transpose_vhpT_kernel<<<dim3(VHPT_W / 64, FEAT / 64), 256, 0, stream>>>(
        vh, perm, meta, vhpT, cmean);
    s_gemm<<<dim3(2080, 1, 4), 256, 0, stream>>>(khp, meta, maskbits, S,
                                                 rowsum);
    pv_gemm<<<dim3(128, 4, 4), 256, 0, stream>>>(S, vhpT, meta, perm, cmean,
                                                 rowsum, out);
  } else {
    float* kh = (float*)(ws + 0UL);
    float* vh = (float*)(ws + 16777216UL);
    int* buckets = (int*)(ws + 33554432UL);
    dim3 gemm_grid(N_NODES / 32, FEAT / 32);
    gemm_dual<<<gemm_grid, 256, 0, stream>>>(input, kW, vW, kh, vh);
    bucket_kernel<<<N_NODES, 64, 0, stream>>>(kh, rot, buckets);
    attn_kernel<<<N_NODES, 256, 0, stream>>>(kh, vh, adj, buckets, out);
  }
}